// Round 5
// baseline (855.300 us; speedup 1.0000x reference)
//
#include <hip/hip_runtime.h>
#include <hip/hip_bf16.h>

// Problem constants (from reference)
#define NB      100000    // B*N nodes
#define NPB     25000     // N per batch
#define T_E     800000    // B*E total edges
#define EPG     200000    // E per graph
#define DMODEL  128       // OUT = H*DH
#define EDIM    32
#define FFD     256

typedef __attribute__((ext_vector_type(8))) short bf16x8;
typedef __attribute__((ext_vector_type(4))) float f32x4;

__device__ inline unsigned short f2bf(float f) {
    unsigned u = __float_as_uint(f);
    unsigned r = u + 0x7fffu + ((u >> 16) & 1u);   // RNE
    return (unsigned short)(r >> 16);
}
__device__ inline unsigned pack_bf16x2(float lo, float hi) {
    return (unsigned)f2bf(lo) | ((unsigned)f2bf(hi) << 16);
}
__device__ inline float bf_lo(unsigned p) { return __uint_as_float(p << 16); }
__device__ inline float bf_hi(unsigned p) { return __uint_as_float(p & 0xffff0000u); }

// -------------------------------------------------------------------------
// Kernel 1 (MFMA): node projections. blockIdx.y selects matrix
// (0=Q,1=K,2=V,3=skip->skipb + zero agg). Outputs q/k/v/skip as bf16.
// 128 nodes per block, 256 threads = 4 waves.
// -------------------------------------------------------------------------
#define XS_OFF 0
#define WT_OFF 32768

__global__ __launch_bounds__(256) void k_proj_mfma(
    const float* __restrict__ x,
    const float* __restrict__ Wq, const float* __restrict__ bq,
    const float* __restrict__ Wk, const float* __restrict__ bk,
    const float* __restrict__ Wv, const float* __restrict__ bv,
    const float* __restrict__ Wskip, const float* __restrict__ bskip,
    unsigned short* __restrict__ qb16, unsigned short* __restrict__ kb16,
    unsigned short* __restrict__ vb16, unsigned short* __restrict__ skipb16,
    float* __restrict__ agg, float* __restrict__ denom)
{
    __shared__ __align__(16) char lds[65536];
    const int tid   = threadIdx.x;
    const int m     = blockIdx.y;
    const int node0 = blockIdx.x * 128;

    const float* W   = (m == 0) ? Wq : (m == 1) ? Wk : (m == 2) ? Wv : Wskip;
    const float* bi  = (m == 0) ? bq : (m == 1) ? bk : (m == 2) ? bv : bskip;
    unsigned short* outp = (m == 0) ? qb16 : (m == 1) ? kb16 : (m == 2) ? vb16 : skipb16;

    // ---- stage xs: x[b,c,nn] -> xs[node_local][c] (bf16, swizzled)
    {
        const int nl   = tid & 127;
        const int half = tid >> 7;
        const int node = node0 + nl;
        const bool valid = node < NB;
        int b  = node / NPB;
        int nn = node - b * NPB;
        const float* xbase = x + (size_t)b * DMODEL * NPB + nn;
#pragma unroll
        for (int o = 0; o < 8; ++o) {
            int c0 = (o * 2 + half) * 8;       // octet of 8 channels
            unsigned vals[4];
#pragma unroll
            for (int j2 = 0; j2 < 4; ++j2) {
                float f0 = valid ? xbase[(size_t)(c0 + 2 * j2) * NPB] : 0.f;
                float f1 = valid ? xbase[(size_t)(c0 + 2 * j2 + 1) * NPB] : 0.f;
                vals[j2] = pack_bf16x2(f0, f1);
            }
            int byte = nl * 256 + ((c0 * 2) ^ ((nl & 7) << 4));
            *(uint4*)(&lds[XS_OFF + byte]) = make_uint4(vals[0], vals[1], vals[2], vals[3]);
        }
    }
    // ---- stage wt: W[c,col] -> wt[col][c] (bf16, swizzled)
    {
        const int col  = tid & 127;
        const int half = tid >> 7;
#pragma unroll
        for (int o = 0; o < 8; ++o) {
            int c0 = (o * 2 + half) * 8;
            unsigned vals[4];
#pragma unroll
            for (int j2 = 0; j2 < 4; ++j2) {
                float f0 = W[(size_t)(c0 + 2 * j2) * DMODEL + col];
                float f1 = W[(size_t)(c0 + 2 * j2 + 1) * DMODEL + col];
                vals[j2] = pack_bf16x2(f0, f1);
            }
            int byte = col * 256 + ((c0 * 2) ^ ((col & 7) << 4));
            *(uint4*)(&lds[WT_OFF + byte]) = make_uint4(vals[0], vals[1], vals[2], vals[3]);
        }
    }
    // denom zero (only the m==0 grid slice)
    if (m == 0) {
#pragma unroll
        for (int i = 0; i < 2; ++i) {
            int idx  = i * 256 + tid;          // 0..511
            int node = node0 + (idx >> 2);
            if (node < NB) denom[node * 4 + (idx & 3)] = 0.f;
        }
    }
    __syncthreads();

    // ---- MFMA: wave w computes nodes [w*32, w*32+32) x all 128 cols
    const int w    = tid >> 6;
    const int lane = tid & 63;
    const int rl   = lane & 15;
    const int g    = lane >> 4;

    f32x4 acc[2][8] = {};
#pragma unroll
    for (int ks = 0; ks < 4; ++ks) {
        const int kb2 = ks * 64 + g * 16;      // byte offset of this lane's k-octet
        bf16x8 a[2], b[8];
#pragma unroll
        for (int mt = 0; mt < 2; ++mt) {
            int row = w * 32 + mt * 16 + rl;
            a[mt] = *(const bf16x8*)(&lds[XS_OFF + row * 256 + (kb2 ^ ((row & 7) << 4))]);
        }
#pragma unroll
        for (int nt = 0; nt < 8; ++nt) {
            int colr = nt * 16 + rl;
            b[nt] = *(const bf16x8*)(&lds[WT_OFF + colr * 256 + (kb2 ^ ((colr & 7) << 4))]);
        }
#pragma unroll
        for (int mt = 0; mt < 2; ++mt)
#pragma unroll
            for (int nt = 0; nt < 8; ++nt)
                acc[mt][nt] = __builtin_amdgcn_mfma_f32_16x16x32_bf16(
                    a[mt], b[nt], acc[mt][nt], 0, 0, 0);
    }

    // ---- epilogue: D col = lane&15, row = (lane>>4)*4 + r  -> bf16 stores
#pragma unroll
    for (int mt = 0; mt < 2; ++mt) {
        int nodeb = node0 + w * 32 + mt * 16 + g * 4;
#pragma unroll
        for (int nt = 0; nt < 8; ++nt) {
            int col = nt * 16 + rl;
            float bv_ = bi[col];
#pragma unroll
            for (int r = 0; r < 4; ++r) {
                int node = nodeb + r;
                if (node < NB) {
                    size_t idx = (size_t)node * DMODEL + col;
                    outp[idx] = f2bf(acc[mt][nt][r] + bv_);
                    if (m == 3) agg[idx] = 0.f;
                }
            }
        }
    }
}

// -------------------------------------------------------------------------
// Kernel 2 (fused edge pass): per edge, e = eattr @ We, alpha = q[dst].(k[src]+e),
// ea = exp(alpha*scale); atomically accumulate UNNORMALIZED ea*(v[src]+e) into
// agg and ea into denom.  1 wave = 1 edge slot, lane l owns channels 2l,2l+1.
// Block = 256 thr = 4 waves; 64 edges staged per block, 16 sub-iterations.
// -------------------------------------------------------------------------
__global__ __launch_bounds__(256) void k_edge(
    const unsigned short* __restrict__ qb16, const unsigned short* __restrict__ kb16,
    const unsigned short* __restrict__ vb16,
    const int*   __restrict__ eidx, const float* __restrict__ eattr,
    const float* __restrict__ We,
    float* __restrict__ agg, float* __restrict__ denom)
{
    __shared__ float eas[64][32];     // 8 KB
    __shared__ int   srcs[64], dsts[64];
    const int tid = threadIdx.x;
    const int t0  = blockIdx.x * 64;
    const int w   = tid >> 6;
    const int l   = tid & 63;

    // per-lane We columns 2l, 2l+1 (64 VGPRs)
    float wer0[32], wer1[32];
#pragma unroll
    for (int k = 0; k < EDIM; ++k) {
        wer0[k] = We[k * DMODEL + 2 * l];
        wer1[k] = We[k * DMODEL + 2 * l + 1];
    }

    // stage 64 edges' attrs (coalesced: contiguous 2048 floats)
#pragma unroll
    for (int it = 0; it < 8; ++it) {
        int linear = it * 256 + tid;
        eas[linear >> 5][linear & 31] = eattr[(size_t)t0 * EDIM + linear];
    }
    if (tid < 64) {
        int t = t0 + tid;
        int b = t / EPG;
        int e = t - b * EPG;
        srcs[tid] = eidx[(size_t)(b * 2) * EPG + e];
        dsts[tid] = eidx[(size_t)(b * 2 + 1) * EPG + e];
    }
    __syncthreads();

    for (int sub = 0; sub < 16; ++sub) {
        int slot = sub * 4 + w;
        // e-proj for channels 2l, 2l+1
        float e0 = 0.f, e1 = 0.f;
        const float4* er = (const float4*)eas[slot];
#pragma unroll
        for (int k4 = 0; k4 < 8; ++k4) {
            float4 ev = er[k4];
            e0 += ev.x * wer0[4 * k4 + 0] + ev.y * wer0[4 * k4 + 1]
                + ev.z * wer0[4 * k4 + 2] + ev.w * wer0[4 * k4 + 3];
            e1 += ev.x * wer1[4 * k4 + 0] + ev.y * wer1[4 * k4 + 1]
                + ev.z * wer1[4 * k4 + 2] + ev.w * wer1[4 * k4 + 3];
        }
        int sv = srcs[slot], dv = dsts[slot];
        unsigned qp = *(const unsigned*)&qb16[(size_t)dv * DMODEL + 2 * l];
        unsigned kp = *(const unsigned*)&kb16[(size_t)sv * DMODEL + 2 * l];
        unsigned vp = *(const unsigned*)&vb16[(size_t)sv * DMODEL + 2 * l];
        float p = bf_lo(qp) * (bf_lo(kp) + e0) + bf_hi(qp) * (bf_hi(kp) + e1);
        // reduce over the 16 lanes of this head (head = l>>4)
#pragma unroll
        for (int off = 8; off >= 1; off >>= 1) p += __shfl_xor(p, off, 64);
        float ea = __expf(p * 0.17677669529663689f);   // 1/sqrt(32)
        float a0 = ea * (bf_lo(vp) + e0);
        float a1 = ea * (bf_hi(vp) + e1);
        float* ap = &agg[(size_t)dv * DMODEL + 2 * l];
        unsafeAtomicAdd(ap, a0);
        unsafeAtomicAdd(ap + 1, a1);
        if ((l & 15) == 0) unsafeAtomicAdd(&denom[dv * 4 + (l >> 4)], ea);
    }
}

// -------------------------------------------------------------------------
// Kernel 2.5: pre-pack W1^T and W2^T into MFMA A-fragment layout (bf16).
// -------------------------------------------------------------------------
__global__ __launch_bounds__(256) void k_prep(
    const float* __restrict__ W1, const float* __restrict__ W2,
    uint4* __restrict__ w1f, uint4* __restrict__ w2f)
{
    int t = blockIdx.x * 256 + threadIdx.x;   // 0..8191
    int lane = t & 63;
    int frag = t >> 6;                         // 0..127
    int rl = lane & 15, g = lane >> 4;
    unsigned v[4];
    if (frag < 64) {
        int m1 = frag >> 2, ks = frag & 3;
        int col1 = m1 * 16 + rl;
        int k0 = ks * 32 + g * 8;
#pragma unroll
        for (int j2 = 0; j2 < 4; ++j2) {
            float f0 = W1[(k0 + 2 * j2) * FFD + col1];
            float f1 = W1[(k0 + 2 * j2 + 1) * FFD + col1];
            v[j2] = pack_bf16x2(f0, f1);
        }
        w1f[frag * 64 + lane] = make_uint4(v[0], v[1], v[2], v[3]);
    } else {
        int f2 = frag - 64;
        int m2 = f2 >> 3, ks = f2 & 7;
        int c2 = m2 * 16 + rl;
        int k0 = ks * 32 + g * 8;
#pragma unroll
        for (int j2 = 0; j2 < 4; ++j2) {
            float f0 = W2[(k0 + 2 * j2) * DMODEL + c2];
            float f1 = W2[(k0 + 2 * j2 + 1) * DMODEL + c2];
            v[j2] = pack_bf16x2(f0, f1);
        }
        w2f[f2 * 64 + lane] = make_uint4(v[0], v[1], v[2], v[3]);
    }
}

// -------------------------------------------------------------------------
// Kernel 3 (MFMA): normalize + skip + FFN + transposed output write.
// xs = agg/(denom+1e-16) + skip  (staged bf16, swizzled), then 2 GEMMs.
// -------------------------------------------------------------------------
#define H1_OFF 16384

__global__ __launch_bounds__(256) void k_ffn_mfma(
    const float* __restrict__ agg, const float* __restrict__ denom,
    const unsigned short* __restrict__ skipb16,
    const uint4* __restrict__ w1f, const float* __restrict__ b1,
    const uint4* __restrict__ w2f, const float* __restrict__ b2,
    float* __restrict__ out)
{
    __shared__ __align__(16) char lds[49152];
    const int tid   = threadIdx.x;
    const int node0 = blockIdx.x * 64;

    // ---- stage xs[row][c] = agg/(den+eps) + skip   (bf16 swizzled)
#pragma unroll
    for (int i = 0; i < 8; ++i) {
        int linear = i * 256 + tid;            // 0..2047
        int row = linear >> 5;                 // 0..63
        int c4  = (linear & 31) * 4;           // starting channel, mult of 4
        int node = node0 + row;
        float v0 = 0.f, v1 = 0.f, v2 = 0.f, v3 = 0.f;
        if (node < NB) {
            float4 f = *(const float4*)&agg[(size_t)node * DMODEL + c4];
            float den = denom[node * 4 + (c4 >> 5)] + 1e-16f;
            float rden = 1.0f / den;
            uint2 sp = *(const uint2*)&skipb16[(size_t)node * DMODEL + c4];
            v0 = f.x * rden + bf_lo(sp.x);
            v1 = f.y * rden + bf_hi(sp.x);
            v2 = f.z * rden + bf_lo(sp.y);
            v3 = f.w * rden + bf_hi(sp.y);
        }
        unsigned lo = pack_bf16x2(v0, v1), hi = pack_bf16x2(v2, v3);
        int byte = row * 256 + ((c4 * 2) ^ ((row & 7) << 4));
        *(uint2*)(&lds[byte]) = make_uint2(lo, hi);
    }
    __syncthreads();

    const int w = tid >> 6, lane = tid & 63;
    const int rl = lane & 15, g = lane >> 4;

    // ---- GEMM1: wave w covers col1 in [w*64, w*64+64)
    {
        f32x4 acc[4][4] = {};
#pragma unroll
        for (int ks = 0; ks < 4; ++ks) {
            bf16x8 a[4], b[4];
#pragma unroll
            for (int mt = 0; mt < 4; ++mt) {
                int m1 = w * 4 + mt;
                a[mt] = *(const bf16x8*)&w1f[(m1 * 4 + ks) * 64 + lane];
            }
#pragma unroll
            for (int nt = 0; nt < 4; ++nt) {
                int node = nt * 16 + rl;
                int byte = node * 256 + ((ks * 64 + g * 16) ^ ((node & 7) << 4));
                b[nt] = *(const bf16x8*)&lds[byte];
            }
#pragma unroll
            for (int mt = 0; mt < 4; ++mt)
#pragma unroll
                for (int nt = 0; nt < 4; ++nt)
                    acc[mt][nt] = __builtin_amdgcn_mfma_f32_16x16x32_bf16(
                        a[mt], b[nt], acc[mt][nt], 0, 0, 0);
        }
        // epilogue: +b1, relu, bf16-pack, ds_write into h1[node][col1]
#pragma unroll
        for (int mt = 0; mt < 4; ++mt) {
            int col1_0 = w * 64 + mt * 16 + g * 4;
            float bb0 = b1[col1_0], bb1 = b1[col1_0 + 1],
                  bb2 = b1[col1_0 + 2], bb3 = b1[col1_0 + 3];
#pragma unroll
            for (int nt = 0; nt < 4; ++nt) {
                int node = nt * 16 + rl;
                float v0 = fmaxf(acc[mt][nt][0] + bb0, 0.f);
                float v1 = fmaxf(acc[mt][nt][1] + bb1, 0.f);
                float v2 = fmaxf(acc[mt][nt][2] + bb2, 0.f);
                float v3 = fmaxf(acc[mt][nt][3] + bb3, 0.f);
                unsigned lo = pack_bf16x2(v0, v1), hi = pack_bf16x2(v2, v3);
                int byte = H1_OFF + node * 512 + ((col1_0 * 2) ^ ((node & 7) << 4));
                *(uint2*)(&lds[byte]) = make_uint2(lo, hi);
            }
        }
    }
    __syncthreads();

    // ---- GEMM2: wave w covers c2 in [w*32, w*32+32)
    {
        f32x4 acc[2][4] = {};
#pragma unroll
        for (int ks = 0; ks < 8; ++ks) {
            bf16x8 a[2], b[4];
#pragma unroll
            for (int mt = 0; mt < 2; ++mt) {
                int m2 = w * 2 + mt;
                a[mt] = *(const bf16x8*)&w2f[(m2 * 8 + ks) * 64 + lane];
            }
#pragma unroll
            for (int nt = 0; nt < 4; ++nt) {
                int node = nt * 16 + rl;
                int byte = H1_OFF + node * 512 + ((ks * 64 + g * 16) ^ ((node & 7) << 4));
                b[nt] = *(const bf16x8*)&lds[byte];
            }
#pragma unroll
            for (int mt = 0; mt < 2; ++mt)
#pragma unroll
                for (int nt = 0; nt < 4; ++nt)
                    acc[mt][nt] = __builtin_amdgcn_mfma_f32_16x16x32_bf16(
                        a[mt], b[nt], acc[mt][nt], 0, 0, 0);
        }
        // epilogue: +b2, relu, transposed global write out[b, c2, nn]
#pragma unroll
        for (int mt = 0; mt < 2; ++mt) {
            int c2_0 = w * 32 + mt * 16 + g * 4;
#pragma unroll
            for (int nt = 0; nt < 4; ++nt) {
                int node = node0 + nt * 16 + rl;
                if (node < NB) {
                    int bb = node / NPB;
                    int nn = node - bb * NPB;
                    size_t base = (size_t)(bb * DMODEL) * NPB + nn;
#pragma unroll
                    for (int r = 0; r < 4; ++r) {
                        float v = fmaxf(acc[mt][nt][r] + b2[c2_0 + r], 0.f);
                        out[base + (size_t)(c2_0 + r) * NPB] = v;
                    }
                }
            }
        }
    }
}

// -------------------------------------------------------------------------
extern "C" void kernel_launch(void* const* d_in, const int* in_sizes, int n_in,
                              void* d_out, int out_size, void* d_ws, size_t ws_size,
                              hipStream_t stream)
{
    const float* x     = (const float*)d_in[0];
    const int*   eidx  = (const int*)  d_in[1];
    const float* eattr = (const float*)d_in[2];
    const float* Wq    = (const float*)d_in[3];
    const float* bq    = (const float*)d_in[4];
    const float* Wk    = (const float*)d_in[5];
    const float* bk    = (const float*)d_in[6];
    const float* Wv    = (const float*)d_in[7];
    const float* bv    = (const float*)d_in[8];
    const float* We    = (const float*)d_in[9];
    const float* Wskip = (const float*)d_in[10];
    const float* bskip = (const float*)d_in[11];
    const float* W1    = (const float*)d_in[12];
    const float* b1    = (const float*)d_in[13];
    const float* W2    = (const float*)d_in[14];
    const float* b2    = (const float*)d_in[15];
    float* out = (float*)d_out;

    // ws layout: qb16|kb16|vb16|skipb16 (bf16) | agg (f32) | denom | w1f | w2f
    // = 25.6*4 + 51.2 + 1.6 + 0.13 MB ~= 155 MB  (well under the proven 219 MB)
    unsigned short* qb16    = (unsigned short*)d_ws;
    unsigned short* kb16    = qb16 + (size_t)NB * DMODEL;
    unsigned short* vb16    = kb16 + (size_t)NB * DMODEL;
    unsigned short* skipb16 = vb16 + (size_t)NB * DMODEL;
    float* agg   = (float*)(skipb16 + (size_t)NB * DMODEL);
    float* denom = agg + (size_t)NB * DMODEL;
    uint4* w1f   = (uint4*)(denom + (size_t)NB * 4);
    uint4* w2f   = w1f + 4096;

    dim3 pgrid((NB + 127) / 128, 4);
    k_proj_mfma<<<pgrid, 256, 0, stream>>>(x, Wq, bq, Wk, bk, Wv, bv,
                                           Wskip, bskip, qb16, kb16, vb16, skipb16,
                                           agg, denom);
    k_edge<<<T_E / 64, 256, 0, stream>>>(qb16, kb16, vb16, eidx, eattr, We, agg, denom);
    k_prep<<<32, 256, 0, stream>>>(W1, W2, w1f, w2f);
    k_ffn_mfma<<<(NB + 63) / 64, 256, 0, stream>>>(agg, denom, skipb16,
                                                   w1f, b1, w2f, b2, out);
}

// Round 6
// 575.131 us; speedup vs baseline: 1.4871x; 1.4871x over previous
//
#include <hip/hip_runtime.h>
#include <hip/hip_bf16.h>

// Problem constants (from reference)
#define NB      100000    // B*N nodes
#define NPB     25000     // N per batch
#define T_E     800000    // B*E total edges
#define EPG     200000    // E per graph
#define DMODEL  128       // OUT = H*DH
#define EDIM    32
#define FFD     256
#define SCAN_NBLK 98      // ceil(NB/1024)

typedef __attribute__((ext_vector_type(8))) short bf16x8;
typedef __attribute__((ext_vector_type(4))) float f32x4;

__device__ inline unsigned short f2bf(float f) {
    unsigned u = __float_as_uint(f);
    unsigned r = u + 0x7fffu + ((u >> 16) & 1u);   // RNE
    return (unsigned short)(r >> 16);
}
__device__ inline unsigned pack_bf16x2(float lo, float hi) {
    return (unsigned)f2bf(lo) | ((unsigned)f2bf(hi) << 16);
}
__device__ inline float bf_lo(unsigned p) { return __uint_as_float(p << 16); }
__device__ inline float bf_hi(unsigned p) { return __uint_as_float(p & 0xffff0000u); }

// -------------------------------------------------------------------------
// Kernel 1 (MFMA): node projections -> bf16 q/k/v/skip. blockIdx.y selects
// matrix (0=Q also zeroes CSR counts, 1=K, 2=V, 3=skip).
// -------------------------------------------------------------------------
#define XS_OFF 0
#define WT_OFF 32768

__global__ __launch_bounds__(256) void k_proj_mfma(
    const float* __restrict__ x,
    const float* __restrict__ Wq, const float* __restrict__ bq,
    const float* __restrict__ Wk, const float* __restrict__ bk,
    const float* __restrict__ Wv, const float* __restrict__ bv,
    const float* __restrict__ Wskip, const float* __restrict__ bskip,
    unsigned short* __restrict__ qb16, unsigned short* __restrict__ kb16,
    unsigned short* __restrict__ vb16, unsigned short* __restrict__ skipb16,
    int* __restrict__ counts)
{
    __shared__ __align__(16) char lds[65536];
    const int tid   = threadIdx.x;
    const int m     = blockIdx.y;
    const int node0 = blockIdx.x * 128;

    const float* W   = (m == 0) ? Wq : (m == 1) ? Wk : (m == 2) ? Wv : Wskip;
    const float* bi  = (m == 0) ? bq : (m == 1) ? bk : (m == 2) ? bv : bskip;
    unsigned short* outp = (m == 0) ? qb16 : (m == 1) ? kb16 : (m == 2) ? vb16 : skipb16;

    // ---- stage xs: x[b,c,nn] -> xs[node_local][c] (bf16, swizzled)
    {
        const int nl   = tid & 127;
        const int half = tid >> 7;
        const int node = node0 + nl;
        const bool valid = node < NB;
        int b  = node / NPB;
        int nn = node - b * NPB;
        const float* xbase = x + (size_t)b * DMODEL * NPB + nn;
#pragma unroll
        for (int o = 0; o < 8; ++o) {
            int c0 = (o * 2 + half) * 8;       // octet of 8 channels
            unsigned vals[4];
#pragma unroll
            for (int j2 = 0; j2 < 4; ++j2) {
                float f0 = valid ? xbase[(size_t)(c0 + 2 * j2) * NPB] : 0.f;
                float f1 = valid ? xbase[(size_t)(c0 + 2 * j2 + 1) * NPB] : 0.f;
                vals[j2] = pack_bf16x2(f0, f1);
            }
            int byte = nl * 256 + ((c0 * 2) ^ ((nl & 7) << 4));
            *(uint4*)(&lds[XS_OFF + byte]) = make_uint4(vals[0], vals[1], vals[2], vals[3]);
        }
    }
    // ---- stage wt: W[c,col] -> wt[col][c] (bf16, swizzled)
    {
        const int col  = tid & 127;
        const int half = tid >> 7;
#pragma unroll
        for (int o = 0; o < 8; ++o) {
            int c0 = (o * 2 + half) * 8;
            unsigned vals[4];
#pragma unroll
            for (int j2 = 0; j2 < 4; ++j2) {
                float f0 = W[(size_t)(c0 + 2 * j2) * DMODEL + col];
                float f1 = W[(size_t)(c0 + 2 * j2 + 1) * DMODEL + col];
                vals[j2] = pack_bf16x2(f0, f1);
            }
            int byte = col * 256 + ((c0 * 2) ^ ((col & 7) << 4));
            *(uint4*)(&lds[WT_OFF + byte]) = make_uint4(vals[0], vals[1], vals[2], vals[3]);
        }
    }
    // zero CSR counts (only the m==0 grid slice; one count per node)
    if (m == 0 && tid < 128) {
        int node = node0 + tid;
        if (node < NB) counts[node] = 0;
    }
    __syncthreads();

    // ---- MFMA: wave w computes nodes [w*32, w*32+32) x all 128 cols
    const int w    = tid >> 6;
    const int lane = tid & 63;
    const int rl   = lane & 15;
    const int g    = lane >> 4;

    f32x4 acc[2][8] = {};
#pragma unroll
    for (int ks = 0; ks < 4; ++ks) {
        const int kb2 = ks * 64 + g * 16;
        bf16x8 a[2], b[8];
#pragma unroll
        for (int mt = 0; mt < 2; ++mt) {
            int row = w * 32 + mt * 16 + rl;
            a[mt] = *(const bf16x8*)(&lds[XS_OFF + row * 256 + (kb2 ^ ((row & 7) << 4))]);
        }
#pragma unroll
        for (int nt = 0; nt < 8; ++nt) {
            int colr = nt * 16 + rl;
            b[nt] = *(const bf16x8*)(&lds[WT_OFF + colr * 256 + (kb2 ^ ((colr & 7) << 4))]);
        }
#pragma unroll
        for (int mt = 0; mt < 2; ++mt)
#pragma unroll
            for (int nt = 0; nt < 8; ++nt)
                acc[mt][nt] = __builtin_amdgcn_mfma_f32_16x16x32_bf16(
                    a[mt], b[nt], acc[mt][nt], 0, 0, 0);
    }

    // ---- epilogue: D col = lane&15, row = (lane>>4)*4 + r  -> bf16 stores
#pragma unroll
    for (int mt = 0; mt < 2; ++mt) {
        int nodeb = node0 + w * 32 + mt * 16 + g * 4;
#pragma unroll
        for (int nt = 0; nt < 8; ++nt) {
            int col = nt * 16 + rl;
            float bv_ = bi[col];
#pragma unroll
            for (int r = 0; r < 4; ++r) {
                int node = nodeb + r;
                if (node < NB)
                    outp[(size_t)node * DMODEL + col] = f2bf(acc[mt][nt][r] + bv_);
            }
        }
    }
}

// -------------------------------------------------------------------------
// CSR build: histogram -> scan (3 kernels) -> scatter.
// -------------------------------------------------------------------------
__global__ __launch_bounds__(256) void k_hist(
    const int* __restrict__ eidx, int* __restrict__ counts)
{
    int t = blockIdx.x * 256 + threadIdx.x;
    if (t < T_E) {
        int b = t / EPG, e = t - b * EPG;
        int dst = eidx[(size_t)(b * 2 + 1) * EPG + e];
        atomicAdd(&counts[dst], 1);
    }
}

__global__ __launch_bounds__(1024) void k_scan1(
    const int* __restrict__ counts, int* __restrict__ row_start,
    int* __restrict__ bsum)
{
    __shared__ int s[1024];
    const int tid = threadIdx.x;
    const int gid = blockIdx.x * 1024 + tid;
    int v = (gid < NB) ? counts[gid] : 0;
    s[tid] = v;
    __syncthreads();
#pragma unroll
    for (int off = 1; off < 1024; off <<= 1) {
        int tv = (tid >= off) ? s[tid - off] : 0;
        __syncthreads();
        s[tid] += tv;
        __syncthreads();
    }
    int incl = s[tid];
    if (gid < NB) row_start[gid] = incl - v;     // exclusive within block
    if (tid == 1023) bsum[blockIdx.x] = incl;    // block total
}

__global__ __launch_bounds__(128) void k_scan2(int* __restrict__ bsum)
{
    __shared__ int s[128];
    const int tid = threadIdx.x;
    int v = (tid < SCAN_NBLK) ? bsum[tid] : 0;
    s[tid] = v;
    __syncthreads();
#pragma unroll
    for (int off = 1; off < 128; off <<= 1) {
        int tv = (tid >= off) ? s[tid - off] : 0;
        __syncthreads();
        s[tid] += tv;
        __syncthreads();
    }
    if (tid < SCAN_NBLK) bsum[tid] = s[tid] - v;  // exclusive
}

__global__ __launch_bounds__(1024) void k_scan3(
    int* __restrict__ row_start, const int* __restrict__ bsum,
    int* __restrict__ cursor)
{
    const int gid = blockIdx.x * 1024 + threadIdx.x;
    if (gid < NB) {
        int v = row_start[gid] + bsum[blockIdx.x];
        row_start[gid] = v;
        cursor[gid] = v;
    }
}

__global__ __launch_bounds__(256) void k_scatter(
    const int* __restrict__ eidx, int* __restrict__ cursor,
    int* __restrict__ elist)
{
    int t = blockIdx.x * 256 + threadIdx.x;
    if (t < T_E) {
        int b = t / EPG, e = t - b * EPG;
        int dst = eidx[(size_t)(b * 2 + 1) * EPG + e];
        int pos = atomicAdd(&cursor[dst], 1);
        elist[pos] = t;                 // after kernel: cursor[d] == row_end[d]
    }
}

// -------------------------------------------------------------------------
// Kernel: per-node gather-aggregate (NO atomics). 1 wave = 1 node, lane l
// owns channels 2l,2l+1. Single pass: acc += ea*(v[src]+e), den += ea;
// write acc/(den+1e-16). eattr row broadcast via wave-private LDS.
// -------------------------------------------------------------------------
__global__ __launch_bounds__(256) void k_aggr_csr(
    const unsigned short* __restrict__ qb16,
    const unsigned short* __restrict__ kb16,
    const unsigned short* __restrict__ vb16,
    const int* __restrict__ eidx, const float* __restrict__ eattr,
    const float* __restrict__ We,
    const int* __restrict__ row_start, const int* __restrict__ row_end,
    const int* __restrict__ elist,
    float* __restrict__ agg)
{
    __shared__ float ea_s[4][32];      // wave-private eattr row
    const int tid = threadIdx.x;
    const int w = tid >> 6, l = tid & 63;

    // per-lane We columns 2l, 2l+1 (64 VGPRs), amortized via grid-stride
    float wer0[32], wer1[32];
#pragma unroll
    for (int k = 0; k < EDIM; ++k) {
        wer0[k] = We[k * DMODEL + 2 * l];
        wer1[k] = We[k * DMODEL + 2 * l + 1];
    }

    const int nwaves = gridDim.x * 4;
    for (int node = blockIdx.x * 4 + w; node < NB; node += nwaves) {
        const int rs = row_start[node];
        const int re = row_end[node];
        unsigned qp = *(const unsigned*)&qb16[(size_t)node * DMODEL + 2 * l];
        const float q0 = bf_lo(qp), q1 = bf_hi(qp);
        float acc0 = 0.f, acc1 = 0.f, den = 0.f;

        for (int j = rs; j < re; ++j) {
            const int eid = elist[j];                    // wave-uniform
            const int b = eid / EPG;
            const int e = eid - b * EPG;
            const int src = eidx[(size_t)(b * 2) * EPG + e];
            // stage this edge's eattr row into wave-private LDS (broadcast src)
            ea_s[w][l & 31] = eattr[(size_t)eid * EDIM + (l & 31)];
            unsigned kp = *(const unsigned*)&kb16[(size_t)src * DMODEL + 2 * l];
            unsigned vp = *(const unsigned*)&vb16[(size_t)src * DMODEL + 2 * l];
            // e-projection for channels 2l, 2l+1 (LDS reads are broadcasts)
            float e0 = 0.f, e1 = 0.f;
            const float4* er = (const float4*)ea_s[w];
#pragma unroll
            for (int k4 = 0; k4 < 8; ++k4) {
                float4 ev = er[k4];
                e0 += ev.x * wer0[4 * k4 + 0] + ev.y * wer0[4 * k4 + 1]
                    + ev.z * wer0[4 * k4 + 2] + ev.w * wer0[4 * k4 + 3];
                e1 += ev.x * wer1[4 * k4 + 0] + ev.y * wer1[4 * k4 + 1]
                    + ev.z * wer1[4 * k4 + 2] + ev.w * wer1[4 * k4 + 3];
            }
            float p = q0 * (bf_lo(kp) + e0) + q1 * (bf_hi(kp) + e1);
            // reduce over the 16 lanes of this head (head = l>>4)
#pragma unroll
            for (int off = 8; off >= 1; off >>= 1) p += __shfl_xor(p, off, 64);
            float ea = __expf(p * 0.17677669529663689f);   // 1/sqrt(32)
            acc0 += ea * (bf_lo(vp) + e0);
            acc1 += ea * (bf_hi(vp) + e1);
            den  += ea;
        }
        float r = 1.0f / (den + 1e-16f);
        *(float2*)&agg[(size_t)node * DMODEL + 2 * l] = make_float2(acc0 * r, acc1 * r);
    }
}

// -------------------------------------------------------------------------
// Kernel: pre-pack W1^T and W2^T into MFMA A-fragment layout (bf16).
// -------------------------------------------------------------------------
__global__ __launch_bounds__(256) void k_prep(
    const float* __restrict__ W1, const float* __restrict__ W2,
    uint4* __restrict__ w1f, uint4* __restrict__ w2f)
{
    int t = blockIdx.x * 256 + threadIdx.x;   // 0..8191
    int lane = t & 63;
    int frag = t >> 6;                         // 0..127
    int rl = lane & 15, g = lane >> 4;
    unsigned v[4];
    if (frag < 64) {
        int m1 = frag >> 2, ks = frag & 3;
        int col1 = m1 * 16 + rl;
        int k0 = ks * 32 + g * 8;
#pragma unroll
        for (int j2 = 0; j2 < 4; ++j2) {
            float f0 = W1[(k0 + 2 * j2) * FFD + col1];
            float f1 = W1[(k0 + 2 * j2 + 1) * FFD + col1];
            v[j2] = pack_bf16x2(f0, f1);
        }
        w1f[frag * 64 + lane] = make_uint4(v[0], v[1], v[2], v[3]);
    } else {
        int f2 = frag - 64;
        int m2 = f2 >> 3, ks = f2 & 7;
        int c2 = m2 * 16 + rl;
        int k0 = ks * 32 + g * 8;
#pragma unroll
        for (int j2 = 0; j2 < 4; ++j2) {
            float f0 = W2[(k0 + 2 * j2) * DMODEL + c2];
            float f1 = W2[(k0 + 2 * j2 + 1) * DMODEL + c2];
            v[j2] = pack_bf16x2(f0, f1);
        }
        w2f[f2 * 64 + lane] = make_uint4(v[0], v[1], v[2], v[3]);
    }
}

// -------------------------------------------------------------------------
// Kernel (MFMA): skip-add + FFN + transposed output write.
// xs = agg (already normalized) + skip, staged bf16 swizzled; 2 GEMMs.
// -------------------------------------------------------------------------
#define H1_OFF 16384

__global__ __launch_bounds__(256) void k_ffn_mfma(
    const float* __restrict__ agg,
    const unsigned short* __restrict__ skipb16,
    const uint4* __restrict__ w1f, const float* __restrict__ b1,
    const uint4* __restrict__ w2f, const float* __restrict__ b2,
    float* __restrict__ out)
{
    __shared__ __align__(16) char lds[49152];
    const int tid   = threadIdx.x;
    const int node0 = blockIdx.x * 64;

    // ---- stage xs[row][c] = agg + skip   (bf16 swizzled)
#pragma unroll
    for (int i = 0; i < 8; ++i) {
        int linear = i * 256 + tid;            // 0..2047
        int row = linear >> 5;                 // 0..63
        int c4  = (linear & 31) * 4;
        int node = node0 + row;
        float v0 = 0.f, v1 = 0.f, v2 = 0.f, v3 = 0.f;
        if (node < NB) {
            float4 f = *(const float4*)&agg[(size_t)node * DMODEL + c4];
            uint2 sp = *(const uint2*)&skipb16[(size_t)node * DMODEL + c4];
            v0 = f.x + bf_lo(sp.x);
            v1 = f.y + bf_hi(sp.x);
            v2 = f.z + bf_lo(sp.y);
            v3 = f.w + bf_hi(sp.y);
        }
        unsigned lo = pack_bf16x2(v0, v1), hi = pack_bf16x2(v2, v3);
        int byte = row * 256 + ((c4 * 2) ^ ((row & 7) << 4));
        *(uint2*)(&lds[byte]) = make_uint2(lo, hi);
    }
    __syncthreads();

    const int w = tid >> 6, lane = tid & 63;
    const int rl = lane & 15, g = lane >> 4;

    // ---- GEMM1: wave w covers col1 in [w*64, w*64+64)
    {
        f32x4 acc[4][4] = {};
#pragma unroll
        for (int ks = 0; ks < 4; ++ks) {
            bf16x8 a[4], b[4];
#pragma unroll
            for (int mt = 0; mt < 4; ++mt) {
                int m1 = w * 4 + mt;
                a[mt] = *(const bf16x8*)&w1f[(m1 * 4 + ks) * 64 + lane];
            }
#pragma unroll
            for (int nt = 0; nt < 4; ++nt) {
                int node = nt * 16 + rl;
                int byte = node * 256 + ((ks * 64 + g * 16) ^ ((node & 7) << 4));
                b[nt] = *(const bf16x8*)&lds[byte];
            }
#pragma unroll
            for (int mt = 0; mt < 4; ++mt)
#pragma unroll
                for (int nt = 0; nt < 4; ++nt)
                    acc[mt][nt] = __builtin_amdgcn_mfma_f32_16x16x32_bf16(
                        a[mt], b[nt], acc[mt][nt], 0, 0, 0);
        }
#pragma unroll
        for (int mt = 0; mt < 4; ++mt) {
            int col1_0 = w * 64 + mt * 16 + g * 4;
            float bb0 = b1[col1_0], bb1 = b1[col1_0 + 1],
                  bb2 = b1[col1_0 + 2], bb3 = b1[col1_0 + 3];
#pragma unroll
            for (int nt = 0; nt < 4; ++nt) {
                int node = nt * 16 + rl;
                float v0 = fmaxf(acc[mt][nt][0] + bb0, 0.f);
                float v1 = fmaxf(acc[mt][nt][1] + bb1, 0.f);
                float v2 = fmaxf(acc[mt][nt][2] + bb2, 0.f);
                float v3 = fmaxf(acc[mt][nt][3] + bb3, 0.f);
                unsigned lo = pack_bf16x2(v0, v1), hi = pack_bf16x2(v2, v3);
                int byte = H1_OFF + node * 512 + ((col1_0 * 2) ^ ((node & 7) << 4));
                *(uint2*)(&lds[byte]) = make_uint2(lo, hi);
            }
        }
    }
    __syncthreads();

    // ---- GEMM2: wave w covers c2 in [w*32, w*32+32)
    {
        f32x4 acc[2][4] = {};
#pragma unroll
        for (int ks = 0; ks < 8; ++ks) {
            bf16x8 a[2], b[4];
#pragma unroll
            for (int mt = 0; mt < 2; ++mt) {
                int m2 = w * 2 + mt;
                a[mt] = *(const bf16x8*)&w2f[(m2 * 8 + ks) * 64 + lane];
            }
#pragma unroll
            for (int nt = 0; nt < 4; ++nt) {
                int node = nt * 16 + rl;
                int byte = H1_OFF + node * 512 + ((ks * 64 + g * 16) ^ ((node & 7) << 4));
                b[nt] = *(const bf16x8*)&lds[byte];
            }
#pragma unroll
            for (int mt = 0; mt < 2; ++mt)
#pragma unroll
                for (int nt = 0; nt < 4; ++nt)
                    acc[mt][nt] = __builtin_amdgcn_mfma_f32_16x16x32_bf16(
                        a[mt], b[nt], acc[mt][nt], 0, 0, 0);
        }
#pragma unroll
        for (int mt = 0; mt < 2; ++mt) {
            int c2_0 = w * 32 + mt * 16 + g * 4;
#pragma unroll
            for (int nt = 0; nt < 4; ++nt) {
                int node = node0 + nt * 16 + rl;
                if (node < NB) {
                    int bb = node / NPB;
                    int nn = node - bb * NPB;
                    size_t base = (size_t)(bb * DMODEL) * NPB + nn;
#pragma unroll
                    for (int r = 0; r < 4; ++r) {
                        float v = fmaxf(acc[mt][nt][r] + b2[c2_0 + r], 0.f);
                        out[base + (size_t)(c2_0 + r) * NPB] = v;
                    }
                }
            }
        }
    }
}

// -------------------------------------------------------------------------
extern "C" void kernel_launch(void* const* d_in, const int* in_sizes, int n_in,
                              void* d_out, int out_size, void* d_ws, size_t ws_size,
                              hipStream_t stream)
{
    const float* x     = (const float*)d_in[0];
    const int*   eidx  = (const int*)  d_in[1];
    const float* eattr = (const float*)d_in[2];
    const float* Wq    = (const float*)d_in[3];
    const float* bq    = (const float*)d_in[4];
    const float* Wk    = (const float*)d_in[5];
    const float* bk    = (const float*)d_in[6];
    const float* Wv    = (const float*)d_in[7];
    const float* bv    = (const float*)d_in[8];
    const float* We    = (const float*)d_in[9];
    const float* Wskip = (const float*)d_in[10];
    const float* bskip = (const float*)d_in[11];
    const float* W1    = (const float*)d_in[12];
    const float* b1    = (const float*)d_in[13];
    const float* W2    = (const float*)d_in[14];
    const float* b2    = (const float*)d_in[15];
    float* out = (float*)d_out;

    // ws layout (~159 MB, proven budget 219 MB):
    // qb16|kb16|vb16|skipb16 (bf16) | agg f32 | w1f | w2f | counts | row_start
    // | cursor | elist | bsum
    const size_t NBD = (size_t)NB * DMODEL;
    unsigned short* qb16    = (unsigned short*)d_ws;
    unsigned short* kb16    = qb16 + NBD;
    unsigned short* vb16    = kb16 + NBD;
    unsigned short* skipb16 = vb16 + NBD;
    float* agg    = (float*)(skipb16 + NBD);
    uint4* w1f    = (uint4*)(agg + NBD);
    uint4* w2f    = w1f + 4096;
    int* counts    = (int*)(w2f + 4096);
    int* row_start = counts + NB;
    int* cursor    = row_start + NB;
    int* elist     = cursor + NB;
    int* bsum      = elist + T_E;

    dim3 pgrid((NB + 127) / 128, 4);
    k_proj_mfma<<<pgrid, 256, 0, stream>>>(x, Wq, bq, Wk, bk, Wv, bv,
                                           Wskip, bskip, qb16, kb16, vb16, skipb16,
                                           counts);
    k_hist<<<(T_E + 255) / 256, 256, 0, stream>>>(eidx, counts);
    k_scan1<<<SCAN_NBLK, 1024, 0, stream>>>(counts, row_start, bsum);
    k_scan2<<<1, 128, 0, stream>>>(bsum);
    k_scan3<<<SCAN_NBLK, 1024, 0, stream>>>(row_start, bsum, cursor);
    k_scatter<<<(T_E + 255) / 256, 256, 0, stream>>>(eidx, cursor, elist);
    k_aggr_csr<<<2048, 256, 0, stream>>>(qb16, kb16, vb16, eidx, eattr, We,
                                         row_start, cursor, elist, agg);
    k_prep<<<32, 256, 0, stream>>>(W1, W2, w1f, w2f);
    k_ffn_mfma<<<(NB + 63) / 64, 256, 0, stream>>>(agg, skipb16,
                                                   w1f, b1, w2f, b2, out);
}

// Round 7
// 416.450 us; speedup vs baseline: 2.0538x; 1.3810x over previous
//
#include <hip/hip_runtime.h>
#include <hip/hip_bf16.h>

// Problem constants (from reference)
#define NB      100000    // B*N nodes
#define NPB     25000     // N per batch
#define T_E     800000    // B*E total edges
#define EPG     200000    // E per graph
#define DMODEL  128       // OUT = H*DH
#define EDIM    32
#define FFD     256
#define SCAN_NBLK 98      // ceil(NB/1024)

typedef __attribute__((ext_vector_type(8))) short bf16x8;
typedef __attribute__((ext_vector_type(4))) float f32x4;
typedef __attribute__((ext_vector_type(2))) float f32x2;

__device__ inline unsigned short f2bf(float f) {
    unsigned u = __float_as_uint(f);
    unsigned r = u + 0x7fffu + ((u >> 16) & 1u);   // RNE
    return (unsigned short)(r >> 16);
}
__device__ inline unsigned pack_bf16x2(float lo, float hi) {
    return (unsigned)f2bf(lo) | ((unsigned)f2bf(hi) << 16);
}
__device__ inline float bf_lo(unsigned p) { return __uint_as_float(p << 16); }
__device__ inline float bf_hi(unsigned p) { return __uint_as_float(p & 0xffff0000u); }

// -------------------------------------------------------------------------
// Kernel 1 (MFMA): node projections -> bf16 q/k/v/skip. blockIdx.y selects
// matrix (0=Q also zeroes CSR counts, 1=K, 2=V, 3=skip).
// -------------------------------------------------------------------------
#define XS_OFF 0
#define WT_OFF 32768

__global__ __launch_bounds__(256) void k_proj_mfma(
    const float* __restrict__ x,
    const float* __restrict__ Wq, const float* __restrict__ bq,
    const float* __restrict__ Wk, const float* __restrict__ bk,
    const float* __restrict__ Wv, const float* __restrict__ bv,
    const float* __restrict__ Wskip, const float* __restrict__ bskip,
    unsigned short* __restrict__ qb16, unsigned short* __restrict__ kb16,
    unsigned short* __restrict__ vb16, unsigned short* __restrict__ skipb16,
    int* __restrict__ counts)
{
    __shared__ __align__(16) char lds[65536];
    const int tid   = threadIdx.x;
    const int m     = blockIdx.y;
    const int node0 = blockIdx.x * 128;

    const float* W   = (m == 0) ? Wq : (m == 1) ? Wk : (m == 2) ? Wv : Wskip;
    const float* bi  = (m == 0) ? bq : (m == 1) ? bk : (m == 2) ? bv : bskip;
    unsigned short* outp = (m == 0) ? qb16 : (m == 1) ? kb16 : (m == 2) ? vb16 : skipb16;

    // ---- stage xs: x[b,c,nn] -> xs[node_local][c] (bf16, swizzled)
    {
        const int nl   = tid & 127;
        const int half = tid >> 7;
        const int node = node0 + nl;
        const bool valid = node < NB;
        int b  = node / NPB;
        int nn = node - b * NPB;
        const float* xbase = x + (size_t)b * DMODEL * NPB + nn;
#pragma unroll
        for (int o = 0; o < 8; ++o) {
            int c0 = (o * 2 + half) * 8;       // octet of 8 channels
            unsigned vals[4];
#pragma unroll
            for (int j2 = 0; j2 < 4; ++j2) {
                float f0 = valid ? xbase[(size_t)(c0 + 2 * j2) * NPB] : 0.f;
                float f1 = valid ? xbase[(size_t)(c0 + 2 * j2 + 1) * NPB] : 0.f;
                vals[j2] = pack_bf16x2(f0, f1);
            }
            int byte = nl * 256 + ((c0 * 2) ^ ((nl & 7) << 4));
            *(uint4*)(&lds[XS_OFF + byte]) = make_uint4(vals[0], vals[1], vals[2], vals[3]);
        }
    }
    // ---- stage wt: W[c,col] -> wt[col][c] (bf16, swizzled)
    {
        const int col  = tid & 127;
        const int half = tid >> 7;
#pragma unroll
        for (int o = 0; o < 8; ++o) {
            int c0 = (o * 2 + half) * 8;
            unsigned vals[4];
#pragma unroll
            for (int j2 = 0; j2 < 4; ++j2) {
                float f0 = W[(size_t)(c0 + 2 * j2) * DMODEL + col];
                float f1 = W[(size_t)(c0 + 2 * j2 + 1) * DMODEL + col];
                vals[j2] = pack_bf16x2(f0, f1);
            }
            int byte = col * 256 + ((c0 * 2) ^ ((col & 7) << 4));
            *(uint4*)(&lds[WT_OFF + byte]) = make_uint4(vals[0], vals[1], vals[2], vals[3]);
        }
    }
    // zero CSR counts (only the m==0 grid slice; one count per node)
    if (m == 0 && tid < 128) {
        int node = node0 + tid;
        if (node < NB) counts[node] = 0;
    }
    __syncthreads();

    // ---- MFMA: wave w computes nodes [w*32, w*32+32) x all 128 cols
    const int w    = tid >> 6;
    const int lane = tid & 63;
    const int rl   = lane & 15;
    const int g    = lane >> 4;

    f32x4 acc[2][8] = {};
#pragma unroll
    for (int ks = 0; ks < 4; ++ks) {
        const int kb2 = ks * 64 + g * 16;
        bf16x8 a[2], b[8];
#pragma unroll
        for (int mt = 0; mt < 2; ++mt) {
            int row = w * 32 + mt * 16 + rl;
            a[mt] = *(const bf16x8*)(&lds[XS_OFF + row * 256 + (kb2 ^ ((row & 7) << 4))]);
        }
#pragma unroll
        for (int nt = 0; nt < 8; ++nt) {
            int colr = nt * 16 + rl;
            b[nt] = *(const bf16x8*)(&lds[WT_OFF + colr * 256 + (kb2 ^ ((colr & 7) << 4))]);
        }
#pragma unroll
        for (int mt = 0; mt < 2; ++mt)
#pragma unroll
            for (int nt = 0; nt < 8; ++nt)
                acc[mt][nt] = __builtin_amdgcn_mfma_f32_16x16x32_bf16(
                    a[mt], b[nt], acc[mt][nt], 0, 0, 0);
    }

    // ---- epilogue: D col = lane&15, row = (lane>>4)*4 + r  -> bf16 stores
#pragma unroll
    for (int mt = 0; mt < 2; ++mt) {
        int nodeb = node0 + w * 32 + mt * 16 + g * 4;
#pragma unroll
        for (int nt = 0; nt < 8; ++nt) {
            int col = nt * 16 + rl;
            float bv_ = bi[col];
#pragma unroll
            for (int r = 0; r < 4; ++r) {
                int node = nodeb + r;
                if (node < NB)
                    outp[(size_t)node * DMODEL + col] = f2bf(acc[mt][nt][r] + bv_);
            }
        }
    }
}

// -------------------------------------------------------------------------
// CSR build: histogram -> scan (3 kernels) -> scatter (stores (src,eid)).
// -------------------------------------------------------------------------
__global__ __launch_bounds__(256) void k_hist(
    const int* __restrict__ eidx, int* __restrict__ counts)
{
    int t = blockIdx.x * 256 + threadIdx.x;
    if (t < T_E) {
        int b = t / EPG, e = t - b * EPG;
        int dst = eidx[(size_t)(b * 2 + 1) * EPG + e];
        atomicAdd(&counts[dst], 1);
    }
}

__global__ __launch_bounds__(1024) void k_scan1(
    const int* __restrict__ counts, int* __restrict__ row_start,
    int* __restrict__ bsum)
{
    __shared__ int s[1024];
    const int tid = threadIdx.x;
    const int gid = blockIdx.x * 1024 + tid;
    int v = (gid < NB) ? counts[gid] : 0;
    s[tid] = v;
    __syncthreads();
#pragma unroll
    for (int off = 1; off < 1024; off <<= 1) {
        int tv = (tid >= off) ? s[tid - off] : 0;
        __syncthreads();
        s[tid] += tv;
        __syncthreads();
    }
    int incl = s[tid];
    if (gid < NB) row_start[gid] = incl - v;
    if (tid == 1023) bsum[blockIdx.x] = incl;
}

__global__ __launch_bounds__(128) void k_scan2(int* __restrict__ bsum)
{
    __shared__ int s[128];
    const int tid = threadIdx.x;
    int v = (tid < SCAN_NBLK) ? bsum[tid] : 0;
    s[tid] = v;
    __syncthreads();
#pragma unroll
    for (int off = 1; off < 128; off <<= 1) {
        int tv = (tid >= off) ? s[tid - off] : 0;
        __syncthreads();
        s[tid] += tv;
        __syncthreads();
    }
    if (tid < SCAN_NBLK) bsum[tid] = s[tid] - v;
}

__global__ __launch_bounds__(1024) void k_scan3(
    int* __restrict__ row_start, const int* __restrict__ bsum,
    int* __restrict__ cursor)
{
    const int gid = blockIdx.x * 1024 + threadIdx.x;
    if (gid < NB) {
        int v = row_start[gid] + bsum[blockIdx.x];
        row_start[gid] = v;
        cursor[gid] = v;
    }
}

__global__ __launch_bounds__(256) void k_scatter(
    const int* __restrict__ eidx, int* __restrict__ cursor,
    int2* __restrict__ elist2)
{
    int t = blockIdx.x * 256 + threadIdx.x;
    if (t < T_E) {
        int b = t / EPG, e = t - b * EPG;
        int dst = eidx[(size_t)(b * 2 + 1) * EPG + e];
        int src = eidx[(size_t)(b * 2) * EPG + e];
        int pos = atomicAdd(&cursor[dst], 1);
        elist2[pos] = make_int2(src, t);   // after: cursor[d] == row_end[d]
    }
}

// -------------------------------------------------------------------------
// Kernel: pre-pack W1^T, W2^T, We^T into MFMA A-fragment layout (bf16).
// frags 0..63 -> w1f, 64..127 -> w2f, 128..135 -> wef.
// -------------------------------------------------------------------------
__global__ __launch_bounds__(256) void k_prep(
    const float* __restrict__ W1, const float* __restrict__ W2,
    const float* __restrict__ We,
    uint4* __restrict__ w1f, uint4* __restrict__ w2f, uint4* __restrict__ wef)
{
    int t = blockIdx.x * 256 + threadIdx.x;   // 0..8703
    int lane = t & 63;
    int frag = t >> 6;                         // 0..135
    if (frag >= 136) return;
    int rl = lane & 15, g = lane >> 4;
    unsigned v[4];
    if (frag < 64) {
        int m1 = frag >> 2, ks = frag & 3;
        int col1 = m1 * 16 + rl;
        int k0 = ks * 32 + g * 8;
#pragma unroll
        for (int j2 = 0; j2 < 4; ++j2) {
            float f0 = W1[(k0 + 2 * j2) * FFD + col1];
            float f1 = W1[(k0 + 2 * j2 + 1) * FFD + col1];
            v[j2] = pack_bf16x2(f0, f1);
        }
        w1f[frag * 64 + lane] = make_uint4(v[0], v[1], v[2], v[3]);
    } else if (frag < 128) {
        int f2 = frag - 64;
        int m2 = f2 >> 3, ks = f2 & 7;
        int c2 = m2 * 16 + rl;
        int k0 = ks * 32 + g * 8;
#pragma unroll
        for (int j2 = 0; j2 < 4; ++j2) {
            float f0 = W2[(k0 + 2 * j2) * DMODEL + c2];
            float f1 = W2[(k0 + 2 * j2 + 1) * DMODEL + c2];
            v[j2] = pack_bf16x2(f0, f1);
        }
        w2f[f2 * 64 + lane] = make_uint4(v[0], v[1], v[2], v[3]);
    } else {
        // wef: A-frag of We^T  (rows = output cols, k = edge-attr dim 0..31)
        int m = frag - 128;                    // 0..7
        int ocol = m * 16 + rl;
        int k0 = g * 8;
#pragma unroll
        for (int j2 = 0; j2 < 4; ++j2) {
            float f0 = We[(k0 + 2 * j2) * DMODEL + ocol];
            float f1 = We[(k0 + 2 * j2 + 1) * DMODEL + ocol];
            v[j2] = pack_bf16x2(f0, f1);
        }
        wef[m * 64 + lane] = make_uint4(v[0], v[1], v[2], v[3]);
    }
}

// -------------------------------------------------------------------------
// Kernel: e-projection, edge-parallel MFMA.  eb[eid][128] fp8 e4m3.
// Per wave-iter: one 16-edge tile; D[ocol][edge] = We^T @ eattr^T (swapped).
// -------------------------------------------------------------------------
__global__ __launch_bounds__(256) void k_eproj(
    const float* __restrict__ eattr, const uint4* __restrict__ wef,
    unsigned char* __restrict__ eb)
{
    const int tid = threadIdx.x;
    const int w = tid >> 6, lane = tid & 63;
    const int rl = lane & 15, g = lane >> 4;

    bf16x8 a[8];
#pragma unroll
    for (int m = 0; m < 8; ++m) a[m] = *(const bf16x8*)&wef[m * 64 + lane];

    const int nwaves = gridDim.x * 4;
    for (int tile = blockIdx.x * 4 + w; tile < T_E / 16; tile += nwaves) {
        const float* ep = &eattr[((size_t)tile * 16 + rl) * EDIM + g * 8];
        float4 f0 = *(const float4*)ep;
        float4 f1 = *(const float4*)(ep + 4);
        uint4 bu = make_uint4(pack_bf16x2(f0.x, f0.y), pack_bf16x2(f0.z, f0.w),
                              pack_bf16x2(f1.x, f1.y), pack_bf16x2(f1.z, f1.w));
        bf16x8 b = *(bf16x8*)&bu;
        f32x4 z = {0.f, 0.f, 0.f, 0.f};
        f32x4 acc[8];
#pragma unroll
        for (int m = 0; m < 8; ++m)
            acc[m] = __builtin_amdgcn_mfma_f32_16x16x32_bf16(a[m], b, z, 0, 0, 0);
        // D: col(lane&15)=edge rl, row(g*4+r)=ocol within m*16 block
        unsigned char* out = &eb[((size_t)tile * 16 + rl) * DMODEL + g * 4];
#pragma unroll
        for (int m = 0; m < 8; ++m) {
            unsigned d = __builtin_amdgcn_cvt_pk_fp8_f32(acc[m][0], acc[m][1], 0, false);
            d = __builtin_amdgcn_cvt_pk_fp8_f32(acc[m][2], acc[m][3], d, true);
            *(unsigned*)(out + m * 16) = d;
        }
    }
}

// -------------------------------------------------------------------------
// Kernel: per-node gather-aggregate, 2 edges per wave concurrently
// (half-waves), 4 channels per lane.  No atomics, no LDS, no We regs.
// Output: xs16[node][c] = agg_norm + skip (bf16)  — written into qb16 space.
// -------------------------------------------------------------------------
__global__ __launch_bounds__(256) void k_aggr2(
    unsigned short* qx,                       // q (read) / xs16 (write) — aliased
    const unsigned short* __restrict__ kb16,
    const unsigned short* __restrict__ vb16,
    const unsigned short* __restrict__ skipb16,
    const unsigned char* __restrict__ eb,
    const int2* __restrict__ elist2,
    const int* __restrict__ row_start, const int* __restrict__ row_end)
{
    const int tid  = threadIdx.x;
    const int w    = tid >> 6, l = tid & 63;
    const int half = l >> 5;                  // which edge of the pair
    const int li   = l & 31;
    const int c0   = li * 4;                  // this lane's 4 channels

    const int nwaves = gridDim.x * 4;
    for (int node = blockIdx.x * 4 + w; node < NB; node += nwaves) {
        const int rs = row_start[node];
        const int re = row_end[node];
        uint2 qp = *(const uint2*)&qx[(size_t)node * DMODEL + c0];
        const float q0 = bf_lo(qp.x), q1 = bf_hi(qp.x);
        const float q2 = bf_lo(qp.y), q3 = bf_hi(qp.y);
        float a0 = 0.f, a1 = 0.f, a2 = 0.f, a3 = 0.f, den = 0.f;

        for (int j0 = rs; j0 < re; j0 += 2) {
            const int jc = j0 + half;
            const bool act = jc < re;
            const int jj = act ? jc : re - 1;
            int2 se = elist2[jj];                       // (src, eid)
            uint2 kp = *(const uint2*)&kb16[(size_t)se.x * DMODEL + c0];
            uint2 vp = *(const uint2*)&vb16[(size_t)se.x * DMODEL + c0];
            unsigned ep8 = *(const unsigned*)&eb[(size_t)se.y * DMODEL + c0];
            f32x2 elo = __builtin_amdgcn_cvt_pk_f32_fp8(ep8, false);
            f32x2 ehi = __builtin_amdgcn_cvt_pk_f32_fp8(ep8, true);
            const float e0 = elo[0], e1 = elo[1], e2 = ehi[0], e3 = ehi[1];
            float p = q0 * (bf_lo(kp.x) + e0) + q1 * (bf_hi(kp.x) + e1)
                    + q2 * (bf_lo(kp.y) + e2) + q3 * (bf_hi(kp.y) + e3);
            // reduce over the 8 lanes of this head (32 ch / 4 ch-per-lane)
            p += __shfl_xor(p, 1, 64);
            p += __shfl_xor(p, 2, 64);
            p += __shfl_xor(p, 4, 64);
            float ea = act ? __expf(p * 0.17677669529663689f) : 0.f;
            a0 += ea * (bf_lo(vp.x) + e0);
            a1 += ea * (bf_hi(vp.x) + e1);
            a2 += ea * (bf_lo(vp.y) + e2);
            a3 += ea * (bf_hi(vp.y) + e3);
            den += ea;
        }
        // combine the two half-wave edge streams
        a0 += __shfl_xor(a0, 32, 64);
        a1 += __shfl_xor(a1, 32, 64);
        a2 += __shfl_xor(a2, 32, 64);
        a3 += __shfl_xor(a3, 32, 64);
        den += __shfl_xor(den, 32, 64);
        float r = 1.0f / (den + 1e-16f);
        if (half == 0) {
            uint2 sp = *(const uint2*)&skipb16[(size_t)node * DMODEL + c0];
            unsigned lo = pack_bf16x2(a0 * r + bf_lo(sp.x), a1 * r + bf_hi(sp.x));
            unsigned hi = pack_bf16x2(a2 * r + bf_lo(sp.y), a3 * r + bf_hi(sp.y));
            *(uint2*)&qx[(size_t)node * DMODEL + c0] = make_uint2(lo, hi);
        }
    }
}

// -------------------------------------------------------------------------
// Kernel (MFMA): FFN on xs16 (= agg_norm + skip, bf16) + transposed write.
// -------------------------------------------------------------------------
#define H1_OFF 16384

__global__ __launch_bounds__(256) void k_ffn_mfma(
    const unsigned short* __restrict__ xs16,
    const uint4* __restrict__ w1f, const float* __restrict__ b1,
    const uint4* __restrict__ w2f, const float* __restrict__ b2,
    float* __restrict__ out)
{
    __shared__ __align__(16) char lds[49152];
    const int tid   = threadIdx.x;
    const int node0 = blockIdx.x * 64;

    // ---- stage xs[row][c] bf16 swizzled (direct uint4 copies)
#pragma unroll
    for (int i = 0; i < 4; ++i) {
        int linear = i * 256 + tid;            // 0..1023
        int row = linear >> 4;                 // 0..63
        int c8  = (linear & 15) * 8;           // channel octet start
        int node = node0 + row;
        uint4 vv = (node < NB) ? *(const uint4*)&xs16[(size_t)node * DMODEL + c8]
                               : make_uint4(0, 0, 0, 0);
        int byte = row * 256 + ((c8 * 2) ^ ((row & 7) << 4));
        *(uint4*)(&lds[byte]) = vv;
    }
    __syncthreads();

    const int w = tid >> 6, lane = tid & 63;
    const int rl = lane & 15, g = lane >> 4;

    // ---- GEMM1: wave w covers col1 in [w*64, w*64+64)
    {
        f32x4 acc[4][4] = {};
#pragma unroll
        for (int ks = 0; ks < 4; ++ks) {
            bf16x8 a[4], b[4];
#pragma unroll
            for (int mt = 0; mt < 4; ++mt) {
                int m1 = w * 4 + mt;
                a[mt] = *(const bf16x8*)&w1f[(m1 * 4 + ks) * 64 + lane];
            }
#pragma unroll
            for (int nt = 0; nt < 4; ++nt) {
                int node = nt * 16 + rl;
                int byte = node * 256 + ((ks * 64 + g * 16) ^ ((node & 7) << 4));
                b[nt] = *(const bf16x8*)&lds[byte];
            }
#pragma unroll
            for (int mt = 0; mt < 4; ++mt)
#pragma unroll
                for (int nt = 0; nt < 4; ++nt)
                    acc[mt][nt] = __builtin_amdgcn_mfma_f32_16x16x32_bf16(
                        a[mt], b[nt], acc[mt][nt], 0, 0, 0);
        }
#pragma unroll
        for (int mt = 0; mt < 4; ++mt) {
            int col1_0 = w * 64 + mt * 16 + g * 4;
            float bb0 = b1[col1_0], bb1 = b1[col1_0 + 1],
                  bb2 = b1[col1_0 + 2], bb3 = b1[col1_0 + 3];
#pragma unroll
            for (int nt = 0; nt < 4; ++nt) {
                int node = nt * 16 + rl;
                float v0 = fmaxf(acc[mt][nt][0] + bb0, 0.f);
                float v1 = fmaxf(acc[mt][nt][1] + bb1, 0.f);
                float v2 = fmaxf(acc[mt][nt][2] + bb2, 0.f);
                float v3 = fmaxf(acc[mt][nt][3] + bb3, 0.f);
                unsigned lo = pack_bf16x2(v0, v1), hi = pack_bf16x2(v2, v3);
                int byte = H1_OFF + node * 512 + ((col1_0 * 2) ^ ((node & 7) << 4));
                *(uint2*)(&lds[byte]) = make_uint2(lo, hi);
            }
        }
    }
    __syncthreads();

    // ---- GEMM2: wave w covers c2 in [w*32, w*32+32)
    {
        f32x4 acc[2][4] = {};
#pragma unroll
        for (int ks = 0; ks < 8; ++ks) {
            bf16x8 a[2], b[4];
#pragma unroll
            for (int mt = 0; mt < 2; ++mt) {
                int m2 = w * 2 + mt;
                a[mt] = *(const bf16x8*)&w2f[(m2 * 8 + ks) * 64 + lane];
            }
#pragma unroll
            for (int nt = 0; nt < 4; ++nt) {
                int node = nt * 16 + rl;
                int byte = H1_OFF + node * 512 + ((ks * 64 + g * 16) ^ ((node & 7) << 4));
                b[nt] = *(const bf16x8*)&lds[byte];
            }
#pragma unroll
            for (int mt = 0; mt < 2; ++mt)
#pragma unroll
                for (int nt = 0; nt < 4; ++nt)
                    acc[mt][nt] = __builtin_amdgcn_mfma_f32_16x16x32_bf16(
                        a[mt], b[nt], acc[mt][nt], 0, 0, 0);
        }
#pragma unroll
        for (int mt = 0; mt < 2; ++mt) {
            int c2_0 = w * 32 + mt * 16 + g * 4;
#pragma unroll
            for (int nt = 0; nt < 4; ++nt) {
                int node = node0 + nt * 16 + rl;
                if (node < NB) {
                    int bb = node / NPB;
                    int nn = node - bb * NPB;
                    size_t base = (size_t)(bb * DMODEL) * NPB + nn;
#pragma unroll
                    for (int r = 0; r < 4; ++r) {
                        float v = fmaxf(acc[mt][nt][r] + b2[c2_0 + r], 0.f);
                        out[base + (size_t)(c2_0 + r) * NPB] = v;
                    }
                }
            }
        }
    }
}

// -------------------------------------------------------------------------
extern "C" void kernel_launch(void* const* d_in, const int* in_sizes, int n_in,
                              void* d_out, int out_size, void* d_ws, size_t ws_size,
                              hipStream_t stream)
{
    const float* x     = (const float*)d_in[0];
    const int*   eidx  = (const int*)  d_in[1];
    const float* eattr = (const float*)d_in[2];
    const float* Wq    = (const float*)d_in[3];
    const float* bq    = (const float*)d_in[4];
    const float* Wk    = (const float*)d_in[5];
    const float* bk    = (const float*)d_in[6];
    const float* Wv    = (const float*)d_in[7];
    const float* bv    = (const float*)d_in[8];
    const float* We    = (const float*)d_in[9];
    const float* Wskip = (const float*)d_in[10];
    const float* bskip = (const float*)d_in[11];
    const float* W1    = (const float*)d_in[12];
    const float* b1    = (const float*)d_in[13];
    const float* W2    = (const float*)d_in[14];
    const float* b2    = (const float*)d_in[15];
    float* out = (float*)d_out;

    // ws layout (~212.6 MB; proven budget >= 219 MB):
    // qb16(->xs16) | kb16 | vb16 | skipb16 | eb fp8 | frags | counts |
    // row_start | cursor | elist2 | bsum
    const size_t NBD = (size_t)NB * DMODEL;
    unsigned short* qb16    = (unsigned short*)d_ws;
    unsigned short* kb16    = qb16 + NBD;
    unsigned short* vb16    = kb16 + NBD;
    unsigned short* skipb16 = vb16 + NBD;
    unsigned char*  eb      = (unsigned char*)(skipb16 + NBD);
    uint4* w1f = (uint4*)(eb + (size_t)T_E * DMODEL);
    uint4* w2f = w1f + 64 * 64;
    uint4* wef = w2f + 64 * 64;
    int* counts    = (int*)(wef + 8 * 64);
    int* row_start = counts + NB;
    int* cursor    = row_start + NB;
    int2* elist2   = (int2*)(cursor + NB);
    int* bsum      = (int*)(elist2 + T_E);

    dim3 pgrid((NB + 127) / 128, 4);
    k_proj_mfma<<<pgrid, 256, 0, stream>>>(x, Wq, bq, Wk, bk, Wv, bv,
                                           Wskip, bskip, qb16, kb16, vb16, skipb16,
                                           counts);
    k_hist<<<(T_E + 255) / 256, 256, 0, stream>>>(eidx, counts);
    k_scan1<<<SCAN_NBLK, 1024, 0, stream>>>(counts, row_start, bsum);
    k_scan2<<<1, 128, 0, stream>>>(bsum);
    k_scan3<<<SCAN_NBLK, 1024, 0, stream>>>(row_start, bsum, cursor);
    k_scatter<<<(T_E + 255) / 256, 256, 0, stream>>>(eidx, cursor, elist2);
    k_prep<<<34, 256, 0, stream>>>(W1, W2, We, w1f, w2f, wef);
    k_eproj<<<2048, 256, 0, stream>>>(eattr, wef, eb);
    k_aggr2<<<2048, 256, 0, stream>>>(qb16, kb16, vb16, skipb16, eb, elist2,
                                      row_start, cursor);
    k_ffn_mfma<<<(NB + 63) / 64, 256, 0, stream>>>(qb16, w1f, b1, w2f, b2, out);
}

// Round 8
// 369.437 us; speedup vs baseline: 2.3151x; 1.1273x over previous
//
#include <hip/hip_runtime.h>
#include <hip/hip_bf16.h>

// Problem constants (from reference)
#define NB      100000    // B*N nodes
#define NPB     25000     // N per batch
#define T_E     800000    // B*E total edges
#define EPG     200000    // E per graph
#define DMODEL  128       // OUT = H*DH
#define EDIM    32
#define FFD     256
#define SCAN_NBLK 98      // ceil(NB/1024)

typedef __attribute__((ext_vector_type(8))) short bf16x8;
typedef __attribute__((ext_vector_type(4))) float f32x4;
typedef __attribute__((ext_vector_type(2))) float f32x2;

__device__ inline unsigned short f2bf(float f) {
    unsigned u = __float_as_uint(f);
    unsigned r = u + 0x7fffu + ((u >> 16) & 1u);   // RNE
    return (unsigned short)(r >> 16);
}
__device__ inline unsigned pack_bf16x2(float lo, float hi) {
    return (unsigned)f2bf(lo) | ((unsigned)f2bf(hi) << 16);
}
__device__ inline float bf_lo(unsigned p) { return __uint_as_float(p << 16); }
__device__ inline float bf_hi(unsigned p) { return __uint_as_float(p & 0xffff0000u); }

// -------------------------------------------------------------------------
// Kernel: pre-pack ALL weight matrices into MFMA A-fragment layout (bf16).
// frags 0..63 -> w1f | 64..127 -> w2f | 128..135 -> wef |
// 136..263 -> wpf (Wq,Wk,Wv,Wskip: 32 frags each, [ct 0..7][ks 0..3])
// -------------------------------------------------------------------------
__global__ __launch_bounds__(256) void k_prep(
    const float* __restrict__ W1, const float* __restrict__ W2,
    const float* __restrict__ We,
    const float* __restrict__ Wq, const float* __restrict__ Wk,
    const float* __restrict__ Wv, const float* __restrict__ Wskip,
    uint4* __restrict__ w1f, uint4* __restrict__ w2f,
    uint4* __restrict__ wef, uint4* __restrict__ wpf)
{
    int t = blockIdx.x * 256 + threadIdx.x;   // 0..16895
    int lane = t & 63;
    int frag = t >> 6;                         // 0..263
    if (frag >= 264) return;
    int rl = lane & 15, g = lane >> 4;
    unsigned v[4];
    if (frag < 64) {
        int m1 = frag >> 2, ks = frag & 3;
        int col1 = m1 * 16 + rl;
        int k0 = ks * 32 + g * 8;
#pragma unroll
        for (int j2 = 0; j2 < 4; ++j2) {
            float f0 = W1[(k0 + 2 * j2) * FFD + col1];
            float f1 = W1[(k0 + 2 * j2 + 1) * FFD + col1];
            v[j2] = pack_bf16x2(f0, f1);
        }
        w1f[frag * 64 + lane] = make_uint4(v[0], v[1], v[2], v[3]);
    } else if (frag < 128) {
        int f2 = frag - 64;
        int m2 = f2 >> 3, ks = f2 & 7;
        int c2 = m2 * 16 + rl;
        int k0 = ks * 32 + g * 8;
#pragma unroll
        for (int j2 = 0; j2 < 4; ++j2) {
            float f0 = W2[(k0 + 2 * j2) * DMODEL + c2];
            float f1 = W2[(k0 + 2 * j2 + 1) * DMODEL + c2];
            v[j2] = pack_bf16x2(f0, f1);
        }
        w2f[f2 * 64 + lane] = make_uint4(v[0], v[1], v[2], v[3]);
    } else if (frag < 136) {
        int m = frag - 128;                    // 0..7
        int ocol = m * 16 + rl;
        int k0 = g * 8;
#pragma unroll
        for (int j2 = 0; j2 < 4; ++j2) {
            float f0 = We[(k0 + 2 * j2) * DMODEL + ocol];
            float f1 = We[(k0 + 2 * j2 + 1) * DMODEL + ocol];
            v[j2] = pack_bf16x2(f0, f1);
        }
        wef[m * 64 + lane] = make_uint4(v[0], v[1], v[2], v[3]);
    } else {
        int fi = frag - 136;                   // 0..127
        int m  = fi >> 5;                      // matrix 0..3
        int r  = fi & 31;
        int ct = r >> 2, ks = r & 3;
        const float* W = (m == 0) ? Wq : (m == 1) ? Wk : (m == 2) ? Wv : Wskip;
        int col = ct * 16 + rl;
        int k0  = ks * 32 + g * 8;
#pragma unroll
        for (int j2 = 0; j2 < 4; ++j2) {
            float f0 = W[(k0 + 2 * j2) * DMODEL + col];
            float f1 = W[(k0 + 2 * j2 + 1) * DMODEL + col];
            v[j2] = pack_bf16x2(f0, f1);
        }
        wpf[fi * 64 + lane] = make_uint4(v[0], v[1], v[2], v[3]);
    }
}

// -------------------------------------------------------------------------
// Kernel (MFMA): node projections, single pass. Stage x-tile once (32 KB);
// wave w computes matrix w (0=Q,1=K,2=V,3=skip) from pre-packed W frags.
// Swapped orientation: D[col][node]; epilogue packs 4 cols -> uint2 store.
// -------------------------------------------------------------------------
__global__ __launch_bounds__(256) void k_proj2(
    const float* __restrict__ x, const uint4* __restrict__ wpf,
    const float* __restrict__ bq, const float* __restrict__ bk,
    const float* __restrict__ bv, const float* __restrict__ bskip,
    unsigned short* __restrict__ qb16, unsigned short* __restrict__ kb16,
    unsigned short* __restrict__ vb16, unsigned short* __restrict__ skipb16)
{
    __shared__ __align__(16) char lds[32768];
    const int tid   = threadIdx.x;
    const int node0 = blockIdx.x * 128;

    // ---- stage xs: x[b,c,nn] -> xs[node_local][c] (bf16, swizzled)
    {
        const int nl   = tid & 127;
        const int half = tid >> 7;
        const int node = node0 + nl;
        const bool valid = node < NB;
        int b  = node / NPB;
        int nn = node - b * NPB;
        const float* xbase = x + (size_t)b * DMODEL * NPB + nn;
#pragma unroll
        for (int o = 0; o < 8; ++o) {
            int c0 = (o * 2 + half) * 8;       // octet of 8 channels
            unsigned vals[4];
#pragma unroll
            for (int j2 = 0; j2 < 4; ++j2) {
                float f0 = valid ? xbase[(size_t)(c0 + 2 * j2) * NPB] : 0.f;
                float f1 = valid ? xbase[(size_t)(c0 + 2 * j2 + 1) * NPB] : 0.f;
                vals[j2] = pack_bf16x2(f0, f1);
            }
            int byte = nl * 256 + ((c0 * 2) ^ ((nl & 7) << 4));
            *(uint4*)(&lds[byte]) = make_uint4(vals[0], vals[1], vals[2], vals[3]);
        }
    }
    __syncthreads();

    const int w = tid >> 6, lane = tid & 63;
    const int rl = lane & 15, g = lane >> 4;

    const uint4* wf = wpf + (size_t)w * 32 * 64;
    const float* bi = (w == 0) ? bq : (w == 1) ? bk : (w == 2) ? bv : bskip;
    unsigned short* outp = (w == 0) ? qb16 : (w == 1) ? kb16 : (w == 2) ? vb16 : skipb16;

#pragma unroll
    for (int ct = 0; ct < 8; ++ct) {
        bf16x8 A[4];
#pragma unroll
        for (int ks = 0; ks < 4; ++ks)
            A[ks] = *(const bf16x8*)&wf[(ct * 4 + ks) * 64 + lane];
        const int colb = ct * 16 + g * 4;
        const float bb0 = bi[colb], bb1 = bi[colb + 1],
                    bb2 = bi[colb + 2], bb3 = bi[colb + 3];
#pragma unroll
        for (int nt = 0; nt < 8; ++nt) {
            const int nl = nt * 16 + rl;
            f32x4 acc = {0.f, 0.f, 0.f, 0.f};
#pragma unroll
            for (int ks = 0; ks < 4; ++ks) {
                bf16x8 B = *(const bf16x8*)(&lds[nl * 256 +
                              ((ks * 64 + g * 16) ^ ((nl & 7) << 4))]);
                acc = __builtin_amdgcn_mfma_f32_16x16x32_bf16(A[ks], B, acc, 0, 0, 0);
            }
            const int node = node0 + nl;
            if (node < NB) {
                unsigned lo = pack_bf16x2(acc[0] + bb0, acc[1] + bb1);
                unsigned hi = pack_bf16x2(acc[2] + bb2, acc[3] + bb3);
                *(uint2*)&outp[(size_t)node * DMODEL + colb] = make_uint2(lo, hi);
            }
        }
    }
}

// -------------------------------------------------------------------------
// CSR build: histogram -> scan (3 kernels) -> scatter (stores (src,eid)).
// -------------------------------------------------------------------------
__global__ __launch_bounds__(256) void k_hist(
    const int* __restrict__ eidx, int* __restrict__ counts)
{
    int t = blockIdx.x * 256 + threadIdx.x;
    if (t < T_E) {
        int b = t / EPG, e = t - b * EPG;
        int dst = eidx[(size_t)(b * 2 + 1) * EPG + e];
        atomicAdd(&counts[dst], 1);
    }
}

__global__ __launch_bounds__(1024) void k_scan1(
    const int* __restrict__ counts, int* __restrict__ row_start,
    int* __restrict__ bsum)
{
    __shared__ int s[1024];
    const int tid = threadIdx.x;
    const int gid = blockIdx.x * 1024 + tid;
    int v = (gid < NB) ? counts[gid] : 0;
    s[tid] = v;
    __syncthreads();
#pragma unroll
    for (int off = 1; off < 1024; off <<= 1) {
        int tv = (tid >= off) ? s[tid - off] : 0;
        __syncthreads();
        s[tid] += tv;
        __syncthreads();
    }
    int incl = s[tid];
    if (gid < NB) row_start[gid] = incl - v;
    if (tid == 1023) bsum[blockIdx.x] = incl;
}

__global__ __launch_bounds__(128) void k_scan2(int* __restrict__ bsum)
{
    __shared__ int s[128];
    const int tid = threadIdx.x;
    int v = (tid < SCAN_NBLK) ? bsum[tid] : 0;
    s[tid] = v;
    __syncthreads();
#pragma unroll
    for (int off = 1; off < 128; off <<= 1) {
        int tv = (tid >= off) ? s[tid - off] : 0;
        __syncthreads();
        s[tid] += tv;
        __syncthreads();
    }
    if (tid < SCAN_NBLK) bsum[tid] = s[tid] - v;
}

__global__ __launch_bounds__(1024) void k_scan3(
    int* __restrict__ row_start, const int* __restrict__ bsum,
    int* __restrict__ cursor)
{
    const int gid = blockIdx.x * 1024 + threadIdx.x;
    if (gid < NB) {
        int v = row_start[gid] + bsum[blockIdx.x];
        row_start[gid] = v;
        cursor[gid] = v;
    }
}

__global__ __launch_bounds__(256) void k_scatter(
    const int* __restrict__ eidx, int* __restrict__ cursor,
    int2* __restrict__ elist2)
{
    int t = blockIdx.x * 256 + threadIdx.x;
    if (t < T_E) {
        int b = t / EPG, e = t - b * EPG;
        int dst = eidx[(size_t)(b * 2 + 1) * EPG + e];
        int src = eidx[(size_t)(b * 2) * EPG + e];
        int pos = atomicAdd(&cursor[dst], 1);
        elist2[pos] = make_int2(src, t);   // after: cursor[d] == row_end[d]
    }
}

// -------------------------------------------------------------------------
// Kernel: e-projection, edge-parallel MFMA.  eb[eid][128] fp8 e4m3.
// -------------------------------------------------------------------------
__global__ __launch_bounds__(256) void k_eproj(
    const float* __restrict__ eattr, const uint4* __restrict__ wef,
    unsigned char* __restrict__ eb)
{
    const int tid = threadIdx.x;
    const int w = tid >> 6, lane = tid & 63;
    const int rl = lane & 15, g = lane >> 4;

    bf16x8 a[8];
#pragma unroll
    for (int m = 0; m < 8; ++m) a[m] = *(const bf16x8*)&wef[m * 64 + lane];

    const int nwaves = gridDim.x * 4;
    for (int tile = blockIdx.x * 4 + w; tile < T_E / 16; tile += nwaves) {
        const float* ep = &eattr[((size_t)tile * 16 + rl) * EDIM + g * 8];
        float4 f0 = *(const float4*)ep;
        float4 f1 = *(const float4*)(ep + 4);
        uint4 bu = make_uint4(pack_bf16x2(f0.x, f0.y), pack_bf16x2(f0.z, f0.w),
                              pack_bf16x2(f1.x, f1.y), pack_bf16x2(f1.z, f1.w));
        bf16x8 b = *(bf16x8*)&bu;
        f32x4 z = {0.f, 0.f, 0.f, 0.f};
        f32x4 acc[8];
#pragma unroll
        for (int m = 0; m < 8; ++m)
            acc[m] = __builtin_amdgcn_mfma_f32_16x16x32_bf16(a[m], b, z, 0, 0, 0);
        unsigned char* out = &eb[((size_t)tile * 16 + rl) * DMODEL + g * 4];
#pragma unroll
        for (int m = 0; m < 8; ++m) {
            unsigned d = __builtin_amdgcn_cvt_pk_fp8_f32(acc[m][0], acc[m][1], 0, false);
            d = __builtin_amdgcn_cvt_pk_fp8_f32(acc[m][2], acc[m][3], d, true);
            *(unsigned*)(out + m * 16) = d;
        }
    }
}

// -------------------------------------------------------------------------
// Kernel: per-node gather-aggregate, 4 edges per wave concurrently
// (quarter-waves), 8 channels per lane (uint4 k/v gathers).
// Output: xs16[node][c] = agg_norm + skip (bf16) — into qb16 space.
// -------------------------------------------------------------------------
__global__ __launch_bounds__(256) void k_aggr3(
    unsigned short* qx,                       // q (read) / xs16 (write) — aliased
    const unsigned short* __restrict__ kb16,
    const unsigned short* __restrict__ vb16,
    const unsigned short* __restrict__ skipb16,
    const unsigned char* __restrict__ eb,
    const int2* __restrict__ elist2,
    const int* __restrict__ row_start, const int* __restrict__ row_end)
{
    const int tid = threadIdx.x;
    const int w = tid >> 6, l = tid & 63;
    const int q4 = l >> 4;                    // which edge of the quad
    const int li = l & 15;
    const int c0 = li * 8;                    // this lane's 8 channels

    const int nwaves = gridDim.x * 4;
    for (int node = blockIdx.x * 4 + w; node < NB; node += nwaves) {
        const int rs = row_start[node];
        const int re = row_end[node];
        uint4 qp = *(const uint4*)&qx[(size_t)node * DMODEL + c0];
        const float q0 = bf_lo(qp.x), q1 = bf_hi(qp.x);
        const float q2 = bf_lo(qp.y), q3 = bf_hi(qp.y);
        const float q4_ = bf_lo(qp.z), q5 = bf_hi(qp.z);
        const float q6 = bf_lo(qp.w), q7 = bf_hi(qp.w);
        float a0 = 0.f, a1 = 0.f, a2 = 0.f, a3 = 0.f;
        float a4 = 0.f, a5 = 0.f, a6 = 0.f, a7 = 0.f, den = 0.f;

        for (int j0 = rs; j0 < re; j0 += 4) {
            const int jc = j0 + q4;
            const bool act = jc < re;
            const int jj = act ? jc : re - 1;
            int2 se = elist2[jj];                       // (src, eid)
            uint4 kp = *(const uint4*)&kb16[(size_t)se.x * DMODEL + c0];
            uint4 vp = *(const uint4*)&vb16[(size_t)se.x * DMODEL + c0];
            uint2 ep8 = *(const uint2*)&eb[(size_t)se.y * DMODEL + c0];
            f32x2 exl = __builtin_amdgcn_cvt_pk_f32_fp8(ep8.x, false);
            f32x2 exh = __builtin_amdgcn_cvt_pk_f32_fp8(ep8.x, true);
            f32x2 eyl = __builtin_amdgcn_cvt_pk_f32_fp8(ep8.y, false);
            f32x2 eyh = __builtin_amdgcn_cvt_pk_f32_fp8(ep8.y, true);
            const float e0 = exl[0], e1 = exl[1], e2 = exh[0], e3 = exh[1];
            const float e4 = eyl[0], e5 = eyl[1], e6 = eyh[0], e7 = eyh[1];
            const float k0 = bf_lo(kp.x) + e0, k1 = bf_hi(kp.x) + e1;
            const float k2 = bf_lo(kp.y) + e2, k3 = bf_hi(kp.y) + e3;
            const float k4 = bf_lo(kp.z) + e4, k5 = bf_hi(kp.z) + e5;
            const float k6 = bf_lo(kp.w) + e6, k7 = bf_hi(kp.w) + e7;
            float p = q0 * k0 + q1 * k1 + q2 * k2 + q3 * k3
                    + q4_ * k4 + q5 * k5 + q6 * k6 + q7 * k7;
            // head = 32 ch = 4 lanes (li>>2); reduce over those 4 lanes
            p += __shfl_xor(p, 1, 64);
            p += __shfl_xor(p, 2, 64);
            float ea = act ? __expf(p * 0.17677669529663689f) : 0.f;
            a0 += ea * (bf_lo(vp.x) + e0);
            a1 += ea * (bf_hi(vp.x) + e1);
            a2 += ea * (bf_lo(vp.y) + e2);
            a3 += ea * (bf_hi(vp.y) + e3);
            a4 += ea * (bf_lo(vp.z) + e4);
            a5 += ea * (bf_hi(vp.z) + e5);
            a6 += ea * (bf_lo(vp.w) + e6);
            a7 += ea * (bf_hi(vp.w) + e7);
            den += ea;
        }
        // combine the four quarter-wave edge streams
#pragma unroll
        for (int off = 16; off <= 32; off <<= 1) {
            a0 += __shfl_xor(a0, off, 64);
            a1 += __shfl_xor(a1, off, 64);
            a2 += __shfl_xor(a2, off, 64);
            a3 += __shfl_xor(a3, off, 64);
            a4 += __shfl_xor(a4, off, 64);
            a5 += __shfl_xor(a5, off, 64);
            a6 += __shfl_xor(a6, off, 64);
            a7 += __shfl_xor(a7, off, 64);
            den += __shfl_xor(den, off, 64);
        }
        float r = 1.0f / (den + 1e-16f);
        if (q4 == 0) {
            uint4 sp = *(const uint4*)&skipb16[(size_t)node * DMODEL + c0];
            uint4 o;
            o.x = pack_bf16x2(a0 * r + bf_lo(sp.x), a1 * r + bf_hi(sp.x));
            o.y = pack_bf16x2(a2 * r + bf_lo(sp.y), a3 * r + bf_hi(sp.y));
            o.z = pack_bf16x2(a4 * r + bf_lo(sp.z), a5 * r + bf_hi(sp.z));
            o.w = pack_bf16x2(a6 * r + bf_lo(sp.w), a7 * r + bf_hi(sp.w));
            *(uint4*)&qx[(size_t)node * DMODEL + c0] = o;
        }
    }
}

// -------------------------------------------------------------------------
// Kernel (MFMA): FFN on xs16 (= agg_norm + skip, bf16) + transposed write.
// -------------------------------------------------------------------------
#define H1_OFF 16384

__global__ __launch_bounds__(256) void k_ffn_mfma(
    const unsigned short* __restrict__ xs16,
    const uint4* __restrict__ w1f, const float* __restrict__ b1,
    const uint4* __restrict__ w2f, const float* __restrict__ b2,
    float* __restrict__ out)
{
    __shared__ __align__(16) char lds[49152];
    const int tid   = threadIdx.x;
    const int node0 = blockIdx.x * 64;

#pragma unroll
    for (int i = 0; i < 4; ++i) {
        int linear = i * 256 + tid;            // 0..1023
        int row = linear >> 4;                 // 0..63
        int c8  = (linear & 15) * 8;
        int node = node0 + row;
        uint4 vv = (node < NB) ? *(const uint4*)&xs16[(size_t)node * DMODEL + c8]
                               : make_uint4(0, 0, 0, 0);
        int byte = row * 256 + ((c8 * 2) ^ ((row & 7) << 4));
        *(uint4*)(&lds[byte]) = vv;
    }
    __syncthreads();

    const int w = tid >> 6, lane = tid & 63;
    const int rl = lane & 15, g = lane >> 4;

    // ---- GEMM1: wave w covers col1 in [w*64, w*64+64)
    {
        f32x4 acc[4][4] = {};
#pragma unroll
        for (int ks = 0; ks < 4; ++ks) {
            bf16x8 a[4], b[4];
#pragma unroll
            for (int mt = 0; mt < 4; ++mt) {
                int m1 = w * 4 + mt;
                a[mt] = *(const bf16x8*)&w1f[(m1 * 4 + ks) * 64 + lane];
            }
#pragma unroll
            for (int nt = 0; nt < 4; ++nt) {
                int node = nt * 16 + rl;
                int byte = node * 256 + ((ks * 64 + g * 16) ^ ((node & 7) << 4));
                b[nt] = *(const bf16x8*)&lds[byte];
            }
#pragma unroll
            for (int mt = 0; mt < 4; ++mt)
#pragma unroll
                for (int nt = 0; nt < 4; ++nt)
                    acc[mt][nt] = __builtin_amdgcn_mfma_f32_16x16x32_bf16(
                        a[mt], b[nt], acc[mt][nt], 0, 0, 0);
        }
#pragma unroll
        for (int mt = 0; mt < 4; ++mt) {
            int col1_0 = w * 64 + mt * 16 + g * 4;
            float bb0 = b1[col1_0], bb1 = b1[col1_0 + 1],
                  bb2 = b1[col1_0 + 2], bb3 = b1[col1_0 + 3];
#pragma unroll
            for (int nt = 0; nt < 4; ++nt) {
                int node = nt * 16 + rl;
                float v0 = fmaxf(acc[mt][nt][0] + bb0, 0.f);
                float v1 = fmaxf(acc[mt][nt][1] + bb1, 0.f);
                float v2 = fmaxf(acc[mt][nt][2] + bb2, 0.f);
                float v3 = fmaxf(acc[mt][nt][3] + bb3, 0.f);
                unsigned lo = pack_bf16x2(v0, v1), hi = pack_bf16x2(v2, v3);
                int byte = H1_OFF + node * 512 + ((col1_0 * 2) ^ ((node & 7) << 4));
                *(uint2*)(&lds[byte]) = make_uint2(lo, hi);
            }
        }
    }
    __syncthreads();

    // ---- GEMM2: wave w covers c2 in [w*32, w*32+32)
    {
        f32x4 acc[2][4] = {};
#pragma unroll
        for (int ks = 0; ks < 8; ++ks) {
            bf16x8 a[2], b[4];
#pragma unroll
            for (int mt = 0; mt < 2; ++mt) {
                int m2 = w * 2 + mt;
                a[mt] = *(const bf16x8*)&w2f[(m2 * 8 + ks) * 64 + lane];
            }
#pragma unroll
            for (int nt = 0; nt < 4; ++nt) {
                int node = nt * 16 + rl;
                int byte = H1_OFF + node * 512 + ((ks * 64 + g * 16) ^ ((node & 7) << 4));
                b[nt] = *(const bf16x8*)&lds[byte];
            }
#pragma unroll
            for (int mt = 0; mt < 2; ++mt)
#pragma unroll
                for (int nt = 0; nt < 4; ++nt)
                    acc[mt][nt] = __builtin_amdgcn_mfma_f32_16x16x32_bf16(
                        a[mt], b[nt], acc[mt][nt], 0, 0, 0);
        }
#pragma unroll
        for (int mt = 0; mt < 2; ++mt) {
            int c2_0 = w * 32 + mt * 16 + g * 4;
#pragma unroll
            for (int nt = 0; nt < 4; ++nt) {
                int node = node0 + nt * 16 + rl;
                if (node < NB) {
                    int bb = node / NPB;
                    int nn = node - bb * NPB;
                    size_t base = (size_t)(bb * DMODEL) * NPB + nn;
#pragma unroll
                    for (int r = 0; r < 4; ++r) {
                        float v = fmaxf(acc[mt][nt][r] + b2[c2_0 + r], 0.f);
                        out[base + (size_t)(c2_0 + r) * NPB] = v;
                    }
                }
            }
        }
    }
}

// -------------------------------------------------------------------------
extern "C" void kernel_launch(void* const* d_in, const int* in_sizes, int n_in,
                              void* d_out, int out_size, void* d_ws, size_t ws_size,
                              hipStream_t stream)
{
    const float* x     = (const float*)d_in[0];
    const int*   eidx  = (const int*)  d_in[1];
    const float* eattr = (const float*)d_in[2];
    const float* Wq    = (const float*)d_in[3];
    const float* bq    = (const float*)d_in[4];
    const float* Wk    = (const float*)d_in[5];
    const float* bk    = (const float*)d_in[6];
    const float* Wv    = (const float*)d_in[7];
    const float* bv    = (const float*)d_in[8];
    const float* We    = (const float*)d_in[9];
    const float* Wskip = (const float*)d_in[10];
    const float* bskip = (const float*)d_in[11];
    const float* W1    = (const float*)d_in[12];
    const float* b1    = (const float*)d_in[13];
    const float* W2    = (const float*)d_in[14];
    const float* b2    = (const float*)d_in[15];
    float* out = (float*)d_out;

    // ws layout (~212.7 MB):
    // qb16(->xs16) | kb16 | vb16 | skipb16 | eb fp8 | w1f | w2f | wef | wpf |
    // counts | row_start | cursor | elist2 | bsum
    const size_t NBD = (size_t)NB * DMODEL;
    unsigned short* qb16    = (unsigned short*)d_ws;
    unsigned short* kb16    = qb16 + NBD;
    unsigned short* vb16    = kb16 + NBD;
    unsigned short* skipb16 = vb16 + NBD;
    unsigned char*  eb      = (unsigned char*)(skipb16 + NBD);
    uint4* w1f = (uint4*)(eb + (size_t)T_E * DMODEL);
    uint4* w2f = w1f + 64 * 64;
    uint4* wef = w2f + 64 * 64;
    uint4* wpf = wef + 8 * 64;
    int* counts    = (int*)(wpf + 128 * 64);
    int* row_start = counts + NB;
    int* cursor    = row_start + NB;
    int2* elist2   = (int2*)(cursor + NB);
    int* bsum      = (int*)(elist2 + T_E);

    hipMemsetAsync(counts, 0, NB * sizeof(int), stream);
    k_prep<<<66, 256, 0, stream>>>(W1, W2, We, Wq, Wk, Wv, Wskip,
                                   w1f, w2f, wef, wpf);
    k_proj2<<<(NB + 127) / 128, 256, 0, stream>>>(x, wpf, bq, bk, bv, bskip,
                                                  qb16, kb16, vb16, skipb16);
    k_hist<<<(T_E + 255) / 256, 256, 0, stream>>>(eidx, counts);
    k_scan1<<<SCAN_NBLK, 1024, 0, stream>>>(counts, row_start, bsum);
    k_scan2<<<1, 128, 0, stream>>>(bsum);
    k_scan3<<<SCAN_NBLK, 1024, 0, stream>>>(row_start, bsum, cursor);
    k_scatter<<<(T_E + 255) / 256, 256, 0, stream>>>(eidx, cursor, elist2);
    k_eproj<<<2048, 256, 0, stream>>>(eattr, wef, eb);
    k_aggr3<<<2048, 256, 0, stream>>>(qb16, kb16, vb16, skipb16, eb, elist2,
                                      row_start, cursor);
    k_ffn_mfma<<<(NB + 63) / 64, 256, 0, stream>>>(qb16, w1f, b1, w2f, b2, out);
}

// Round 9
// 369.126 us; speedup vs baseline: 2.3171x; 1.0008x over previous
//
#include <hip/hip_runtime.h>
#include <hip/hip_bf16.h>

// Problem constants (from reference)
#define NB      100000    // B*N nodes
#define NPB     25000     // N per batch
#define T_E     800000    // B*E total edges
#define EPG     200000    // E per graph
#define DMODEL  128       // OUT = H*DH
#define EDIM    32
#define FFD     256
#define SCAN_NBLK 98      // ceil(NB/1024)

typedef __attribute__((ext_vector_type(8))) short bf16x8;
typedef __attribute__((ext_vector_type(4))) float f32x4;
typedef __attribute__((ext_vector_type(2))) float f32x2;

__device__ inline unsigned short f2bf(float f) {
    unsigned u = __float_as_uint(f);
    unsigned r = u + 0x7fffu + ((u >> 16) & 1u);   // RNE
    return (unsigned short)(r >> 16);
}
__device__ inline unsigned pack_bf16x2(float lo, float hi) {
    return (unsigned)f2bf(lo) | ((unsigned)f2bf(hi) << 16);
}
__device__ inline float bf_lo(unsigned p) { return __uint_as_float(p << 16); }
__device__ inline float bf_hi(unsigned p) { return __uint_as_float(p & 0xffff0000u); }

// -------------------------------------------------------------------------
// Kernel: pre-pack ALL weight matrices into MFMA A-fragment layout (bf16).
// frags 0..63 -> w1f | 64..127 -> w2f | 128..135 -> wef |
// 136..263 -> wpf (Wq,Wk,Wv,Wskip: 32 frags each, [ct 0..7][ks 0..3])
// -------------------------------------------------------------------------
__global__ __launch_bounds__(256) void k_prep(
    const float* __restrict__ W1, const float* __restrict__ W2,
    const float* __restrict__ We,
    const float* __restrict__ Wq, const float* __restrict__ Wk,
    const float* __restrict__ Wv, const float* __restrict__ Wskip,
    uint4* __restrict__ w1f, uint4* __restrict__ w2f,
    uint4* __restrict__ wef, uint4* __restrict__ wpf)
{
    int t = blockIdx.x * 256 + threadIdx.x;   // 0..16895
    int lane = t & 63;
    int frag = t >> 6;                         // 0..263
    if (frag >= 264) return;
    int rl = lane & 15, g = lane >> 4;
    unsigned v[4];
    if (frag < 64) {
        int m1 = frag >> 2, ks = frag & 3;
        int col1 = m1 * 16 + rl;
        int k0 = ks * 32 + g * 8;
#pragma unroll
        for (int j2 = 0; j2 < 4; ++j2) {
            float f0 = W1[(k0 + 2 * j2) * FFD + col1];
            float f1 = W1[(k0 + 2 * j2 + 1) * FFD + col1];
            v[j2] = pack_bf16x2(f0, f1);
        }
        w1f[frag * 64 + lane] = make_uint4(v[0], v[1], v[2], v[3]);
    } else if (frag < 128) {
        int f2 = frag - 64;
        int m2 = f2 >> 3, ks = f2 & 7;
        int c2 = m2 * 16 + rl;
        int k0 = ks * 32 + g * 8;
#pragma unroll
        for (int j2 = 0; j2 < 4; ++j2) {
            float f0 = W2[(k0 + 2 * j2) * DMODEL + c2];
            float f1 = W2[(k0 + 2 * j2 + 1) * DMODEL + c2];
            v[j2] = pack_bf16x2(f0, f1);
        }
        w2f[f2 * 64 + lane] = make_uint4(v[0], v[1], v[2], v[3]);
    } else if (frag < 136) {
        int m = frag - 128;                    // 0..7
        int ocol = m * 16 + rl;
        int k0 = g * 8;
#pragma unroll
        for (int j2 = 0; j2 < 4; ++j2) {
            float f0 = We[(k0 + 2 * j2) * DMODEL + ocol];
            float f1 = We[(k0 + 2 * j2 + 1) * DMODEL + ocol];
            v[j2] = pack_bf16x2(f0, f1);
        }
        wef[m * 64 + lane] = make_uint4(v[0], v[1], v[2], v[3]);
    } else {
        int fi = frag - 136;                   // 0..127
        int m  = fi >> 5;                      // matrix 0..3
        int r  = fi & 31;
        int ct = r >> 2, ks = r & 3;
        const float* W = (m == 0) ? Wq : (m == 1) ? Wk : (m == 2) ? Wv : Wskip;
        int col = ct * 16 + rl;
        int k0  = ks * 32 + g * 8;
#pragma unroll
        for (int j2 = 0; j2 < 4; ++j2) {
            float f0 = W[(k0 + 2 * j2) * DMODEL + col];
            float f1 = W[(k0 + 2 * j2 + 1) * DMODEL + col];
            v[j2] = pack_bf16x2(f0, f1);
        }
        wpf[fi * 64 + lane] = make_uint4(v[0], v[1], v[2], v[3]);
    }
}

// -------------------------------------------------------------------------
// Kernel (MFMA): node projections, 64-node tiles (grid 1563, LDS 16 KB).
// Wave w computes matrix w (0=Q,1=K,2=V,3=skip) from pre-packed W frags.
// K and V write interleaved into kvb[node][256] (k at 0, v at 128).
// -------------------------------------------------------------------------
__global__ __launch_bounds__(256) void k_proj2(
    const float* __restrict__ x, const uint4* __restrict__ wpf,
    const float* __restrict__ bq, const float* __restrict__ bk,
    const float* __restrict__ bv, const float* __restrict__ bskip,
    unsigned short* __restrict__ qb16, unsigned short* __restrict__ kvb,
    unsigned short* __restrict__ skipb16)
{
    __shared__ __align__(16) char lds[16384];
    const int tid   = threadIdx.x;
    const int node0 = blockIdx.x * 64;

    // ---- stage xs: x[b,c,nn] -> xs[node_local][c] (bf16, swizzled)
    // 4 threads per node, 4 octets (32 ch) each.
    {
        const int nl   = tid & 63;
        const int half = tid >> 6;             // 0..3
        const int node = node0 + nl;
        const bool valid = node < NB;
        int b  = node / NPB;
        int nn = node - b * NPB;
        const float* xbase = x + (size_t)b * DMODEL * NPB + nn;
#pragma unroll
        for (int o = 0; o < 4; ++o) {
            int c0 = (half * 4 + o) * 8;       // octet of 8 channels
            unsigned vals[4];
#pragma unroll
            for (int j2 = 0; j2 < 4; ++j2) {
                float f0 = valid ? xbase[(size_t)(c0 + 2 * j2) * NPB] : 0.f;
                float f1 = valid ? xbase[(size_t)(c0 + 2 * j2 + 1) * NPB] : 0.f;
                vals[j2] = pack_bf16x2(f0, f1);
            }
            int byte = nl * 256 + ((c0 * 2) ^ ((nl & 7) << 4));
            *(uint4*)(&lds[byte]) = make_uint4(vals[0], vals[1], vals[2], vals[3]);
        }
    }
    __syncthreads();

    const int w = tid >> 6, lane = tid & 63;
    const int rl = lane & 15, g = lane >> 4;

    const uint4* wf = wpf + (size_t)w * 32 * 64;
    const float* bi = (w == 0) ? bq : (w == 1) ? bk : (w == 2) ? bv : bskip;
    unsigned short* base = (w == 0) ? qb16 : (w == 3) ? skipb16
                          : kvb + ((w == 2) ? 128 : 0);
    const int rowstride = (w == 1 || w == 2) ? 256 : 128;

#pragma unroll
    for (int ct = 0; ct < 8; ++ct) {
        bf16x8 A[4];
#pragma unroll
        for (int ks = 0; ks < 4; ++ks)
            A[ks] = *(const bf16x8*)&wf[(ct * 4 + ks) * 64 + lane];
        const int colb = ct * 16 + g * 4;
        const float bb0 = bi[colb], bb1 = bi[colb + 1],
                    bb2 = bi[colb + 2], bb3 = bi[colb + 3];
#pragma unroll
        for (int nt = 0; nt < 4; ++nt) {
            const int nl = nt * 16 + rl;
            f32x4 acc = {0.f, 0.f, 0.f, 0.f};
#pragma unroll
            for (int ks = 0; ks < 4; ++ks) {
                bf16x8 B = *(const bf16x8*)(&lds[nl * 256 +
                              ((ks * 64 + g * 16) ^ ((nl & 7) << 4))]);
                acc = __builtin_amdgcn_mfma_f32_16x16x32_bf16(A[ks], B, acc, 0, 0, 0);
            }
            const int node = node0 + nl;
            if (node < NB) {
                unsigned lo = pack_bf16x2(acc[0] + bb0, acc[1] + bb1);
                unsigned hi = pack_bf16x2(acc[2] + bb2, acc[3] + bb3);
                *(uint2*)&base[(size_t)node * rowstride + colb] = make_uint2(lo, hi);
            }
        }
    }
}

// -------------------------------------------------------------------------
// CSR build: histogram -> scan (3 kernels) -> scatter (stores (src,eid)).
// -------------------------------------------------------------------------
__global__ __launch_bounds__(256) void k_hist(
    const int* __restrict__ eidx, int* __restrict__ counts)
{
    int t = blockIdx.x * 256 + threadIdx.x;
    if (t < T_E) {
        int b = t / EPG, e = t - b * EPG;
        int dst = eidx[(size_t)(b * 2 + 1) * EPG + e];
        atomicAdd(&counts[dst], 1);
    }
}

__global__ __launch_bounds__(1024) void k_scan1(
    const int* __restrict__ counts, int* __restrict__ row_start,
    int* __restrict__ bsum)
{
    __shared__ int s[1024];
    const int tid = threadIdx.x;
    const int gid = blockIdx.x * 1024 + tid;
    int v = (gid < NB) ? counts[gid] : 0;
    s[tid] = v;
    __syncthreads();
#pragma unroll
    for (int off = 1; off < 1024; off <<= 1) {
        int tv = (tid >= off) ? s[tid - off] : 0;
        __syncthreads();
        s[tid] += tv;
        __syncthreads();
    }
    int incl = s[tid];
    if (gid < NB) row_start[gid] = incl - v;
    if (tid == 1023) bsum[blockIdx.x] = incl;
}

__global__ __launch_bounds__(128) void k_scan2(int* __restrict__ bsum)
{
    __shared__ int s[128];
    const int tid = threadIdx.x;
    int v = (tid < SCAN_NBLK) ? bsum[tid] : 0;
    s[tid] = v;
    __syncthreads();
#pragma unroll
    for (int off = 1; off < 128; off <<= 1) {
        int tv = (tid >= off) ? s[tid - off] : 0;
        __syncthreads();
        s[tid] += tv;
        __syncthreads();
    }
    if (tid < SCAN_NBLK) bsum[tid] = s[tid] - v;
}

__global__ __launch_bounds__(1024) void k_scan3(
    int* __restrict__ row_start, const int* __restrict__ bsum,
    int* __restrict__ cursor)
{
    const int gid = blockIdx.x * 1024 + threadIdx.x;
    if (gid < NB) {
        int v = row_start[gid] + bsum[blockIdx.x];
        row_start[gid] = v;
        cursor[gid] = v;
    }
}

__global__ __launch_bounds__(256) void k_scatter(
    const int* __restrict__ eidx, int* __restrict__ cursor,
    int2* __restrict__ elist2)
{
    int t = blockIdx.x * 256 + threadIdx.x;
    if (t < T_E) {
        int b = t / EPG, e = t - b * EPG;
        int dst = eidx[(size_t)(b * 2 + 1) * EPG + e];
        int src = eidx[(size_t)(b * 2) * EPG + e];
        int pos = atomicAdd(&cursor[dst], 1);
        elist2[pos] = make_int2(src, t);   // after: cursor[d] == row_end[d]
    }
}

// -------------------------------------------------------------------------
// Kernel: e-projection, edge-parallel MFMA.  eb[eid][128] fp8 e4m3.
// -------------------------------------------------------------------------
__global__ __launch_bounds__(256) void k_eproj(
    const float* __restrict__ eattr, const uint4* __restrict__ wef,
    unsigned char* __restrict__ eb)
{
    const int tid = threadIdx.x;
    const int w = tid >> 6, lane = tid & 63;
    const int rl = lane & 15, g = lane >> 4;

    bf16x8 a[8];
#pragma unroll
    for (int m = 0; m < 8; ++m) a[m] = *(const bf16x8*)&wef[m * 64 + lane];

    const int nwaves = gridDim.x * 4;
    for (int tile = blockIdx.x * 4 + w; tile < T_E / 16; tile += nwaves) {
        const float* ep = &eattr[((size_t)tile * 16 + rl) * EDIM + g * 8];
        float4 f0 = *(const float4*)ep;
        float4 f1 = *(const float4*)(ep + 4);
        uint4 bu = make_uint4(pack_bf16x2(f0.x, f0.y), pack_bf16x2(f0.z, f0.w),
                              pack_bf16x2(f1.x, f1.y), pack_bf16x2(f1.z, f1.w));
        bf16x8 b = *(bf16x8*)&bu;
        f32x4 z = {0.f, 0.f, 0.f, 0.f};
        f32x4 acc[8];
#pragma unroll
        for (int m = 0; m < 8; ++m)
            acc[m] = __builtin_amdgcn_mfma_f32_16x16x32_bf16(a[m], b, z, 0, 0, 0);
        unsigned char* out = &eb[((size_t)tile * 16 + rl) * DMODEL + g * 4];
#pragma unroll
        for (int m = 0; m < 8; ++m) {
            unsigned d = __builtin_amdgcn_cvt_pk_fp8_f32(acc[m][0], acc[m][1], 0, false);
            d = __builtin_amdgcn_cvt_pk_fp8_f32(acc[m][2], acc[m][3], d, true);
            *(unsigned*)(out + m * 16) = d;
        }
    }
}

// -------------------------------------------------------------------------
// Kernel: per-node gather-aggregate, 4 edges per wave (quarter-waves),
// 8 channels per lane. k/v interleaved rows; gathers guarded on act.
// Output: xs16[node][c] = agg_norm + skip (bf16) — into qb16 space.
// -------------------------------------------------------------------------
__global__ __launch_bounds__(256) void k_aggr3(
    unsigned short* qx,                       // q (read) / xs16 (write) — aliased
    const unsigned short* __restrict__ kvb,
    const unsigned short* __restrict__ skipb16,
    const unsigned char* __restrict__ eb,
    const int2* __restrict__ elist2,
    const int* __restrict__ row_start, const int* __restrict__ row_end)
{
    const int tid = threadIdx.x;
    const int w = tid >> 6, l = tid & 63;
    const int q4 = l >> 4;                    // which edge of the quad
    const int li = l & 15;
    const int c0 = li * 8;                    // this lane's 8 channels

    const int nwaves = gridDim.x * 4;
    for (int node = blockIdx.x * 4 + w; node < NB; node += nwaves) {
        const int rs = row_start[node];
        const int re = row_end[node];
        uint4 qp = *(const uint4*)&qx[(size_t)node * DMODEL + c0];
        const float q0 = bf_lo(qp.x), q1 = bf_hi(qp.x);
        const float q2 = bf_lo(qp.y), q3 = bf_hi(qp.y);
        const float q4_ = bf_lo(qp.z), q5 = bf_hi(qp.z);
        const float q6 = bf_lo(qp.w), q7 = bf_hi(qp.w);
        float a0 = 0.f, a1 = 0.f, a2 = 0.f, a3 = 0.f;
        float a4 = 0.f, a5 = 0.f, a6 = 0.f, a7 = 0.f, den = 0.f;

        for (int j0 = rs; j0 < re; j0 += 4) {
            const int jc = j0 + q4;
            const bool act = jc < re;          // uniform across the 16-lane group
            uint4 kp = make_uint4(0, 0, 0, 0), vp = make_uint4(0, 0, 0, 0);
            uint2 ep8 = make_uint2(0, 0);
            if (act) {
                int2 se = elist2[jc];                   // (src, eid)
                kp = *(const uint4*)&kvb[(size_t)se.x * 256 + c0];
                vp = *(const uint4*)&kvb[(size_t)se.x * 256 + 128 + c0];
                ep8 = *(const uint2*)&eb[(size_t)se.y * DMODEL + c0];
            }
            f32x2 exl = __builtin_amdgcn_cvt_pk_f32_fp8(ep8.x, false);
            f32x2 exh = __builtin_amdgcn_cvt_pk_f32_fp8(ep8.x, true);
            f32x2 eyl = __builtin_amdgcn_cvt_pk_f32_fp8(ep8.y, false);
            f32x2 eyh = __builtin_amdgcn_cvt_pk_f32_fp8(ep8.y, true);
            const float e0 = exl[0], e1 = exl[1], e2 = exh[0], e3 = exh[1];
            const float e4 = eyl[0], e5 = eyl[1], e6 = eyh[0], e7 = eyh[1];
            const float k0 = bf_lo(kp.x) + e0, k1 = bf_hi(kp.x) + e1;
            const float k2 = bf_lo(kp.y) + e2, k3 = bf_hi(kp.y) + e3;
            const float k4 = bf_lo(kp.z) + e4, k5 = bf_hi(kp.z) + e5;
            const float k6 = bf_lo(kp.w) + e6, k7 = bf_hi(kp.w) + e7;
            float p = q0 * k0 + q1 * k1 + q2 * k2 + q3 * k3
                    + q4_ * k4 + q5 * k5 + q6 * k6 + q7 * k7;
            // head = 32 ch = 4 lanes; reduce over those 4 lanes
            p += __shfl_xor(p, 1, 64);
            p += __shfl_xor(p, 2, 64);
            float ea = act ? __expf(p * 0.17677669529663689f) : 0.f;
            a0 += ea * (bf_lo(vp.x) + e0);
            a1 += ea * (bf_hi(vp.x) + e1);
            a2 += ea * (bf_lo(vp.y) + e2);
            a3 += ea * (bf_hi(vp.y) + e3);
            a4 += ea * (bf_lo(vp.z) + e4);
            a5 += ea * (bf_hi(vp.z) + e5);
            a6 += ea * (bf_lo(vp.w) + e6);
            a7 += ea * (bf_hi(vp.w) + e7);
            den += ea;
        }
        // combine the four quarter-wave edge streams
#pragma unroll
        for (int off = 16; off <= 32; off <<= 1) {
            a0 += __shfl_xor(a0, off, 64);
            a1 += __shfl_xor(a1, off, 64);
            a2 += __shfl_xor(a2, off, 64);
            a3 += __shfl_xor(a3, off, 64);
            a4 += __shfl_xor(a4, off, 64);
            a5 += __shfl_xor(a5, off, 64);
            a6 += __shfl_xor(a6, off, 64);
            a7 += __shfl_xor(a7, off, 64);
            den += __shfl_xor(den, off, 64);
        }
        float r = 1.0f / (den + 1e-16f);
        if (q4 == 0) {
            uint4 sp = *(const uint4*)&skipb16[(size_t)node * DMODEL + c0];
            uint4 o;
            o.x = pack_bf16x2(a0 * r + bf_lo(sp.x), a1 * r + bf_hi(sp.x));
            o.y = pack_bf16x2(a2 * r + bf_lo(sp.y), a3 * r + bf_hi(sp.y));
            o.z = pack_bf16x2(a4 * r + bf_lo(sp.z), a5 * r + bf_hi(sp.z));
            o.w = pack_bf16x2(a6 * r + bf_lo(sp.w), a7 * r + bf_hi(sp.w));
            *(uint4*)&qx[(size_t)node * DMODEL + c0] = o;
        }
    }
}

// -------------------------------------------------------------------------
// Kernel (MFMA): FFN on xs16 (= agg_norm + skip, bf16) + transposed write.
// -------------------------------------------------------------------------
#define H1_OFF 16384

__global__ __launch_bounds__(256) void k_ffn_mfma(
    const unsigned short* __restrict__ xs16,
    const uint4* __restrict__ w1f, const float* __restrict__ b1,
    const uint4* __restrict__ w2f, const float* __restrict__ b2,
    float* __restrict__ out)
{
    __shared__ __align__(16) char lds[49152];
    const int tid   = threadIdx.x;
    const int node0 = blockIdx.x * 64;

#pragma unroll
    for (int i = 0; i < 4; ++i) {
        int linear = i * 256 + tid;            // 0..1023
        int row = linear >> 4;                 // 0..63
        int c8  = (linear & 15) * 8;
        int node = node0 + row;
        uint4 vv = (node < NB) ? *(const uint4*)&xs16[(size_t)node * DMODEL + c8]
                               : make_uint4(0, 0, 0, 0);
        int byte = row * 256 + ((c8 * 2) ^ ((row & 7) << 4));
        *(uint4*)(&lds[byte]) = vv;
    }
    __syncthreads();

    const int w = tid >> 6, lane = tid & 63;
    const int rl = lane & 15, g = lane >> 4;

    // ---- GEMM1: wave w covers col1 in [w*64, w*64+64)
    {
        f32x4 acc[4][4] = {};
#pragma unroll
        for (int ks = 0; ks < 4; ++ks) {
            bf16x8 a[4], b[4];
#pragma unroll
            for (int mt = 0; mt < 4; ++mt) {
                int m1 = w * 4 + mt;
                a[mt] = *(const bf16x8*)&w1f[(m1 * 4 + ks) * 64 + lane];
            }
#pragma unroll
            for (int nt = 0; nt < 4; ++nt) {
                int node = nt * 16 + rl;
                int byte = node * 256 + ((ks * 64 + g * 16) ^ ((node & 7) << 4));
                b[nt] = *(const bf16x8*)&lds[byte];
            }
#pragma unroll
            for (int mt = 0; mt < 4; ++mt)
#pragma unroll
                for (int nt = 0; nt < 4; ++nt)
                    acc[mt][nt] = __builtin_amdgcn_mfma_f32_16x16x32_bf16(
                        a[mt], b[nt], acc[mt][nt], 0, 0, 0);
        }
#pragma unroll
        for (int mt = 0; mt < 4; ++mt) {
            int col1_0 = w * 64 + mt * 16 + g * 4;
            float bb0 = b1[col1_0], bb1 = b1[col1_0 + 1],
                  bb2 = b1[col1_0 + 2], bb3 = b1[col1_0 + 3];
#pragma unroll
            for (int nt = 0; nt < 4; ++nt) {
                int node = nt * 16 + rl;
                float v0 = fmaxf(acc[mt][nt][0] + bb0, 0.f);
                float v1 = fmaxf(acc[mt][nt][1] + bb1, 0.f);
                float v2 = fmaxf(acc[mt][nt][2] + bb2, 0.f);
                float v3 = fmaxf(acc[mt][nt][3] + bb3, 0.f);
                unsigned lo = pack_bf16x2(v0, v1), hi = pack_bf16x2(v2, v3);
                int byte = H1_OFF + node * 512 + ((col1_0 * 2) ^ ((node & 7) << 4));
                *(uint2*)(&lds[byte]) = make_uint2(lo, hi);
            }
        }
    }
    __syncthreads();

    // ---- GEMM2: wave w covers c2 in [w*32, w*32+32)
    {
        f32x4 acc[2][4] = {};
#pragma unroll
        for (int ks = 0; ks < 8; ++ks) {
            bf16x8 a[2], b[4];
#pragma unroll
            for (int mt = 0; mt < 2; ++mt) {
                int m2 = w * 2 + mt;
                a[mt] = *(const bf16x8*)&w2f[(m2 * 8 + ks) * 64 + lane];
            }
#pragma unroll
            for (int nt = 0; nt < 4; ++nt) {
                int node = nt * 16 + rl;
                int byte = H1_OFF + node * 512 + ((ks * 64 + g * 16) ^ ((node & 7) << 4));
                b[nt] = *(const bf16x8*)&lds[byte];
            }
#pragma unroll
            for (int mt = 0; mt < 2; ++mt)
#pragma unroll
                for (int nt = 0; nt < 4; ++nt)
                    acc[mt][nt] = __builtin_amdgcn_mfma_f32_16x16x32_bf16(
                        a[mt], b[nt], acc[mt][nt], 0, 0, 0);
        }
#pragma unroll
        for (int mt = 0; mt < 2; ++mt) {
            int c2_0 = w * 32 + mt * 16 + g * 4;
#pragma unroll
            for (int nt = 0; nt < 4; ++nt) {
                int node = node0 + nt * 16 + rl;
                if (node < NB) {
                    int bb = node / NPB;
                    int nn = node - bb * NPB;
                    size_t base = (size_t)(bb * DMODEL) * NPB + nn;
#pragma unroll
                    for (int r = 0; r < 4; ++r) {
                        float v = fmaxf(acc[mt][nt][r] + b2[c2_0 + r], 0.f);
                        out[base + (size_t)(c2_0 + r) * NPB] = v;
                    }
                }
            }
        }
    }
}

// -------------------------------------------------------------------------
extern "C" void kernel_launch(void* const* d_in, const int* in_sizes, int n_in,
                              void* d_out, int out_size, void* d_ws, size_t ws_size,
                              hipStream_t stream)
{
    const float* x     = (const float*)d_in[0];
    const int*   eidx  = (const int*)  d_in[1];
    const float* eattr = (const float*)d_in[2];
    const float* Wq    = (const float*)d_in[3];
    const float* bq    = (const float*)d_in[4];
    const float* Wk    = (const float*)d_in[5];
    const float* bk    = (const float*)d_in[6];
    const float* Wv    = (const float*)d_in[7];
    const float* bv    = (const float*)d_in[8];
    const float* We    = (const float*)d_in[9];
    const float* Wskip = (const float*)d_in[10];
    const float* bskip = (const float*)d_in[11];
    const float* W1    = (const float*)d_in[12];
    const float* b1    = (const float*)d_in[13];
    const float* W2    = (const float*)d_in[14];
    const float* b2    = (const float*)d_in[15];
    float* out = (float*)d_out;

    // ws layout (~212.7 MB):
    // qb16(->xs16) | kvb (k|v interleaved) | skipb16 | eb fp8 | w1f | w2f |
    // wef | wpf | counts | row_start | cursor | elist2 | bsum
    const size_t NBD = (size_t)NB * DMODEL;
    unsigned short* qb16    = (unsigned short*)d_ws;
    unsigned short* kvb     = qb16 + NBD;
    unsigned short* skipb16 = kvb + 2 * NBD;
    unsigned char*  eb      = (unsigned char*)(skipb16 + NBD);
    uint4* w1f = (uint4*)(eb + (size_t)T_E * DMODEL);
    uint4* w2f = w1f + 64 * 64;
    uint4* wef = w2f + 64 * 64;
    uint4* wpf = wef + 8 * 64;
    int* counts    = (int*)(wpf + 128 * 64);
    int* row_start = counts + NB;
    int* cursor    = row_start + NB;
    int2* elist2   = (int2*)(cursor + NB);
    int* bsum      = (int*)(elist2 + T_E);

    hipMemsetAsync(counts, 0, NB * sizeof(int), stream);
    k_prep<<<66, 256, 0, stream>>>(W1, W2, We, Wq, Wk, Wv, Wskip,
                                   w1f, w2f, wef, wpf);
    k_proj2<<<(NB + 63) / 64, 256, 0, stream>>>(x, wpf, bq, bk, bv, bskip,
                                                qb16, kvb, skipb16);
    k_hist<<<(T_E + 255) / 256, 256, 0, stream>>>(eidx, counts);
    k_scan1<<<SCAN_NBLK, 1024, 0, stream>>>(counts, row_start, bsum);
    k_scan2<<<1, 128, 0, stream>>>(bsum);
    k_scan3<<<SCAN_NBLK, 1024, 0, stream>>>(row_start, bsum, cursor);
    k_scatter<<<(T_E + 255) / 256, 256, 0, stream>>>(eidx, cursor, elist2);
    k_eproj<<<2048, 256, 0, stream>>>(eattr, wef, eb);
    k_aggr3<<<2048, 256, 0, stream>>>(qb16, kvb, skipb16, eb, elist2,
                                      row_start, cursor);
    k_ffn_mfma<<<(NB + 63) / 64, 256, 0, stream>>>(qb16, w1f, b1, w2f, b2, out);
}

// Round 10
// 363.643 us; speedup vs baseline: 2.3520x; 1.0151x over previous
//
#include <hip/hip_runtime.h>
#include <hip/hip_bf16.h>

// Problem constants (from reference)
#define NB      100000    // B*N nodes
#define NPB     25000     // N per batch
#define T_E     800000    // B*E total edges
#define EPG     200000    // E per graph
#define DMODEL  128       // OUT = H*DH
#define EDIM    32
#define FFD     256
#define SCAN_NBLK 98      // ceil(NB/1024)

typedef __attribute__((ext_vector_type(8))) short bf16x8;
typedef __attribute__((ext_vector_type(4))) float f32x4;

__device__ inline unsigned short f2bf(float f) {
    unsigned u = __float_as_uint(f);
    unsigned r = u + 0x7fffu + ((u >> 16) & 1u);   // RNE
    return (unsigned short)(r >> 16);
}
__device__ inline unsigned pack_bf16x2(float lo, float hi) {
    return (unsigned)f2bf(lo) | ((unsigned)f2bf(hi) << 16);
}
__device__ inline float bf_lo(unsigned p) { return __uint_as_float(p << 16); }
__device__ inline float bf_hi(unsigned p) { return __uint_as_float(p & 0xffff0000u); }

// -------------------------------------------------------------------------
// Kernel: pre-pack weights into MFMA fragment layout (bf16).
// 0..63 w1f | 64..127 w2f | 128..255 wpf (Wq,Wk,Wv,Wskip) |
// 256..287 wbdf (block-diag We, for sE@We) | 288..319 wetf (block-diag We^T)
// -------------------------------------------------------------------------
__global__ __launch_bounds__(256) void k_prep(
    const float* __restrict__ W1, const float* __restrict__ W2,
    const float* __restrict__ We,
    const float* __restrict__ Wq, const float* __restrict__ Wk,
    const float* __restrict__ Wv, const float* __restrict__ Wskip,
    uint4* __restrict__ w1f, uint4* __restrict__ w2f,
    uint4* __restrict__ wpf, uint4* __restrict__ wbdf, uint4* __restrict__ wetf)
{
    int t = blockIdx.x * 256 + threadIdx.x;   // 0..20479
    int lane = t & 63;
    int frag = t >> 6;                         // 0..319
    if (frag >= 320) return;
    int rl = lane & 15, g = lane >> 4;
    unsigned v[4];
    if (frag < 64) {
        int m1 = frag >> 2, ks = frag & 3;
        int col1 = m1 * 16 + rl;
        int k0 = ks * 32 + g * 8;
#pragma unroll
        for (int j2 = 0; j2 < 4; ++j2) {
            float f0 = W1[(k0 + 2 * j2) * FFD + col1];
            float f1 = W1[(k0 + 2 * j2 + 1) * FFD + col1];
            v[j2] = pack_bf16x2(f0, f1);
        }
        w1f[frag * 64 + lane] = make_uint4(v[0], v[1], v[2], v[3]);
    } else if (frag < 128) {
        int f2 = frag - 64;
        int m2 = f2 >> 3, ks = f2 & 7;
        int c2 = m2 * 16 + rl;
        int k0 = ks * 32 + g * 8;
#pragma unroll
        for (int j2 = 0; j2 < 4; ++j2) {
            float f0 = W2[(k0 + 2 * j2) * DMODEL + c2];
            float f1 = W2[(k0 + 2 * j2 + 1) * DMODEL + c2];
            v[j2] = pack_bf16x2(f0, f1);
        }
        w2f[f2 * 64 + lane] = make_uint4(v[0], v[1], v[2], v[3]);
    } else if (frag < 256) {
        int fi = frag - 128;                   // 0..127
        int m  = fi >> 5;                      // matrix 0..3
        int r  = fi & 31;
        int ct = r >> 2, ks = r & 3;
        const float* W = (m == 0) ? Wq : (m == 1) ? Wk : (m == 2) ? Wv : Wskip;
        int col = ct * 16 + rl;
        int k0  = ks * 32 + g * 8;
#pragma unroll
        for (int j2 = 0; j2 < 4; ++j2) {
            float f0 = W[(k0 + 2 * j2) * DMODEL + col];
            float f1 = W[(k0 + 2 * j2 + 1) * DMODEL + col];
            v[j2] = pack_bf16x2(f0, f1);
        }
        wpf[fi * 64 + lane] = make_uint4(v[0], v[1], v[2], v[3]);
    } else if (frag < 288) {
        // wbdf: Wbd[k][c] = (k>>5 == c>>5) ? We[k&31][c] : 0  (B-frag layout)
        int fi = frag - 256;
        int ct = fi >> 2, ks = fi & 3;
        int c = ct * 16 + rl;
        int k0 = ks * 32 + g * 8;
#pragma unroll
        for (int j2 = 0; j2 < 4; ++j2) {
            int ka = k0 + 2 * j2, kb = k0 + 2 * j2 + 1;
            float f0 = ((ka >> 5) == (c >> 5)) ? We[(ka & 31) * DMODEL + c] : 0.f;
            float f1 = ((kb >> 5) == (c >> 5)) ? We[(kb & 31) * DMODEL + c] : 0.f;
            v[j2] = pack_bf16x2(f0, f1);
        }
        wbdf[fi * 64 + lane] = make_uint4(v[0], v[1], v[2], v[3]);
    } else {
        // wetf: WeT[k][c] = (k>>5 == c>>5) ? We[c&31][k] : 0  (B-frag layout)
        int fi = frag - 288;
        int ct = fi >> 2, ks = fi & 3;
        int c = ct * 16 + rl;
        int k0 = ks * 32 + g * 8;
#pragma unroll
        for (int j2 = 0; j2 < 4; ++j2) {
            int ka = k0 + 2 * j2, kb = k0 + 2 * j2 + 1;
            float f0 = ((ka >> 5) == (c >> 5)) ? We[(c & 31) * DMODEL + ka] : 0.f;
            float f1 = ((kb >> 5) == (c >> 5)) ? We[(c & 31) * DMODEL + kb] : 0.f;
            v[j2] = pack_bf16x2(f0, f1);
        }
        wetf[fi * 64 + lane] = make_uint4(v[0], v[1], v[2], v[3]);
    }
}

// -------------------------------------------------------------------------
// Kernel (MFMA): node projections, phase-per-matrix with LDS-staged
// COALESCED writes, plus a qeh = q @ WeT_bd phase.
// LDS: xs @0 (16 KB), stage @16384 (16 KB).
// -------------------------------------------------------------------------
#define STG 16384

__global__ __launch_bounds__(256) void k_proj2(
    const float* __restrict__ x, const uint4* __restrict__ wpf,
    const uint4* __restrict__ wetf,
    const float* __restrict__ bq, const float* __restrict__ bk,
    const float* __restrict__ bv, const float* __restrict__ bskip,
    unsigned short* __restrict__ qb16, unsigned short* __restrict__ kvb,
    unsigned short* __restrict__ skipb16, unsigned short* __restrict__ qeh16)
{
    __shared__ __align__(16) char lds[32768];
    const int tid   = threadIdx.x;
    const int node0 = blockIdx.x * 64;

    // ---- stage xs: x[b,c,nn] -> xs[node_local][c] (bf16, swizzled)
    {
        const int nl   = tid & 63;
        const int half = tid >> 6;             // 0..3
        const int node = node0 + nl;
        const bool valid = node < NB;
        int b  = node / NPB;
        int nn = node - b * NPB;
        const float* xbase = x + (size_t)b * DMODEL * NPB + nn;
#pragma unroll
        for (int o = 0; o < 4; ++o) {
            int c0 = (half * 4 + o) * 8;
            unsigned vals[4];
#pragma unroll
            for (int j2 = 0; j2 < 4; ++j2) {
                float f0 = valid ? xbase[(size_t)(c0 + 2 * j2) * NPB] : 0.f;
                float f1 = valid ? xbase[(size_t)(c0 + 2 * j2 + 1) * NPB] : 0.f;
                vals[j2] = pack_bf16x2(f0, f1);
            }
            int byte = nl * 256 + ((c0 * 2) ^ ((nl & 7) << 4));
            *(uint4*)(&lds[byte]) = make_uint4(vals[0], vals[1], vals[2], vals[3]);
        }
    }
    __syncthreads();

    const int w = tid >> 6, lane = tid & 63;
    const int rl = lane & 15, g = lane >> 4;

    for (int m = 0; m < 4; ++m) {
        const float* bi = (m == 0) ? bq : (m == 1) ? bk : (m == 2) ? bv : bskip;
        // ---- compute cols [w*32, w*32+32): D[col][node], stage into LDS
#pragma unroll
        for (int ct2 = 0; ct2 < 2; ++ct2) {
            const int ct = w * 2 + ct2;
            bf16x8 A[4];
#pragma unroll
            for (int ks = 0; ks < 4; ++ks)
                A[ks] = *(const bf16x8*)&wpf[((m * 8 + ct) * 4 + ks) * 64 + lane];
            const int colb = ct * 16 + g * 4;
            const float bb0 = bi[colb], bb1 = bi[colb + 1],
                        bb2 = bi[colb + 2], bb3 = bi[colb + 3];
#pragma unroll
            for (int nt = 0; nt < 4; ++nt) {
                const int nl = nt * 16 + rl;
                f32x4 acc = {0.f, 0.f, 0.f, 0.f};
#pragma unroll
                for (int ks = 0; ks < 4; ++ks) {
                    bf16x8 B = *(const bf16x8*)(&lds[nl * 256 +
                                  ((ks * 64 + g * 16) ^ ((nl & 7) << 4))]);
                    acc = __builtin_amdgcn_mfma_f32_16x16x32_bf16(A[ks], B, acc, 0, 0, 0);
                }
                unsigned lo = pack_bf16x2(acc[0] + bb0, acc[1] + bb1);
                unsigned hi = pack_bf16x2(acc[2] + bb2, acc[3] + bb3);
                int byte = STG + nl * 256 + ((colb * 2) ^ ((nl & 7) << 4));
                *(uint2*)(&lds[byte]) = make_uint2(lo, hi);
            }
        }
        __syncthreads();
        // ---- coalesced global write (full 256 B rows)
#pragma unroll
        for (int i = 0; i < 4; ++i) {
            int linear = i * 256 + tid;
            int row = linear >> 4;
            int c8  = (linear & 15) * 8;
            int node = node0 + row;
            if (node < NB) {
                uint4 vv = *(const uint4*)(&lds[STG + row * 256 +
                                ((c8 * 2) ^ ((row & 7) << 4))]);
                if (m == 0)      *(uint4*)&qb16[(size_t)node * DMODEL + c8] = vv;
                else if (m == 1) *(uint4*)&kvb[(size_t)node * 256 + c8] = vv;
                else if (m == 2) *(uint4*)&kvb[(size_t)node * 256 + 128 + c8] = vv;
                else             *(uint4*)&skipb16[(size_t)node * DMODEL + c8] = vv;
            }
        }
        __syncthreads();

        if (m == 0) {
            // ---- qeh phase: qeh = q @ WeT_bd (q still in stage LDS)
            f32x4 qacc[8] = {};
            bf16x8 QA[4];
            const int arow = w * 16 + rl;
#pragma unroll
            for (int ks = 0; ks < 4; ++ks)
                QA[ks] = *(const bf16x8*)(&lds[STG + arow * 256 +
                              ((ks * 64 + g * 16) ^ ((arow & 7) << 4))]);
#pragma unroll
            for (int ks = 0; ks < 4; ++ks)
#pragma unroll
                for (int ct = 0; ct < 8; ++ct) {
                    bf16x8 b = *(const bf16x8*)&wetf[(ct * 4 + ks) * 64 + lane];
                    qacc[ct] = __builtin_amdgcn_mfma_f32_16x16x32_bf16(QA[ks], b, qacc[ct], 0, 0, 0);
                }
            __syncthreads();       // all q reads from stage done
            // D (row=node, col) -> stage as [node][col] bf16 scalars
#pragma unroll
            for (int ct = 0; ct < 8; ++ct) {
                const int col = ct * 16 + rl;
#pragma unroll
                for (int r = 0; r < 4; ++r) {
                    const int nl = w * 16 + g * 4 + r;
                    int byte = STG + nl * 256 + ((col * 2) ^ ((nl & 7) << 4));
                    *(unsigned short*)(&lds[byte]) = f2bf(qacc[ct][r]);
                }
            }
            __syncthreads();
#pragma unroll
            for (int i = 0; i < 4; ++i) {
                int linear = i * 256 + tid;
                int row = linear >> 4;
                int c8  = (linear & 15) * 8;
                int node = node0 + row;
                if (node < NB) {
                    uint4 vv = *(const uint4*)(&lds[STG + row * 256 +
                                    ((c8 * 2) ^ ((row & 7) << 4))]);
                    *(uint4*)&qeh16[(size_t)node * DMODEL + c8] = vv;
                }
            }
            __syncthreads();
        }
    }
}

// -------------------------------------------------------------------------
// CSR build: histogram -> scan (3 kernels) -> scatter (stores (src,eid)).
// -------------------------------------------------------------------------
__global__ __launch_bounds__(256) void k_hist(
    const int* __restrict__ eidx, int* __restrict__ counts)
{
    int t = blockIdx.x * 256 + threadIdx.x;
    if (t < T_E) {
        int b = t / EPG, e = t - b * EPG;
        int dst = eidx[(size_t)(b * 2 + 1) * EPG + e];
        atomicAdd(&counts[dst], 1);
    }
}

__global__ __launch_bounds__(1024) void k_scan1(
    const int* __restrict__ counts, int* __restrict__ row_start,
    int* __restrict__ bsum)
{
    __shared__ int s[1024];
    const int tid = threadIdx.x;
    const int gid = blockIdx.x * 1024 + tid;
    int v = (gid < NB) ? counts[gid] : 0;
    s[tid] = v;
    __syncthreads();
#pragma unroll
    for (int off = 1; off < 1024; off <<= 1) {
        int tv = (tid >= off) ? s[tid - off] : 0;
        __syncthreads();
        s[tid] += tv;
        __syncthreads();
    }
    int incl = s[tid];
    if (gid < NB) row_start[gid] = incl - v;
    if (tid == 1023) bsum[blockIdx.x] = incl;
}

__global__ __launch_bounds__(128) void k_scan2(int* __restrict__ bsum)
{
    __shared__ int s[128];
    const int tid = threadIdx.x;
    int v = (tid < SCAN_NBLK) ? bsum[tid] : 0;
    s[tid] = v;
    __syncthreads();
#pragma unroll
    for (int off = 1; off < 128; off <<= 1) {
        int tv = (tid >= off) ? s[tid - off] : 0;
        __syncthreads();
        s[tid] += tv;
        __syncthreads();
    }
    if (tid < SCAN_NBLK) bsum[tid] = s[tid] - v;
}

__global__ __launch_bounds__(1024) void k_scan3(
    int* __restrict__ row_start, const int* __restrict__ bsum,
    int* __restrict__ cursor)
{
    const int gid = blockIdx.x * 1024 + threadIdx.x;
    if (gid < NB) {
        int v = row_start[gid] + bsum[blockIdx.x];
        row_start[gid] = v;
        cursor[gid] = v;
    }
}

__global__ __launch_bounds__(256) void k_scatter(
    const int* __restrict__ eidx, int* __restrict__ cursor,
    int2* __restrict__ elist2)
{
    int t = blockIdx.x * 256 + threadIdx.x;
    if (t < T_E) {
        int b = t / EPG, e = t - b * EPG;
        int dst = eidx[(size_t)(b * 2 + 1) * EPG + e];
        int src = eidx[(size_t)(b * 2) * EPG + e];
        int pos = atomicAdd(&cursor[dst], 1);
        elist2[pos] = make_int2(src, t);   // after: cursor[d] == row_end[d]
    }
}

// -------------------------------------------------------------------------
// Kernel: per-node gather-aggregate with the e-projection ALGEBRAIZED:
// alpha = q.k + qeh[dst,h].eattr ;  PV e-part via sE = sum(ea*eattr).
// 4 edges per wave (quarter-waves), 8 channels per lane.
// Writes xs16 = agg*r + skip (into qb16) and se16 = sE*r.
// -------------------------------------------------------------------------
__global__ __launch_bounds__(256) void k_aggr3(
    unsigned short* qx,                       // q (read) / xs16 (write) — aliased
    const unsigned short* __restrict__ kvb,
    const unsigned short* __restrict__ skipb16,
    const unsigned short* __restrict__ qeh16,
    const float* __restrict__ eattr,
    unsigned short* __restrict__ se16,
    const int2* __restrict__ elist2,
    const int* __restrict__ row_start, const int* __restrict__ row_end)
{
    const int tid = threadIdx.x;
    const int w = tid >> 6, l = tid & 63;
    const int q4 = l >> 4;                    // which edge of the quad
    const int li = l & 15;
    const int c0 = li * 8;                    // this lane's 8 channels
    const int ed0 = (li & 3) * 8;             // this lane's 8 eattr dims

    const int nwaves = gridDim.x * 4;
    for (int node = blockIdx.x * 4 + w; node < NB; node += nwaves) {
        const int rs = row_start[node];
        const int re = row_end[node];
        uint4 qp  = *(const uint4*)&qx[(size_t)node * DMODEL + c0];
        uint4 qep = *(const uint4*)&qeh16[(size_t)node * DMODEL + c0];
        const float q0 = bf_lo(qp.x), q1 = bf_hi(qp.x);
        const float q2 = bf_lo(qp.y), q3 = bf_hi(qp.y);
        const float q4_ = bf_lo(qp.z), q5 = bf_hi(qp.z);
        const float q6 = bf_lo(qp.w), q7 = bf_hi(qp.w);
        const float qe0 = bf_lo(qep.x), qe1 = bf_hi(qep.x);
        const float qe2 = bf_lo(qep.y), qe3 = bf_hi(qep.y);
        const float qe4 = bf_lo(qep.z), qe5 = bf_hi(qep.z);
        const float qe6 = bf_lo(qep.w), qe7 = bf_hi(qep.w);
        float a0 = 0.f, a1 = 0.f, a2 = 0.f, a3 = 0.f;
        float a4 = 0.f, a5 = 0.f, a6 = 0.f, a7 = 0.f;
        float s0 = 0.f, s1 = 0.f, s2 = 0.f, s3 = 0.f;
        float s4 = 0.f, s5 = 0.f, s6 = 0.f, s7 = 0.f, den = 0.f;

        for (int j0 = rs; j0 < re; j0 += 4) {
            const int jc = j0 + q4;
            const bool act = jc < re;          // uniform across the 16-lane group
            uint4 kp = make_uint4(0, 0, 0, 0), vp = make_uint4(0, 0, 0, 0);
            float4 ef0 = make_float4(0.f, 0.f, 0.f, 0.f);
            float4 ef1 = make_float4(0.f, 0.f, 0.f, 0.f);
            if (act) {
                int2 se = elist2[jc];                   // (src, eid)
                kp = *(const uint4*)&kvb[(size_t)se.x * 256 + c0];
                vp = *(const uint4*)&kvb[(size_t)se.x * 256 + 128 + c0];
                const float* ep = &eattr[(size_t)se.y * EDIM + ed0];
                ef0 = *(const float4*)ep;
                ef1 = *(const float4*)(ep + 4);
            }
            float p = q0 * bf_lo(kp.x) + q1 * bf_hi(kp.x)
                    + q2 * bf_lo(kp.y) + q3 * bf_hi(kp.y)
                    + q4_ * bf_lo(kp.z) + q5 * bf_hi(kp.z)
                    + q6 * bf_lo(kp.w) + q7 * bf_hi(kp.w)
                    + qe0 * ef0.x + qe1 * ef0.y + qe2 * ef0.z + qe3 * ef0.w
                    + qe4 * ef1.x + qe5 * ef1.y + qe6 * ef1.z + qe7 * ef1.w;
            // reduce over the 4 lanes of this head group
            p += __shfl_xor(p, 1, 64);
            p += __shfl_xor(p, 2, 64);
            float ea = act ? __expf(p * 0.17677669529663689f) : 0.f;  // 1/sqrt(32)
            a0 += ea * bf_lo(vp.x);  a1 += ea * bf_hi(vp.x);
            a2 += ea * bf_lo(vp.y);  a3 += ea * bf_hi(vp.y);
            a4 += ea * bf_lo(vp.z);  a5 += ea * bf_hi(vp.z);
            a6 += ea * bf_lo(vp.w);  a7 += ea * bf_hi(vp.w);
            s0 += ea * ef0.x;  s1 += ea * ef0.y;  s2 += ea * ef0.z;  s3 += ea * ef0.w;
            s4 += ea * ef1.x;  s5 += ea * ef1.y;  s6 += ea * ef1.z;  s7 += ea * ef1.w;
            den += ea;
        }
        // combine the four quarter-wave edge streams
#pragma unroll
        for (int off = 16; off <= 32; off <<= 1) {
            a0 += __shfl_xor(a0, off, 64);  a1 += __shfl_xor(a1, off, 64);
            a2 += __shfl_xor(a2, off, 64);  a3 += __shfl_xor(a3, off, 64);
            a4 += __shfl_xor(a4, off, 64);  a5 += __shfl_xor(a5, off, 64);
            a6 += __shfl_xor(a6, off, 64);  a7 += __shfl_xor(a7, off, 64);
            s0 += __shfl_xor(s0, off, 64);  s1 += __shfl_xor(s1, off, 64);
            s2 += __shfl_xor(s2, off, 64);  s3 += __shfl_xor(s3, off, 64);
            s4 += __shfl_xor(s4, off, 64);  s5 += __shfl_xor(s5, off, 64);
            s6 += __shfl_xor(s6, off, 64);  s7 += __shfl_xor(s7, off, 64);
            den += __shfl_xor(den, off, 64);
        }
        float r = 1.0f / (den + 1e-16f);
        if (q4 == 0) {
            uint4 sp = *(const uint4*)&skipb16[(size_t)node * DMODEL + c0];
            uint4 o;
            o.x = pack_bf16x2(a0 * r + bf_lo(sp.x), a1 * r + bf_hi(sp.x));
            o.y = pack_bf16x2(a2 * r + bf_lo(sp.y), a3 * r + bf_hi(sp.y));
            o.z = pack_bf16x2(a4 * r + bf_lo(sp.z), a5 * r + bf_hi(sp.z));
            o.w = pack_bf16x2(a6 * r + bf_lo(sp.w), a7 * r + bf_hi(sp.w));
            *(uint4*)&qx[(size_t)node * DMODEL + c0] = o;
            uint4 so;
            so.x = pack_bf16x2(s0 * r, s1 * r);
            so.y = pack_bf16x2(s2 * r, s3 * r);
            so.z = pack_bf16x2(s4 * r, s5 * r);
            so.w = pack_bf16x2(s6 * r, s7 * r);
            *(uint4*)&se16[(size_t)node * DMODEL + c0] = so;   // layout [h*32+d]
        }
    }
}

// -------------------------------------------------------------------------
// Kernel (MFMA): GEMM0 (sE @ Wbd, RMW'd into xs) + FFN + transposed write.
// LDS: xs @0 (16 KB), sE/h1 @16384 (sE dead before h1 writes).
// -------------------------------------------------------------------------
#define H1_OFF 16384

__global__ __launch_bounds__(256) void k_ffn_mfma(
    const unsigned short* __restrict__ xs16,
    const unsigned short* __restrict__ se16,
    const uint4* __restrict__ w1f, const float* __restrict__ b1,
    const uint4* __restrict__ w2f, const float* __restrict__ b2,
    const uint4* __restrict__ wbdf,
    float* __restrict__ out)
{
    __shared__ __align__(16) char lds[49152];
    const int tid   = threadIdx.x;
    const int node0 = blockIdx.x * 64;

    // ---- stage xs @0 and sE @16384 (bf16 swizzled)
#pragma unroll
    for (int i = 0; i < 4; ++i) {
        int linear = i * 256 + tid;
        int row = linear >> 4;
        int c8  = (linear & 15) * 8;
        int node = node0 + row;
        uint4 xv = (node < NB) ? *(const uint4*)&xs16[(size_t)node * DMODEL + c8]
                               : make_uint4(0, 0, 0, 0);
        uint4 sv = (node < NB) ? *(const uint4*)&se16[(size_t)node * DMODEL + c8]
                               : make_uint4(0, 0, 0, 0);
        int off = row * 256 + ((c8 * 2) ^ ((row & 7) << 4));
        *(uint4*)(&lds[off]) = xv;
        *(uint4*)(&lds[H1_OFF + off]) = sv;
    }
    __syncthreads();

    const int w = tid >> 6, lane = tid & 63;
    const int rl = lane & 15, g = lane >> 4;

    // ---- GEMM0: D[node][col] = sE @ Wbd ; RMW into xs LDS
    {
        f32x4 acc0[8] = {};
        bf16x8 A0[4];
        const int arow = w * 16 + rl;
#pragma unroll
        for (int ks = 0; ks < 4; ++ks)
            A0[ks] = *(const bf16x8*)(&lds[H1_OFF + arow * 256 +
                          ((ks * 64 + g * 16) ^ ((arow & 7) << 4))]);
#pragma unroll
        for (int ks = 0; ks < 4; ++ks)
#pragma unroll
            for (int ct = 0; ct < 8; ++ct) {
                bf16x8 b = *(const bf16x8*)&wbdf[(ct * 4 + ks) * 64 + lane];
                acc0[ct] = __builtin_amdgcn_mfma_f32_16x16x32_bf16(A0[ks], b, acc0[ct], 0, 0, 0);
            }
#pragma unroll
        for (int ct = 0; ct < 8; ++ct) {
            const int col = ct * 16 + rl;
#pragma unroll
            for (int r = 0; r < 4; ++r) {
                const int nl = w * 16 + g * 4 + r;
                int byte = nl * 256 + ((col * 2) ^ ((nl & 7) << 4));
                unsigned short* p = (unsigned short*)&lds[byte];
                float xv = __uint_as_float(((unsigned)*p) << 16);
                *p = f2bf(xv + acc0[ct][r]);
            }
        }
    }
    __syncthreads();

    // ---- GEMM1: wave w covers col1 in [w*64, w*64+64)
    {
        f32x4 acc[4][4] = {};
#pragma unroll
        for (int ks = 0; ks < 4; ++ks) {
            bf16x8 a[4], b[4];
#pragma unroll
            for (int mt = 0; mt < 4; ++mt) {
                int m1 = w * 4 + mt;
                a[mt] = *(const bf16x8*)&w1f[(m1 * 4 + ks) * 64 + lane];
            }
#pragma unroll
            for (int nt = 0; nt < 4; ++nt) {
                int node = nt * 16 + rl;
                int byte = node * 256 + ((ks * 64 + g * 16) ^ ((node & 7) << 4));
                b[nt] = *(const bf16x8*)&lds[byte];
            }
#pragma unroll
            for (int mt = 0; mt < 4; ++mt)
#pragma unroll
                for (int nt = 0; nt < 4; ++nt)
                    acc[mt][nt] = __builtin_amdgcn_mfma_f32_16x16x32_bf16(
                        a[mt], b[nt], acc[mt][nt], 0, 0, 0);
        }
#pragma unroll
        for (int mt = 0; mt < 4; ++mt) {
            int col1_0 = w * 64 + mt * 16 + g * 4;
            float bb0 = b1[col1_0], bb1 = b1[col1_0 + 1],
                  bb2 = b1[col1_0 + 2], bb3 = b1[col1_0 + 3];
#pragma unroll
            for (int nt = 0; nt < 4; ++nt) {
                int node = nt * 16 + rl;
                float v0 = fmaxf(acc[mt][nt][0] + bb0, 0.f);
                float v1 = fmaxf(acc[mt][nt][1] + bb1, 0.f);
                float v2 = fmaxf(acc[mt][nt][2] + bb2, 0.f);
                float v3 = fmaxf(acc[mt][nt][3] + bb3, 0.f);
                unsigned lo = pack_bf16x2(v0, v1), hi = pack_bf16x2(v2, v3);
                int byte = H1_OFF + node * 512 + ((col1_0 * 2) ^ ((node & 7) << 4));
                *(uint2*)(&lds[byte]) = make_uint2(lo, hi);
            }
        }
    }
    __syncthreads();

    // ---- GEMM2: wave w covers c2 in [w*32, w*32+32)
    {
        f32x4 acc[2][4] = {};
#pragma unroll
        for (int ks = 0; ks < 8; ++ks) {
            bf16x8 a[2], b[4];
#pragma unroll
            for (int mt = 0; mt < 2; ++mt) {
                int m2 = w * 2 + mt;
                a[mt] = *(const bf16x8*)&w2f[(m2 * 8 + ks) * 64 + lane];
            }
#pragma unroll
            for (int nt = 0; nt < 4; ++nt) {
                int node = nt * 16 + rl;
                int byte = H1_OFF + node * 512 + ((ks * 64 + g * 16) ^ ((node & 7) << 4));
                b[nt] = *(const bf16x8*)&lds[byte];
            }
#pragma unroll
            for (int mt = 0; mt < 2; ++mt)
#pragma unroll
                for (int nt = 0; nt < 4; ++nt)
                    acc[mt][nt] = __builtin_amdgcn_mfma_f32_16x16x32_bf16(
                        a[mt], b[nt], acc[mt][nt], 0, 0, 0);
        }
#pragma unroll
        for (int mt = 0; mt < 2; ++mt) {
            int c2_0 = w * 32 + mt * 16 + g * 4;
#pragma unroll
            for (int nt = 0; nt < 4; ++nt) {
                int node = node0 + nt * 16 + rl;
                if (node < NB) {
                    int bb = node / NPB;
                    int nn = node - bb * NPB;
                    size_t base = (size_t)(bb * DMODEL) * NPB + nn;
#pragma unroll
                    for (int r = 0; r < 4; ++r) {
                        float v = fmaxf(acc[mt][nt][r] + b2[c2_0 + r], 0.f);
                        out[base + (size_t)(c2_0 + r) * NPB] = v;
                    }
                }
            }
        }
    }
}

// -------------------------------------------------------------------------
extern "C" void kernel_launch(void* const* d_in, const int* in_sizes, int n_in,
                              void* d_out, int out_size, void* d_ws, size_t ws_size,
                              hipStream_t stream)
{
    const float* x     = (const float*)d_in[0];
    const int*   eidx  = (const int*)  d_in[1];
    const float* eattr = (const float*)d_in[2];
    const float* Wq    = (const float*)d_in[3];
    const float* bq    = (const float*)d_in[4];
    const float* Wk    = (const float*)d_in[5];
    const float* bk    = (const float*)d_in[6];
    const float* Wv    = (const float*)d_in[7];
    const float* bv    = (const float*)d_in[8];
    const float* We    = (const float*)d_in[9];
    const float* Wskip = (const float*)d_in[10];
    const float* bskip = (const float*)d_in[11];
    const float* W1    = (const float*)d_in[12];
    const float* b1    = (const float*)d_in[13];
    const float* W2    = (const float*)d_in[14];
    const float* b2    = (const float*)d_in[15];
    float* out = (float*)d_out;

    // ws layout (~175 MB): qb16(->xs16) | kvb | skipb16 | qeh16 | se16 |
    // w1f | w2f | wpf | wbdf | wetf | counts | row_start | cursor | elist2 | bsum
    const size_t NBD = (size_t)NB * DMODEL;
    unsigned short* qb16    = (unsigned short*)d_ws;
    unsigned short* kvb     = qb16 + NBD;
    unsigned short* skipb16 = kvb + 2 * NBD;
    unsigned short* qeh16   = skipb16 + NBD;
    unsigned short* se16    = qeh16 + NBD;
    uint4* w1f  = (uint4*)(se16 + NBD);
    uint4* w2f  = w1f + 64 * 64;
    uint4* wpf  = w2f + 64 * 64;
    uint4* wbdf = wpf + 128 * 64;
    uint4* wetf = wbdf + 32 * 64;
    int* counts    = (int*)(wetf + 32 * 64);
    int* row_start = counts + NB;
    int* cursor    = row_start + NB;
    int2* elist2   = (int2*)(cursor + NB);
    int* bsum      = (int*)(elist2 + T_E);

    hipMemsetAsync(counts, 0, NB * sizeof(int), stream);
    k_prep<<<80, 256, 0, stream>>>(W1, W2, We, Wq, Wk, Wv, Wskip,
                                   w1f, w2f, wpf, wbdf, wetf);
    k_proj2<<<(NB + 63) / 64, 256, 0, stream>>>(x, wpf, wetf, bq, bk, bv, bskip,
                                                qb16, kvb, skipb16, qeh16);
    k_hist<<<(T_E + 255) / 256, 256, 0, stream>>>(eidx, counts);
    k_scan1<<<SCAN_NBLK, 1024, 0, stream>>>(counts, row_start, bsum);
    k_scan2<<<1, 128, 0, stream>>>(bsum);
    k_scan3<<<SCAN_NBLK, 1024, 0, stream>>>(row_start, bsum, cursor);
    k_scatter<<<(T_E + 255) / 256, 256, 0, stream>>>(eidx, cursor, elist2);
    k_aggr3<<<2048, 256, 0, stream>>>(qb16, kvb, skipb16, qeh16, eattr, se16,
                                      elist2, row_start, cursor);
    k_ffn_mfma<<<(NB + 63) / 64, 256, 0, stream>>>(qb16, se16, w1f, b1, w2f, b2,
                                                   wbdf, out);
}

// Round 11
// 340.330 us; speedup vs baseline: 2.5132x; 1.0685x over previous
//
#include <hip/hip_runtime.h>
#include <hip/hip_bf16.h>

// Problem constants (from reference)
#define NB      100000    // B*N nodes
#define NPB     25000     // N per batch
#define T_E     800000    // B*E total edges
#define EPG     200000    // E per graph
#define DMODEL  128       // OUT = H*DH
#define EDIM    32
#define FFD     256
#define SCAN_NBLK 98      // ceil(NB/1024)

typedef __attribute__((ext_vector_type(8))) short bf16x8;
typedef __attribute__((ext_vector_type(4))) float f32x4;
typedef __attribute__((ext_vector_type(2))) float f32x2;

__device__ inline unsigned short f2bf(float f) {
    unsigned u = __float_as_uint(f);
    unsigned r = u + 0x7fffu + ((u >> 16) & 1u);   // RNE
    return (unsigned short)(r >> 16);
}
__device__ inline unsigned pack_bf16x2(float lo, float hi) {
    return (unsigned)f2bf(lo) | ((unsigned)f2bf(hi) << 16);
}
__device__ inline float bf_lo(unsigned p) { return __uint_as_float(p << 16); }
__device__ inline float bf_hi(unsigned p) { return __uint_as_float(p & 0xffff0000u); }

// -------------------------------------------------------------------------
// Kernel: pre-pack weights into MFMA A-fragment layout (bf16).
// frags 0..63 w1f | 64..127 w2f | 128..135 wef | 136..263 wpf (Wq,Wk,Wv,Wskip)
// -------------------------------------------------------------------------
__global__ __launch_bounds__(256) void k_prep(
    const float* __restrict__ W1, const float* __restrict__ W2,
    const float* __restrict__ We,
    const float* __restrict__ Wq, const float* __restrict__ Wk,
    const float* __restrict__ Wv, const float* __restrict__ Wskip,
    uint4* __restrict__ w1f, uint4* __restrict__ w2f,
    uint4* __restrict__ wef, uint4* __restrict__ wpf)
{
    int t = blockIdx.x * 256 + threadIdx.x;   // 0..16895
    int lane = t & 63;
    int frag = t >> 6;                         // 0..263
    if (frag >= 264) return;
    int rl = lane & 15, g = lane >> 4;
    unsigned v[4];
    if (frag < 64) {
        int m1 = frag >> 2, ks = frag & 3;
        int col1 = m1 * 16 + rl;
        int k0 = ks * 32 + g * 8;
#pragma unroll
        for (int j2 = 0; j2 < 4; ++j2) {
            float f0 = W1[(k0 + 2 * j2) * FFD + col1];
            float f1 = W1[(k0 + 2 * j2 + 1) * FFD + col1];
            v[j2] = pack_bf16x2(f0, f1);
        }
        w1f[frag * 64 + lane] = make_uint4(v[0], v[1], v[2], v[3]);
    } else if (frag < 128) {
        int f2 = frag - 64;
        int m2 = f2 >> 3, ks = f2 & 7;
        int c2 = m2 * 16 + rl;
        int k0 = ks * 32 + g * 8;
#pragma unroll
        for (int j2 = 0; j2 < 4; ++j2) {
            float f0 = W2[(k0 + 2 * j2) * DMODEL + c2];
            float f1 = W2[(k0 + 2 * j2 + 1) * DMODEL + c2];
            v[j2] = pack_bf16x2(f0, f1);
        }
        w2f[f2 * 64 + lane] = make_uint4(v[0], v[1], v[2], v[3]);
    } else if (frag < 136) {
        int m = frag - 128;                    // 0..7
        int ocol = m * 16 + rl;
        int k0 = g * 8;
#pragma unroll
        for (int j2 = 0; j2 < 4; ++j2) {
            float f0 = We[(k0 + 2 * j2) * DMODEL + ocol];
            float f1 = We[(k0 + 2 * j2 + 1) * DMODEL + ocol];
            v[j2] = pack_bf16x2(f0, f1);
        }
        wef[m * 64 + lane] = make_uint4(v[0], v[1], v[2], v[3]);
    } else {
        int fi = frag - 136;                   // 0..127
        int m  = fi >> 5;                      // matrix 0..3
        int r  = fi & 31;
        int ct = r >> 2, ks = r & 3;
        const float* W = (m == 0) ? Wq : (m == 1) ? Wk : (m == 2) ? Wv : Wskip;
        int col = ct * 16 + rl;
        int k0  = ks * 32 + g * 8;
#pragma unroll
        for (int j2 = 0; j2 < 4; ++j2) {
            float f0 = W[(k0 + 2 * j2) * DMODEL + col];
            float f1 = W[(k0 + 2 * j2 + 1) * DMODEL + col];
            v[j2] = pack_bf16x2(f0, f1);
        }
        wpf[fi * 64 + lane] = make_uint4(v[0], v[1], v[2], v[3]);
    }
}

// -------------------------------------------------------------------------
// Kernel (MFMA): node projections, phase-per-matrix with LDS-staged
// COALESCED global writes.  LDS: xs @0 (16 KB), stage @16384 (16 KB).
// -------------------------------------------------------------------------
#define STG 16384

__global__ __launch_bounds__(256) void k_proj2(
    const float* __restrict__ x, const uint4* __restrict__ wpf,
    const float* __restrict__ bq, const float* __restrict__ bk,
    const float* __restrict__ bv, const float* __restrict__ bskip,
    unsigned short* __restrict__ qb16, unsigned short* __restrict__ kvb,
    unsigned short* __restrict__ skipb16)
{
    __shared__ __align__(16) char lds[32768];
    const int tid   = threadIdx.x;
    const int node0 = blockIdx.x * 64;

    // ---- stage xs: x[b,c,nn] -> xs[node_local][c] (bf16, swizzled)
    {
        const int nl   = tid & 63;
        const int half = tid >> 6;             // 0..3
        const int node = node0 + nl;
        const bool valid = node < NB;
        int b  = node / NPB;
        int nn = node - b * NPB;
        const float* xbase = x + (size_t)b * DMODEL * NPB + nn;
#pragma unroll
        for (int o = 0; o < 4; ++o) {
            int c0 = (half * 4 + o) * 8;
            unsigned vals[4];
#pragma unroll
            for (int j2 = 0; j2 < 4; ++j2) {
                float f0 = valid ? xbase[(size_t)(c0 + 2 * j2) * NPB] : 0.f;
                float f1 = valid ? xbase[(size_t)(c0 + 2 * j2 + 1) * NPB] : 0.f;
                vals[j2] = pack_bf16x2(f0, f1);
            }
            int byte = nl * 256 + ((c0 * 2) ^ ((nl & 7) << 4));
            *(uint4*)(&lds[byte]) = make_uint4(vals[0], vals[1], vals[2], vals[3]);
        }
    }
    __syncthreads();

    const int w = tid >> 6, lane = tid & 63;
    const int rl = lane & 15, g = lane >> 4;

    for (int m = 0; m < 4; ++m) {
        const float* bi = (m == 0) ? bq : (m == 1) ? bk : (m == 2) ? bv : bskip;
        // ---- compute cols [w*32, w*32+32): D[col][node], stage into LDS
#pragma unroll
        for (int ct2 = 0; ct2 < 2; ++ct2) {
            const int ct = w * 2 + ct2;
            bf16x8 A[4];
#pragma unroll
            for (int ks = 0; ks < 4; ++ks)
                A[ks] = *(const bf16x8*)&wpf[((m * 8 + ct) * 4 + ks) * 64 + lane];
            const int colb = ct * 16 + g * 4;
            const float bb0 = bi[colb], bb1 = bi[colb + 1],
                        bb2 = bi[colb + 2], bb3 = bi[colb + 3];
#pragma unroll
            for (int nt = 0; nt < 4; ++nt) {
                const int nl = nt * 16 + rl;
                f32x4 acc = {0.f, 0.f, 0.f, 0.f};
#pragma unroll
                for (int ks = 0; ks < 4; ++ks) {
                    bf16x8 B = *(const bf16x8*)(&lds[nl * 256 +
                                  ((ks * 64 + g * 16) ^ ((nl & 7) << 4))]);
                    acc = __builtin_amdgcn_mfma_f32_16x16x32_bf16(A[ks], B, acc, 0, 0, 0);
                }
                unsigned lo = pack_bf16x2(acc[0] + bb0, acc[1] + bb1);
                unsigned hi = pack_bf16x2(acc[2] + bb2, acc[3] + bb3);
                int byte = STG + nl * 256 + ((colb * 2) ^ ((nl & 7) << 4));
                *(uint2*)(&lds[byte]) = make_uint2(lo, hi);
            }
        }
        __syncthreads();
        // ---- coalesced global write (full 256 B rows)
#pragma unroll
        for (int i = 0; i < 4; ++i) {
            int linear = i * 256 + tid;
            int row = linear >> 4;
            int c8  = (linear & 15) * 8;
            int node = node0 + row;
            if (node < NB) {
                uint4 vv = *(const uint4*)(&lds[STG + row * 256 +
                                ((c8 * 2) ^ ((row & 7) << 4))]);
                if (m == 0)      *(uint4*)&qb16[(size_t)node * DMODEL + c8] = vv;
                else if (m == 1) *(uint4*)&kvb[(size_t)node * 256 + c8] = vv;
                else if (m == 2) *(uint4*)&kvb[(size_t)node * 256 + 128 + c8] = vv;
                else             *(uint4*)&skipb16[(size_t)node * DMODEL + c8] = vv;
            }
        }
        __syncthreads();
    }
}

// -------------------------------------------------------------------------
// CSR build: histogram -> scan (3 kernels).  Scatter is fused into k_escat.
// -------------------------------------------------------------------------
__global__ __launch_bounds__(256) void k_hist(
    const int* __restrict__ eidx, int* __restrict__ counts)
{
    int t = blockIdx.x * 256 + threadIdx.x;
    if (t < T_E) {
        int b = t / EPG, e = t - b * EPG;
        int dst = eidx[(size_t)(b * 2 + 1) * EPG + e];
        atomicAdd(&counts[dst], 1);
    }
}

__global__ __launch_bounds__(1024) void k_scan1(
    const int* __restrict__ counts, int* __restrict__ row_start,
    int* __restrict__ bsum)
{
    __shared__ int s[1024];
    const int tid = threadIdx.x;
    const int gid = blockIdx.x * 1024 + tid;
    int v = (gid < NB) ? counts[gid] : 0;
    s[tid] = v;
    __syncthreads();
#pragma unroll
    for (int off = 1; off < 1024; off <<= 1) {
        int tv = (tid >= off) ? s[tid - off] : 0;
        __syncthreads();
        s[tid] += tv;
        __syncthreads();
    }
    int incl = s[tid];
    if (gid < NB) row_start[gid] = incl - v;
    if (tid == 1023) bsum[blockIdx.x] = incl;
}

__global__ __launch_bounds__(128) void k_scan2(int* __restrict__ bsum)
{
    __shared__ int s[128];
    const int tid = threadIdx.x;
    int v = (tid < SCAN_NBLK) ? bsum[tid] : 0;
    s[tid] = v;
    __syncthreads();
#pragma unroll
    for (int off = 1; off < 128; off <<= 1) {
        int tv = (tid >= off) ? s[tid - off] : 0;
        __syncthreads();
        s[tid] += tv;
        __syncthreads();
    }
    if (tid < SCAN_NBLK) bsum[tid] = s[tid] - v;
}

__global__ __launch_bounds__(1024) void k_scan3(
    int* __restrict__ row_start, const int* __restrict__ bsum,
    int* __restrict__ cursor)
{
    const int gid = blockIdx.x * 1024 + threadIdx.x;
    if (gid < NB) {
        int v = row_start[gid] + bsum[blockIdx.x];
        row_start[gid] = v;
        cursor[gid] = v;
    }
}

// -------------------------------------------------------------------------
// Kernel: FUSED e-projection (MFMA, 16-edge tiles -> eb fp8) + CSR scatter
// (lanes 0..15 place their tile's edges).  One pass over edges.
// -------------------------------------------------------------------------
__global__ __launch_bounds__(256) void k_escat(
    const float* __restrict__ eattr, const uint4* __restrict__ wef,
    const int* __restrict__ eidx, int* __restrict__ cursor,
    unsigned char* __restrict__ eb, int2* __restrict__ elist2)
{
    const int tid = threadIdx.x;
    const int w = tid >> 6, lane = tid & 63;
    const int rl = lane & 15, g = lane >> 4;

    bf16x8 a[8];
#pragma unroll
    for (int m = 0; m < 8; ++m) a[m] = *(const bf16x8*)&wef[m * 64 + lane];

    const int nwaves = gridDim.x * 4;
    for (int tile = blockIdx.x * 4 + w; tile < T_E / 16; tile += nwaves) {
        // ---- eproj: D[ocol][edge] = We^T @ eattr^T, store fp8
        const float* ep = &eattr[((size_t)tile * 16 + rl) * EDIM + g * 8];
        float4 f0 = *(const float4*)ep;
        float4 f1 = *(const float4*)(ep + 4);
        uint4 bu = make_uint4(pack_bf16x2(f0.x, f0.y), pack_bf16x2(f0.z, f0.w),
                              pack_bf16x2(f1.x, f1.y), pack_bf16x2(f1.z, f1.w));
        bf16x8 b = *(bf16x8*)&bu;
        f32x4 z = {0.f, 0.f, 0.f, 0.f};
        f32x4 acc[8];
#pragma unroll
        for (int m = 0; m < 8; ++m)
            acc[m] = __builtin_amdgcn_mfma_f32_16x16x32_bf16(a[m], b, z, 0, 0, 0);
        unsigned char* out = &eb[((size_t)tile * 16 + rl) * DMODEL + g * 4];
#pragma unroll
        for (int m = 0; m < 8; ++m) {
            unsigned d = __builtin_amdgcn_cvt_pk_fp8_f32(acc[m][0], acc[m][1], 0, false);
            d = __builtin_amdgcn_cvt_pk_fp8_f32(acc[m][2], acc[m][3], d, true);
            *(unsigned*)(out + m * 16) = d;
        }
        // ---- scatter: lanes 0..15 handle their edge of this tile
        if (g == 0) {
            int t = tile * 16 + rl;            // tiles never cross a graph (EPG%16==0)
            int bb = t / EPG, e = t - bb * EPG;
            int dst = eidx[(size_t)(bb * 2 + 1) * EPG + e];
            int src = eidx[(size_t)(bb * 2) * EPG + e];
            int pos = atomicAdd(&cursor[dst], 1);
            elist2[pos] = make_int2(src, t);   // after: cursor[d] == row_end[d]
        }
    }
}

// -------------------------------------------------------------------------
// Kernel: per-node gather-aggregate, 8 edges in flight per wave
// (2 quads of quarter-waves), 8 channels per lane, eb fp8 e-add.
// Output: xs16[node][c] = agg_norm + skip (bf16) — into qb16 space.
// -------------------------------------------------------------------------
__global__ __launch_bounds__(256) void k_aggr3(
    unsigned short* qx,                       // q (read) / xs16 (write) — aliased
    const unsigned short* __restrict__ kvb,
    const unsigned short* __restrict__ skipb16,
    const unsigned char* __restrict__ eb,
    const int2* __restrict__ elist2,
    const int* __restrict__ row_start, const int* __restrict__ row_end)
{
    const int tid = threadIdx.x;
    const int w = tid >> 6, l = tid & 63;
    const int q4 = l >> 4;                    // which edge of the quad
    const int li = l & 15;
    const int c0 = li * 8;                    // this lane's 8 channels

    const int nwaves = gridDim.x * 4;
    for (int node = blockIdx.x * 4 + w; node < NB; node += nwaves) {
        const int rs = row_start[node];
        const int re = row_end[node];
        uint4 qp = *(const uint4*)&qx[(size_t)node * DMODEL + c0];
        const float q0 = bf_lo(qp.x), q1 = bf_hi(qp.x);
        const float q2 = bf_lo(qp.y), q3 = bf_hi(qp.y);
        const float q4_ = bf_lo(qp.z), q5 = bf_hi(qp.z);
        const float q6 = bf_lo(qp.w), q7 = bf_hi(qp.w);
        float a0 = 0.f, a1 = 0.f, a2 = 0.f, a3 = 0.f;
        float a4 = 0.f, a5 = 0.f, a6 = 0.f, a7 = 0.f, den = 0.f;

        for (int j0 = rs; j0 < re; j0 += 8) {
            const int jcA = j0 + q4;
            const int jcB = j0 + 4 + q4;
            const bool actA = jcA < re;        // uniform across 16-lane group
            const bool actB = jcB < re;
            uint4 kpA = make_uint4(0,0,0,0), vpA = make_uint4(0,0,0,0);
            uint4 kpB = make_uint4(0,0,0,0), vpB = make_uint4(0,0,0,0);
            uint2 epA = make_uint2(0,0), epB = make_uint2(0,0);
            if (actA) {
                int2 se = elist2[jcA];
                kpA = *(const uint4*)&kvb[(size_t)se.x * 256 + c0];
                vpA = *(const uint4*)&kvb[(size_t)se.x * 256 + 128 + c0];
                epA = *(const uint2*)&eb[(size_t)se.y * DMODEL + c0];
            }
            if (actB) {
                int2 se = elist2[jcB];
                kpB = *(const uint4*)&kvb[(size_t)se.x * 256 + c0];
                vpB = *(const uint4*)&kvb[(size_t)se.x * 256 + 128 + c0];
                epB = *(const uint2*)&eb[(size_t)se.y * DMODEL + c0];
            }
            // ---- quad A
            {
                f32x2 exl = __builtin_amdgcn_cvt_pk_f32_fp8(epA.x, false);
                f32x2 exh = __builtin_amdgcn_cvt_pk_f32_fp8(epA.x, true);
                f32x2 eyl = __builtin_amdgcn_cvt_pk_f32_fp8(epA.y, false);
                f32x2 eyh = __builtin_amdgcn_cvt_pk_f32_fp8(epA.y, true);
                const float e0 = exl[0], e1 = exl[1], e2 = exh[0], e3 = exh[1];
                const float e4 = eyl[0], e5 = eyl[1], e6 = eyh[0], e7 = eyh[1];
                float p = q0 * (bf_lo(kpA.x) + e0) + q1 * (bf_hi(kpA.x) + e1)
                        + q2 * (bf_lo(kpA.y) + e2) + q3 * (bf_hi(kpA.y) + e3)
                        + q4_ * (bf_lo(kpA.z) + e4) + q5 * (bf_hi(kpA.z) + e5)
                        + q6 * (bf_lo(kpA.w) + e6) + q7 * (bf_hi(kpA.w) + e7);
                p += __shfl_xor(p, 1, 64);
                p += __shfl_xor(p, 2, 64);
                float ea = actA ? __expf(p * 0.17677669529663689f) : 0.f;
                a0 += ea * (bf_lo(vpA.x) + e0);  a1 += ea * (bf_hi(vpA.x) + e1);
                a2 += ea * (bf_lo(vpA.y) + e2);  a3 += ea * (bf_hi(vpA.y) + e3);
                a4 += ea * (bf_lo(vpA.z) + e4);  a5 += ea * (bf_hi(vpA.z) + e5);
                a6 += ea * (bf_lo(vpA.w) + e6);  a7 += ea * (bf_hi(vpA.w) + e7);
                den += ea;
            }
            // ---- quad B
            {
                f32x2 exl = __builtin_amdgcn_cvt_pk_f32_fp8(epB.x, false);
                f32x2 exh = __builtin_amdgcn_cvt_pk_f32_fp8(epB.x, true);
                f32x2 eyl = __builtin_amdgcn_cvt_pk_f32_fp8(epB.y, false);
                f32x2 eyh = __builtin_amdgcn_cvt_pk_f32_fp8(epB.y, true);
                const float e0 = exl[0], e1 = exl[1], e2 = exh[0], e3 = exh[1];
                const float e4 = eyl[0], e5 = eyl[1], e6 = eyh[0], e7 = eyh[1];
                float p = q0 * (bf_lo(kpB.x) + e0) + q1 * (bf_hi(kpB.x) + e1)
                        + q2 * (bf_lo(kpB.y) + e2) + q3 * (bf_hi(kpB.y) + e3)
                        + q4_ * (bf_lo(kpB.z) + e4) + q5 * (bf_hi(kpB.z) + e5)
                        + q6 * (bf_lo(kpB.w) + e6) + q7 * (bf_hi(kpB.w) + e7);
                p += __shfl_xor(p, 1, 64);
                p += __shfl_xor(p, 2, 64);
                float ea = actB ? __expf(p * 0.17677669529663689f) : 0.f;
                a0 += ea * (bf_lo(vpB.x) + e0);  a1 += ea * (bf_hi(vpB.x) + e1);
                a2 += ea * (bf_lo(vpB.y) + e2);  a3 += ea * (bf_hi(vpB.y) + e3);
                a4 += ea * (bf_lo(vpB.z) + e4);  a5 += ea * (bf_hi(vpB.z) + e5);
                a6 += ea * (bf_lo(vpB.w) + e6);  a7 += ea * (bf_hi(vpB.w) + e7);
                den += ea;
            }
        }
        // combine the four quarter-wave edge streams
#pragma unroll
        for (int off = 16; off <= 32; off <<= 1) {
            a0 += __shfl_xor(a0, off, 64);  a1 += __shfl_xor(a1, off, 64);
            a2 += __shfl_xor(a2, off, 64);  a3 += __shfl_xor(a3, off, 64);
            a4 += __shfl_xor(a4, off, 64);  a5 += __shfl_xor(a5, off, 64);
            a6 += __shfl_xor(a6, off, 64);  a7 += __shfl_xor(a7, off, 64);
            den += __shfl_xor(den, off, 64);
        }
        float r = 1.0f / (den + 1e-16f);
        if (q4 == 0) {
            uint4 sp = *(const uint4*)&skipb16[(size_t)node * DMODEL + c0];
            uint4 o;
            o.x = pack_bf16x2(a0 * r + bf_lo(sp.x), a1 * r + bf_hi(sp.x));
            o.y = pack_bf16x2(a2 * r + bf_lo(sp.y), a3 * r + bf_hi(sp.y));
            o.z = pack_bf16x2(a4 * r + bf_lo(sp.z), a5 * r + bf_hi(sp.z));
            o.w = pack_bf16x2(a6 * r + bf_lo(sp.w), a7 * r + bf_hi(sp.w));
            *(uint4*)&qx[(size_t)node * DMODEL + c0] = o;
        }
    }
}

// -------------------------------------------------------------------------
// Kernel (MFMA): FFN on xs16 (= agg_norm + skip, bf16) + transposed write.
// -------------------------------------------------------------------------
#define H1_OFF 16384

__global__ __launch_bounds__(256) void k_ffn_mfma(
    const unsigned short* __restrict__ xs16,
    const uint4* __restrict__ w1f, const float* __restrict__ b1,
    const uint4* __restrict__ w2f, const float* __restrict__ b2,
    float* __restrict__ out)
{
    __shared__ __align__(16) char lds[49152];
    const int tid   = threadIdx.x;
    const int node0 = blockIdx.x * 64;

#pragma unroll
    for (int i = 0; i < 4; ++i) {
        int linear = i * 256 + tid;
        int row = linear >> 4;
        int c8  = (linear & 15) * 8;
        int node = node0 + row;
        uint4 vv = (node < NB) ? *(const uint4*)&xs16[(size_t)node * DMODEL + c8]
                               : make_uint4(0, 0, 0, 0);
        int byte = row * 256 + ((c8 * 2) ^ ((row & 7) << 4));
        *(uint4*)(&lds[byte]) = vv;
    }
    __syncthreads();

    const int w = tid >> 6, lane = tid & 63;
    const int rl = lane & 15, g = lane >> 4;

    // ---- GEMM1: wave w covers col1 in [w*64, w*64+64)
    {
        f32x4 acc[4][4] = {};
#pragma unroll
        for (int ks = 0; ks < 4; ++ks) {
            bf16x8 a[4], b[4];
#pragma unroll
            for (int mt = 0; mt < 4; ++mt) {
                int m1 = w * 4 + mt;
                a[mt] = *(const bf16x8*)&w1f[(m1 * 4 + ks) * 64 + lane];
            }
#pragma unroll
            for (int nt = 0; nt < 4; ++nt) {
                int node = nt * 16 + rl;
                int byte = node * 256 + ((ks * 64 + g * 16) ^ ((node & 7) << 4));
                b[nt] = *(const bf16x8*)&lds[byte];
            }
#pragma unroll
            for (int mt = 0; mt < 4; ++mt)
#pragma unroll
                for (int nt = 0; nt < 4; ++nt)
                    acc[mt][nt] = __builtin_amdgcn_mfma_f32_16x16x32_bf16(
                        a[mt], b[nt], acc[mt][nt], 0, 0, 0);
        }
#pragma unroll
        for (int mt = 0; mt < 4; ++mt) {
            int col1_0 = w * 64 + mt * 16 + g * 4;
            float bb0 = b1[col1_0], bb1 = b1[col1_0 + 1],
                  bb2 = b1[col1_0 + 2], bb3 = b1[col1_0 + 3];
#pragma unroll
            for (int nt = 0; nt < 4; ++nt) {
                int node = nt * 16 + rl;
                float v0 = fmaxf(acc[mt][nt][0] + bb0, 0.f);
                float v1 = fmaxf(acc[mt][nt][1] + bb1, 0.f);
                float v2 = fmaxf(acc[mt][nt][2] + bb2, 0.f);
                float v3 = fmaxf(acc[mt][nt][3] + bb3, 0.f);
                unsigned lo = pack_bf16x2(v0, v1), hi = pack_bf16x2(v2, v3);
                int byte = H1_OFF + node * 512 + ((col1_0 * 2) ^ ((node & 7) << 4));
                *(uint2*)(&lds[byte]) = make_uint2(lo, hi);
            }
        }
    }
    __syncthreads();

    // ---- GEMM2: wave w covers c2 in [w*32, w*32+32)
    {
        f32x4 acc[2][4] = {};
#pragma unroll
        for (int ks = 0; ks < 8; ++ks) {
            bf16x8 a[2], b[4];
#pragma unroll
            for (int mt = 0; mt < 2; ++mt) {
                int m2 = w * 2 + mt;
                a[mt] = *(const bf16x8*)&w2f[(m2 * 8 + ks) * 64 + lane];
            }
#pragma unroll
            for (int nt = 0; nt < 4; ++nt) {
                int node = nt * 16 + rl;
                int byte = H1_OFF + node * 512 + ((ks * 64 + g * 16) ^ ((node & 7) << 4));
                b[nt] = *(const bf16x8*)&lds[byte];
            }
#pragma unroll
            for (int mt = 0; mt < 2; ++mt)
#pragma unroll
                for (int nt = 0; nt < 4; ++nt)
                    acc[mt][nt] = __builtin_amdgcn_mfma_f32_16x16x32_bf16(
                        a[mt], b[nt], acc[mt][nt], 0, 0, 0);
        }
#pragma unroll
        for (int mt = 0; mt < 2; ++mt) {
            int c2_0 = w * 32 + mt * 16 + g * 4;
#pragma unroll
            for (int nt = 0; nt < 4; ++nt) {
                int node = node0 + nt * 16 + rl;
                if (node < NB) {
                    int bb = node / NPB;
                    int nn = node - bb * NPB;
                    size_t base = (size_t)(bb * DMODEL) * NPB + nn;
#pragma unroll
                    for (int r = 0; r < 4; ++r) {
                        float v = fmaxf(acc[mt][nt][r] + b2[c2_0 + r], 0.f);
                        out[base + (size_t)(c2_0 + r) * NPB] = v;
                    }
                }
            }
        }
    }
}

// -------------------------------------------------------------------------
extern "C" void kernel_launch(void* const* d_in, const int* in_sizes, int n_in,
                              void* d_out, int out_size, void* d_ws, size_t ws_size,
                              hipStream_t stream)
{
    const float* x     = (const float*)d_in[0];
    const int*   eidx  = (const int*)  d_in[1];
    const float* eattr = (const float*)d_in[2];
    const float* Wq    = (const float*)d_in[3];
    const float* bq    = (const float*)d_in[4];
    const float* Wk    = (const float*)d_in[5];
    const float* bk    = (const float*)d_in[6];
    const float* Wv    = (const float*)d_in[7];
    const float* bv    = (const float*)d_in[8];
    const float* We    = (const float*)d_in[9];
    const float* Wskip = (const float*)d_in[10];
    const float* bskip = (const float*)d_in[11];
    const float* W1    = (const float*)d_in[12];
    const float* b1    = (const float*)d_in[13];
    const float* W2    = (const float*)d_in[14];
    const float* b2    = (const float*)d_in[15];
    float* out = (float*)d_out;

    // ws layout (~212.9 MB, proven budget):
    // qb16(->xs16) | kvb | skipb16 | eb fp8 | w1f | w2f | wef | wpf |
    // counts | row_start | cursor | elist2 | bsum
    const size_t NBD = (size_t)NB * DMODEL;
    unsigned short* qb16    = (unsigned short*)d_ws;
    unsigned short* kvb     = qb16 + NBD;
    unsigned short* skipb16 = kvb + 2 * NBD;
    unsigned char*  eb      = (unsigned char*)(skipb16 + NBD);
    uint4* w1f = (uint4*)(eb + (size_t)T_E * DMODEL);
    uint4* w2f = w1f + 64 * 64;
    uint4* wef = w2f + 64 * 64;
    uint4* wpf = wef + 8 * 64;
    int* counts    = (int*)(wpf + 128 * 64);
    int* row_start = counts + NB;
    int* cursor    = row_start + NB;
    int2* elist2   = (int2*)(cursor + NB);
    int* bsum      = (int*)(elist2 + T_E);

    hipMemsetAsync(counts, 0, NB * sizeof(int), stream);
    k_prep<<<66, 256, 0, stream>>>(W1, W2, We, Wq, Wk, Wv, Wskip,
                                   w1f, w2f, wef, wpf);
    k_proj2<<<(NB + 63) / 64, 256, 0, stream>>>(x, wpf, bq, bk, bv, bskip,
                                                qb16, kvb, skipb16);
    k_hist<<<(T_E + 255) / 256, 256, 0, stream>>>(eidx, counts);
    k_scan1<<<SCAN_NBLK, 1024, 0, stream>>>(counts, row_start, bsum);
    k_scan2<<<1, 128, 0, stream>>>(bsum);
    k_scan3<<<SCAN_NBLK, 1024, 0, stream>>>(row_start, bsum, cursor);
    k_escat<<<2048, 256, 0, stream>>>(eattr, wef, eidx, cursor, eb, elist2);
    k_aggr3<<<2048, 256, 0, stream>>>(qb16, kvb, skipb16, eb, elist2,
                                      row_start, cursor);
    k_ffn_mfma<<<(NB + 63) / 64, 256, 0, stream>>>(qb16, w1f, b1, w2f, b2, out);
}

// Round 12
// 302.993 us; speedup vs baseline: 2.8228x; 1.1232x over previous
//
#include <hip/hip_runtime.h>
#include <hip/hip_bf16.h>

// Problem constants (from reference)
#define NB      100000    // B*N nodes
#define NPB     25000     // N per batch
#define T_E     800000    // B*E total edges
#define EPG     200000    // E per graph
#define DMODEL  128       // OUT = H*DH
#define EDIM    32
#define FFD     256
#define SCAN_NBLK 98      // ceil(NB/1024)

typedef __attribute__((ext_vector_type(8))) short bf16x8;
typedef __attribute__((ext_vector_type(4))) float f32x4;
typedef __attribute__((ext_vector_type(2))) float f32x2;

__device__ inline unsigned short f2bf(float f) {
    unsigned u = __float_as_uint(f);
    unsigned r = u + 0x7fffu + ((u >> 16) & 1u);   // RNE
    return (unsigned short)(r >> 16);
}
__device__ inline unsigned pack_bf16x2(float lo, float hi) {
    return (unsigned)f2bf(lo) | ((unsigned)f2bf(hi) << 16);
}
__device__ inline float bf_lo(unsigned p) { return __uint_as_float(p << 16); }
__device__ inline float bf_hi(unsigned p) { return __uint_as_float(p & 0xffff0000u); }

// -------------------------------------------------------------------------
// Kernel: pre-pack weights into MFMA A-fragment layout (bf16).
// frags 0..63 w1f | 64..127 w2f | 128..135 wef | 136..263 wpf (Wq,Wk,Wv,Wskip)
// -------------------------------------------------------------------------
__global__ __launch_bounds__(256) void k_prep(
    const float* __restrict__ W1, const float* __restrict__ W2,
    const float* __restrict__ We,
    const float* __restrict__ Wq, const float* __restrict__ Wk,
    const float* __restrict__ Wv, const float* __restrict__ Wskip,
    uint4* __restrict__ w1f, uint4* __restrict__ w2f,
    uint4* __restrict__ wef, uint4* __restrict__ wpf)
{
    int t = blockIdx.x * 256 + threadIdx.x;   // 0..16895
    int lane = t & 63;
    int frag = t >> 6;                         // 0..263
    if (frag >= 264) return;
    int rl = lane & 15, g = lane >> 4;
    unsigned v[4];
    if (frag < 64) {
        int m1 = frag >> 2, ks = frag & 3;
        int col1 = m1 * 16 + rl;
        int k0 = ks * 32 + g * 8;
#pragma unroll
        for (int j2 = 0; j2 < 4; ++j2) {
            float f0 = W1[(k0 + 2 * j2) * FFD + col1];
            float f1 = W1[(k0 + 2 * j2 + 1) * FFD + col1];
            v[j2] = pack_bf16x2(f0, f1);
        }
        w1f[frag * 64 + lane] = make_uint4(v[0], v[1], v[2], v[3]);
    } else if (frag < 128) {
        int f2 = frag - 64;
        int m2 = f2 >> 3, ks = f2 & 7;
        int c2 = m2 * 16 + rl;
        int k0 = ks * 32 + g * 8;
#pragma unroll
        for (int j2 = 0; j2 < 4; ++j2) {
            float f0 = W2[(k0 + 2 * j2) * DMODEL + c2];
            float f1 = W2[(k0 + 2 * j2 + 1) * DMODEL + c2];
            v[j2] = pack_bf16x2(f0, f1);
        }
        w2f[f2 * 64 + lane] = make_uint4(v[0], v[1], v[2], v[3]);
    } else if (frag < 136) {
        int m = frag - 128;                    // 0..7
        int ocol = m * 16 + rl;
        int k0 = g * 8;
#pragma unroll
        for (int j2 = 0; j2 < 4; ++j2) {
            float f0 = We[(k0 + 2 * j2) * DMODEL + ocol];
            float f1 = We[(k0 + 2 * j2 + 1) * DMODEL + ocol];
            v[j2] = pack_bf16x2(f0, f1);
        }
        wef[m * 64 + lane] = make_uint4(v[0], v[1], v[2], v[3]);
    } else {
        int fi = frag - 136;                   // 0..127
        int m  = fi >> 5;                      // matrix 0..3
        int r  = fi & 31;
        int ct = r >> 2, ks = r & 3;
        const float* W = (m == 0) ? Wq : (m == 1) ? Wk : (m == 2) ? Wv : Wskip;
        int col = ct * 16 + rl;
        int k0  = ks * 32 + g * 8;
#pragma unroll
        for (int j2 = 0; j2 < 4; ++j2) {
            float f0 = W[(k0 + 2 * j2) * DMODEL + col];
            float f1 = W[(k0 + 2 * j2 + 1) * DMODEL + col];
            v[j2] = pack_bf16x2(f0, f1);
        }
        wpf[fi * 64 + lane] = make_uint4(v[0], v[1], v[2], v[3]);
    }
}

// -------------------------------------------------------------------------
// Kernel (MFMA): node projections, phase-per-matrix with LDS-staged
// COALESCED global writes.  LDS: xs @0 (16 KB), stage @16384 (16 KB).
// -------------------------------------------------------------------------
#define STG 16384

__global__ __launch_bounds__(256) void k_proj2(
    const float* __restrict__ x, const uint4* __restrict__ wpf,
    const float* __restrict__ bq, const float* __restrict__ bk,
    const float* __restrict__ bv, const float* __restrict__ bskip,
    unsigned short* __restrict__ qb16, unsigned short* __restrict__ kvb,
    unsigned short* __restrict__ skipb16)
{
    __shared__ __align__(16) char lds[32768];
    const int tid   = threadIdx.x;
    const int node0 = blockIdx.x * 64;

    // ---- stage xs: x[b,c,nn] -> xs[node_local][c] (bf16, swizzled)
    {
        const int nl   = tid & 63;
        const int half = tid >> 6;             // 0..3
        const int node = node0 + nl;
        const bool valid = node < NB;
        int b  = node / NPB;
        int nn = node - b * NPB;
        const float* xbase = x + (size_t)b * DMODEL * NPB + nn;
#pragma unroll
        for (int o = 0; o < 4; ++o) {
            int c0 = (half * 4 + o) * 8;
            unsigned vals[4];
#pragma unroll
            for (int j2 = 0; j2 < 4; ++j2) {
                float f0 = valid ? xbase[(size_t)(c0 + 2 * j2) * NPB] : 0.f;
                float f1 = valid ? xbase[(size_t)(c0 + 2 * j2 + 1) * NPB] : 0.f;
                vals[j2] = pack_bf16x2(f0, f1);
            }
            int byte = nl * 256 + ((c0 * 2) ^ ((nl & 7) << 4));
            *(uint4*)(&lds[byte]) = make_uint4(vals[0], vals[1], vals[2], vals[3]);
        }
    }
    __syncthreads();

    const int w = tid >> 6, lane = tid & 63;
    const int rl = lane & 15, g = lane >> 4;

    for (int m = 0; m < 4; ++m) {
        const float* bi = (m == 0) ? bq : (m == 1) ? bk : (m == 2) ? bv : bskip;
        // ---- compute cols [w*32, w*32+32): D[col][node], stage into LDS
#pragma unroll
        for (int ct2 = 0; ct2 < 2; ++ct2) {
            const int ct = w * 2 + ct2;
            bf16x8 A[4];
#pragma unroll
            for (int ks = 0; ks < 4; ++ks)
                A[ks] = *(const bf16x8*)&wpf[((m * 8 + ct) * 4 + ks) * 64 + lane];
            const int colb = ct * 16 + g * 4;
            const float bb0 = bi[colb], bb1 = bi[colb + 1],
                        bb2 = bi[colb + 2], bb3 = bi[colb + 3];
#pragma unroll
            for (int nt = 0; nt < 4; ++nt) {
                const int nl = nt * 16 + rl;
                f32x4 acc = {0.f, 0.f, 0.f, 0.f};
#pragma unroll
                for (int ks = 0; ks < 4; ++ks) {
                    bf16x8 B = *(const bf16x8*)(&lds[nl * 256 +
                                  ((ks * 64 + g * 16) ^ ((nl & 7) << 4))]);
                    acc = __builtin_amdgcn_mfma_f32_16x16x32_bf16(A[ks], B, acc, 0, 0, 0);
                }
                unsigned lo = pack_bf16x2(acc[0] + bb0, acc[1] + bb1);
                unsigned hi = pack_bf16x2(acc[2] + bb2, acc[3] + bb3);
                int byte = STG + nl * 256 + ((colb * 2) ^ ((nl & 7) << 4));
                *(uint2*)(&lds[byte]) = make_uint2(lo, hi);
            }
        }
        __syncthreads();
        // ---- coalesced global write (full 256 B rows)
#pragma unroll
        for (int i = 0; i < 4; ++i) {
            int linear = i * 256 + tid;
            int row = linear >> 4;
            int c8  = (linear & 15) * 8;
            int node = node0 + row;
            if (node < NB) {
                uint4 vv = *(const uint4*)(&lds[STG + row * 256 +
                                ((c8 * 2) ^ ((row & 7) << 4))]);
                if (m == 0)      *(uint4*)&qb16[(size_t)node * DMODEL + c8] = vv;
                else if (m == 1) *(uint4*)&kvb[(size_t)node * 256 + c8] = vv;
                else if (m == 2) *(uint4*)&kvb[(size_t)node * 256 + 128 + c8] = vv;
                else             *(uint4*)&skipb16[(size_t)node * DMODEL + c8] = vv;
            }
        }
        __syncthreads();
    }
}

// -------------------------------------------------------------------------
// CSR build: histogram -> scan (3 kernels) -> scatter.
// -------------------------------------------------------------------------
__global__ __launch_bounds__(256) void k_hist(
    const int* __restrict__ eidx, int* __restrict__ counts)
{
    int t = blockIdx.x * 256 + threadIdx.x;
    if (t < T_E) {
        int b = t / EPG, e = t - b * EPG;
        int dst = eidx[(size_t)(b * 2 + 1) * EPG + e];
        atomicAdd(&counts[dst], 1);
    }
}

__global__ __launch_bounds__(1024) void k_scan1(
    const int* __restrict__ counts, int* __restrict__ row_start,
    int* __restrict__ bsum)
{
    __shared__ int s[1024];
    const int tid = threadIdx.x;
    const int gid = blockIdx.x * 1024 + tid;
    int v = (gid < NB) ? counts[gid] : 0;
    s[tid] = v;
    __syncthreads();
#pragma unroll
    for (int off = 1; off < 1024; off <<= 1) {
        int tv = (tid >= off) ? s[tid - off] : 0;
        __syncthreads();
        s[tid] += tv;
        __syncthreads();
    }
    int incl = s[tid];
    if (gid < NB) row_start[gid] = incl - v;
    if (tid == 1023) bsum[blockIdx.x] = incl;
}

__global__ __launch_bounds__(128) void k_scan2(int* __restrict__ bsum)
{
    __shared__ int s[128];
    const int tid = threadIdx.x;
    int v = (tid < SCAN_NBLK) ? bsum[tid] : 0;
    s[tid] = v;
    __syncthreads();
#pragma unroll
    for (int off = 1; off < 128; off <<= 1) {
        int tv = (tid >= off) ? s[tid - off] : 0;
        __syncthreads();
        s[tid] += tv;
        __syncthreads();
    }
    if (tid < SCAN_NBLK) bsum[tid] = s[tid] - v;
}

__global__ __launch_bounds__(1024) void k_scan3(
    int* __restrict__ row_start, const int* __restrict__ bsum,
    int* __restrict__ cursor)
{
    const int gid = blockIdx.x * 1024 + threadIdx.x;
    if (gid < NB) {
        int v = row_start[gid] + bsum[blockIdx.x];
        row_start[gid] = v;
        cursor[gid] = v;
    }
}

__global__ __launch_bounds__(256) void k_scatter(
    const int* __restrict__ eidx, int* __restrict__ cursor,
    int2* __restrict__ elist2)
{
    int t = blockIdx.x * 256 + threadIdx.x;
    if (t < T_E) {
        int b = t / EPG, e = t - b * EPG;
        int dst = eidx[(size_t)(b * 2 + 1) * EPG + e];
        int src = eidx[(size_t)(b * 2) * EPG + e];
        int pos = atomicAdd(&cursor[dst], 1);
        elist2[pos] = make_int2(src, t);   // after: cursor[d] == row_end[d]
    }
}

// -------------------------------------------------------------------------
// Kernel: e-projection, edge-parallel MFMA -> eb fp8, with wave-private
// LDS transpose so eb is written in fully coalesced 1 KB bursts.
// -------------------------------------------------------------------------
__global__ __launch_bounds__(256) void k_eproj(
    const float* __restrict__ eattr, const uint4* __restrict__ wef,
    unsigned char* __restrict__ eb)
{
    __shared__ __align__(16) char elds[8192];   // 4 waves x 2 KB
    const int tid = threadIdx.x;
    const int w = tid >> 6, lane = tid & 63;
    const int rl = lane & 15, g = lane >> 4;
    char* myl = &elds[w * 2048];

    bf16x8 a[8];
#pragma unroll
    for (int m = 0; m < 8; ++m) a[m] = *(const bf16x8*)&wef[m * 64 + lane];

    const int nwaves = gridDim.x * 4;
    for (int tile = blockIdx.x * 4 + w; tile < T_E / 16; tile += nwaves) {
        const float* ep = &eattr[((size_t)tile * 16 + rl) * EDIM + g * 8];
        float4 f0 = *(const float4*)ep;
        float4 f1 = *(const float4*)(ep + 4);
        uint4 bu = make_uint4(pack_bf16x2(f0.x, f0.y), pack_bf16x2(f0.z, f0.w),
                              pack_bf16x2(f1.x, f1.y), pack_bf16x2(f1.z, f1.w));
        bf16x8 b = *(bf16x8*)&bu;
        f32x4 z = {0.f, 0.f, 0.f, 0.f};
        f32x4 acc[8];
#pragma unroll
        for (int m = 0; m < 8; ++m)
            acc[m] = __builtin_amdgcn_mfma_f32_16x16x32_bf16(a[m], b, z, 0, 0, 0);
        // pack fp8 -> wave-private LDS (swizzled 16B chunks: 2-way conflicts max)
#pragma unroll
        for (int m = 0; m < 8; ++m) {
            unsigned d = __builtin_amdgcn_cvt_pk_fp8_f32(acc[m][0], acc[m][1], 0, false);
            d = __builtin_amdgcn_cvt_pk_fp8_f32(acc[m][2], acc[m][3], d, true);
            *(unsigned*)(myl + rl * 128 + ((m * 16) ^ ((rl & 7) << 4)) + g * 4) = d;
        }
        // read back (same wave, in-order) and write coalesced 1 KB x 2
#pragma unroll
        for (int it = 0; it < 2; ++it) {
            int lin = it * 64 + lane;
            int row = lin >> 3, chunk = lin & 7;
            uint4 vv = *(const uint4*)(myl + row * 128 + ((chunk ^ (row & 7)) << 4));
            *(uint4*)&eb[(size_t)tile * 2048 + (size_t)lin * 16] = vv;
        }
    }
}

// -------------------------------------------------------------------------
// Kernel: per-node gather-aggregate, 8 edges in flight per wave
// (2 quads of quarter-waves), 8 channels per lane, eb fp8 e-add.
// Output: xs16[node][c] = agg_norm + skip (bf16) — into qb16 space.
// -------------------------------------------------------------------------
__global__ __launch_bounds__(256) void k_aggr3(
    unsigned short* qx,                       // q (read) / xs16 (write) — aliased
    const unsigned short* __restrict__ kvb,
    const unsigned short* __restrict__ skipb16,
    const unsigned char* __restrict__ eb,
    const int2* __restrict__ elist2,
    const int* __restrict__ row_start, const int* __restrict__ row_end)
{
    const int tid = threadIdx.x;
    const int w = tid >> 6, l = tid & 63;
    const int q4 = l >> 4;                    // which edge of the quad
    const int li = l & 15;
    const int c0 = li * 8;                    // this lane's 8 channels

    const int nwaves = gridDim.x * 4;
    for (int node = blockIdx.x * 4 + w; node < NB; node += nwaves) {
        const int rs = row_start[node];
        const int re = row_end[node];
        uint4 qp = *(const uint4*)&qx[(size_t)node * DMODEL + c0];
        const float q0 = bf_lo(qp.x), q1 = bf_hi(qp.x);
        const float q2 = bf_lo(qp.y), q3 = bf_hi(qp.y);
        const float q4_ = bf_lo(qp.z), q5 = bf_hi(qp.z);
        const float q6 = bf_lo(qp.w), q7 = bf_hi(qp.w);
        float a0 = 0.f, a1 = 0.f, a2 = 0.f, a3 = 0.f;
        float a4 = 0.f, a5 = 0.f, a6 = 0.f, a7 = 0.f, den = 0.f;

        for (int j0 = rs; j0 < re; j0 += 8) {
            const int jcA = j0 + q4;
            const int jcB = j0 + 4 + q4;
            const bool actA = jcA < re;        // uniform across 16-lane group
            const bool actB = jcB < re;
            uint4 kpA = make_uint4(0,0,0,0), vpA = make_uint4(0,0,0,0);
            uint4 kpB = make_uint4(0,0,0,0), vpB = make_uint4(0,0,0,0);
            uint2 epA = make_uint2(0,0), epB = make_uint2(0,0);
            if (actA) {
                int2 se = elist2[jcA];
                kpA = *(const uint4*)&kvb[(size_t)se.x * 256 + c0];
                vpA = *(const uint4*)&kvb[(size_t)se.x * 256 + 128 + c0];
                epA = *(const uint2*)&eb[(size_t)se.y * DMODEL + c0];
            }
            if (actB) {
                int2 se = elist2[jcB];
                kpB = *(const uint4*)&kvb[(size_t)se.x * 256 + c0];
                vpB = *(const uint4*)&kvb[(size_t)se.x * 256 + 128 + c0];
                epB = *(const uint2*)&eb[(size_t)se.y * DMODEL + c0];
            }
            // ---- quad A
            {
                f32x2 exl = __builtin_amdgcn_cvt_pk_f32_fp8(epA.x, false);
                f32x2 exh = __builtin_amdgcn_cvt_pk_f32_fp8(epA.x, true);
                f32x2 eyl = __builtin_amdgcn_cvt_pk_f32_fp8(epA.y, false);
                f32x2 eyh = __builtin_amdgcn_cvt_pk_f32_fp8(epA.y, true);
                const float e0 = exl[0], e1 = exl[1], e2 = exh[0], e3 = exh[1];
                const float e4 = eyl[0], e5 = eyl[1], e6 = eyh[0], e7 = eyh[1];
                float p = q0 * (bf_lo(kpA.x) + e0) + q1 * (bf_hi(kpA.x) + e1)
                        + q2 * (bf_lo(kpA.y) + e2) + q3 * (bf_hi(kpA.y) + e3)
                        + q4_ * (bf_lo(kpA.z) + e4) + q5 * (bf_hi(kpA.z) + e5)
                        + q6 * (bf_lo(kpA.w) + e6) + q7 * (bf_hi(kpA.w) + e7);
                p += __shfl_xor(p, 1, 64);
                p += __shfl_xor(p, 2, 64);
                float ea = actA ? __expf(p * 0.17677669529663689f) : 0.f;
                a0 += ea * (bf_lo(vpA.x) + e0);  a1 += ea * (bf_hi(vpA.x) + e1);
                a2 += ea * (bf_lo(vpA.y) + e2);  a3 += ea * (bf_hi(vpA.y) + e3);
                a4 += ea * (bf_lo(vpA.z) + e4);  a5 += ea * (bf_hi(vpA.z) + e5);
                a6 += ea * (bf_lo(vpA.w) + e6);  a7 += ea * (bf_hi(vpA.w) + e7);
                den += ea;
            }
            // ---- quad B
            {
                f32x2 exl = __builtin_amdgcn_cvt_pk_f32_fp8(epB.x, false);
                f32x2 exh = __builtin_amdgcn_cvt_pk_f32_fp8(epB.x, true);
                f32x2 eyl = __builtin_amdgcn_cvt_pk_f32_fp8(epB.y, false);
                f32x2 eyh = __builtin_amdgcn_cvt_pk_f32_fp8(epB.y, true);
                const float e0 = exl[0], e1 = exl[1], e2 = exh[0], e3 = exh[1];
                const float e4 = eyl[0], e5 = eyl[1], e6 = eyh[0], e7 = eyh[1];
                float p = q0 * (bf_lo(kpB.x) + e0) + q1 * (bf_hi(kpB.x) + e1)
                        + q2 * (bf_lo(kpB.y) + e2) + q3 * (bf_hi(kpB.y) + e3)
                        + q4_ * (bf_lo(kpB.z) + e4) + q5 * (bf_hi(kpB.z) + e5)
                        + q6 * (bf_lo(kpB.w) + e6) + q7 * (bf_hi(kpB.w) + e7);
                p += __shfl_xor(p, 1, 64);
                p += __shfl_xor(p, 2, 64);
                float ea = actB ? __expf(p * 0.17677669529663689f) : 0.f;
                a0 += ea * (bf_lo(vpB.x) + e0);  a1 += ea * (bf_hi(vpB.x) + e1);
                a2 += ea * (bf_lo(vpB.y) + e2);  a3 += ea * (bf_hi(vpB.y) + e3);
                a4 += ea * (bf_lo(vpB.z) + e4);  a5 += ea * (bf_hi(vpB.z) + e5);
                a6 += ea * (bf_lo(vpB.w) + e6);  a7 += ea * (bf_hi(vpB.w) + e7);
                den += ea;
            }
        }
        // combine the four quarter-wave edge streams
#pragma unroll
        for (int off = 16; off <= 32; off <<= 1) {
            a0 += __shfl_xor(a0, off, 64);  a1 += __shfl_xor(a1, off, 64);
            a2 += __shfl_xor(a2, off, 64);  a3 += __shfl_xor(a3, off, 64);
            a4 += __shfl_xor(a4, off, 64);  a5 += __shfl_xor(a5, off, 64);
            a6 += __shfl_xor(a6, off, 64);  a7 += __shfl_xor(a7, off, 64);
            den += __shfl_xor(den, off, 64);
        }
        float r = 1.0f / (den + 1e-16f);
        if (q4 == 0) {
            uint4 sp = *(const uint4*)&skipb16[(size_t)node * DMODEL + c0];
            uint4 o;
            o.x = pack_bf16x2(a0 * r + bf_lo(sp.x), a1 * r + bf_hi(sp.x));
            o.y = pack_bf16x2(a2 * r + bf_lo(sp.y), a3 * r + bf_hi(sp.y));
            o.z = pack_bf16x2(a4 * r + bf_lo(sp.z), a5 * r + bf_hi(sp.z));
            o.w = pack_bf16x2(a6 * r + bf_lo(sp.w), a7 * r + bf_hi(sp.w));
            *(uint4*)&qx[(size_t)node * DMODEL + c0] = o;
        }
    }
}

// -------------------------------------------------------------------------
// Kernel (MFMA): FFN on xs16 (= agg_norm + skip, bf16) + transposed write.
// -------------------------------------------------------------------------
#define H1_OFF 16384

__global__ __launch_bounds__(256) void k_ffn_mfma(
    const unsigned short* __restrict__ xs16,
    const uint4* __restrict__ w1f, const float* __restrict__ b1,
    const uint4* __restrict__ w2f, const float* __restrict__ b2,
    float* __restrict__ out)
{
    __shared__ __align__(16) char lds[49152];
    const int tid   = threadIdx.x;
    const int node0 = blockIdx.x * 64;

#pragma unroll
    for (int i = 0; i < 4; ++i) {
        int linear = i * 256 + tid;
        int row = linear >> 4;
        int c8  = (linear & 15) * 8;
        int node = node0 + row;
        uint4 vv = (node < NB) ? *(const uint4*)&xs16[(size_t)node * DMODEL + c8]
                               : make_uint4(0, 0, 0, 0);
        int byte = row * 256 + ((c8 * 2) ^ ((row & 7) << 4));
        *(uint4*)(&lds[byte]) = vv;
    }
    __syncthreads();

    const int w = tid >> 6, lane = tid & 63;
    const int rl = lane & 15, g = lane >> 4;

    // ---- GEMM1: wave w covers col1 in [w*64, w*64+64)
    {
        f32x4 acc[4][4] = {};
#pragma unroll
        for (int ks = 0; ks < 4; ++ks) {
            bf16x8 a[4], b[4];
#pragma unroll
            for (int mt = 0; mt < 4; ++mt) {
                int m1 = w * 4 + mt;
                a[mt] = *(const bf16x8*)&w1f[(m1 * 4 + ks) * 64 + lane];
            }
#pragma unroll
            for (int nt = 0; nt < 4; ++nt) {
                int node = nt * 16 + rl;
                int byte = node * 256 + ((ks * 64 + g * 16) ^ ((node & 7) << 4));
                b[nt] = *(const bf16x8*)&lds[byte];
            }
#pragma unroll
            for (int mt = 0; mt < 4; ++mt)
#pragma unroll
                for (int nt = 0; nt < 4; ++nt)
                    acc[mt][nt] = __builtin_amdgcn_mfma_f32_16x16x32_bf16(
                        a[mt], b[nt], acc[mt][nt], 0, 0, 0);
        }
#pragma unroll
        for (int mt = 0; mt < 4; ++mt) {
            int col1_0 = w * 64 + mt * 16 + g * 4;
            float bb0 = b1[col1_0], bb1 = b1[col1_0 + 1],
                  bb2 = b1[col1_0 + 2], bb3 = b1[col1_0 + 3];
#pragma unroll
            for (int nt = 0; nt < 4; ++nt) {
                int node = nt * 16 + rl;
                float v0 = fmaxf(acc[mt][nt][0] + bb0, 0.f);
                float v1 = fmaxf(acc[mt][nt][1] + bb1, 0.f);
                float v2 = fmaxf(acc[mt][nt][2] + bb2, 0.f);
                float v3 = fmaxf(acc[mt][nt][3] + bb3, 0.f);
                unsigned lo = pack_bf16x2(v0, v1), hi = pack_bf16x2(v2, v3);
                int byte = H1_OFF + node * 512 + ((col1_0 * 2) ^ ((node & 7) << 4));
                *(uint2*)(&lds[byte]) = make_uint2(lo, hi);
            }
        }
    }
    __syncthreads();

    // ---- GEMM2: wave w covers c2 in [w*32, w*32+32)
    {
        f32x4 acc[2][4] = {};
#pragma unroll
        for (int ks = 0; ks < 8; ++ks) {
            bf16x8 a[2], b[4];
#pragma unroll
            for (int mt = 0; mt < 2; ++mt) {
                int m2 = w * 2 + mt;
                a[mt] = *(const bf16x8*)&w2f[(m2 * 8 + ks) * 64 + lane];
            }
#pragma unroll
            for (int nt = 0; nt < 4; ++nt) {
                int node = nt * 16 + rl;
                int byte = H1_OFF + node * 512 + ((ks * 64 + g * 16) ^ ((node & 7) << 4));
                b[nt] = *(const bf16x8*)&lds[byte];
            }
#pragma unroll
            for (int mt = 0; mt < 2; ++mt)
#pragma unroll
                for (int nt = 0; nt < 4; ++nt)
                    acc[mt][nt] = __builtin_amdgcn_mfma_f32_16x16x32_bf16(
                        a[mt], b[nt], acc[mt][nt], 0, 0, 0);
        }
#pragma unroll
        for (int mt = 0; mt < 2; ++mt) {
            int c2_0 = w * 32 + mt * 16 + g * 4;
#pragma unroll
            for (int nt = 0; nt < 4; ++nt) {
                int node = node0 + nt * 16 + rl;
                if (node < NB) {
                    int bb = node / NPB;
                    int nn = node - bb * NPB;
                    size_t base = (size_t)(bb * DMODEL) * NPB + nn;
#pragma unroll
                    for (int r = 0; r < 4; ++r) {
                        float v = fmaxf(acc[mt][nt][r] + b2[c2_0 + r], 0.f);
                        out[base + (size_t)(c2_0 + r) * NPB] = v;
                    }
                }
            }
        }
    }
}

// -------------------------------------------------------------------------
extern "C" void kernel_launch(void* const* d_in, const int* in_sizes, int n_in,
                              void* d_out, int out_size, void* d_ws, size_t ws_size,
                              hipStream_t stream)
{
    const float* x     = (const float*)d_in[0];
    const int*   eidx  = (const int*)  d_in[1];
    const float* eattr = (const float*)d_in[2];
    const float* Wq    = (const float*)d_in[3];
    const float* bq    = (const float*)d_in[4];
    const float* Wk    = (const float*)d_in[5];
    const float* bk    = (const float*)d_in[6];
    const float* Wv    = (const float*)d_in[7];
    const float* bv    = (const float*)d_in[8];
    const float* We    = (const float*)d_in[9];
    const float* Wskip = (const float*)d_in[10];
    const float* bskip = (const float*)d_in[11];
    const float* W1    = (const float*)d_in[12];
    const float* b1    = (const float*)d_in[13];
    const float* W2    = (const float*)d_in[14];
    const float* b2    = (const float*)d_in[15];
    float* out = (float*)d_out;

    // ws layout (~212.9 MB, proven budget):
    // qb16(->xs16) | kvb | skipb16 | eb fp8 | w1f | w2f | wef | wpf |
    // counts | row_start | cursor | elist2 | bsum
    const size_t NBD = (size_t)NB * DMODEL;
    unsigned short* qb16    = (unsigned short*)d_ws;
    unsigned short* kvb     = qb16 + NBD;
    unsigned short* skipb16 = kvb + 2 * NBD;
    unsigned char*  eb      = (unsigned char*)(skipb16 + NBD);
    uint4* w1f = (uint4*)(eb + (size_t)T_E * DMODEL);
    uint4* w2f = w1f + 64 * 64;
    uint4* wef = w2f + 64 * 64;
    uint4* wpf = wef + 8 * 64;
    int* counts    = (int*)(wpf + 128 * 64);
    int* row_start = counts + NB;
    int* cursor    = row_start + NB;
    int2* elist2   = (int2*)(cursor + NB);
    int* bsum      = (int*)(elist2 + T_E);

    hipMemsetAsync(counts, 0, NB * sizeof(int), stream);
    k_prep<<<66, 256, 0, stream>>>(W1, W2, We, Wq, Wk, Wv, Wskip,
                                   w1f, w2f, wef, wpf);
    k_proj2<<<(NB + 63) / 64, 256, 0, stream>>>(x, wpf, bq, bk, bv, bskip,
                                                qb16, kvb, skipb16);
    k_hist<<<(T_E + 255) / 256, 256, 0, stream>>>(eidx, counts);
    k_scan1<<<SCAN_NBLK, 1024, 0, stream>>>(counts, row_start, bsum);
    k_scan2<<<1, 128, 0, stream>>>(bsum);
    k_scan3<<<SCAN_NBLK, 1024, 0, stream>>>(row_start, bsum, cursor);
    k_scatter<<<(T_E + 255) / 256, 256, 0, stream>>>(eidx, cursor, elist2);
    k_eproj<<<2048, 256, 0, stream>>>(eattr, wef, eb);
    k_aggr3<<<2048, 256, 0, stream>>>(qb16, kvb, skipb16, eb, elist2,
                                      row_start, cursor);
    k_ffn_mfma<<<(NB + 63) / 64, 256, 0, stream>>>(qb16, w1f, b1, w2f, b2, out);
}